// Round 10
// baseline (6965.993 us; speedup 1.0000x reference)
//
#include <hip/hip_runtime.h>
#include <cmath>

namespace {

constexpr int B = 16;
constexpr int N = 978;
constexpr int M = B * N;          // 15648
constexpr int IB2 = 128;          // 2*IB
constexpr int KATT = 4096;        // P*HID
constexpr int KCH = 512;          // hp column chunk
constexpr int DF = 2304;
constexpr int TOPKK = 50;
constexpr int NEDGE = 50000;
constexpr int CANDMAX = 64;
constexpr int WST = 120;

typedef __attribute__((ext_vector_type(8))) short bf16x8;
typedef __attribute__((ext_vector_type(4))) float f32x4;

__device__ __forceinline__ float geluf(float x) {
  return 0.5f * x * (1.f + erff(x * 0.7071067811865476f));
}
__device__ __forceinline__ float sigm(float x) { return 1.f / (1.f + expf(-x)); }
__device__ __forceinline__ double sigm64(double x) { return 1.0 / (1.0 + exp(-x)); }

__device__ __forceinline__ unsigned short f2bf(float f) {
  union { float f; unsigned u; } x; x.f = f;
  unsigned r = (x.u + 0x7FFFu + ((x.u >> 16) & 1u)) >> 16;
  return (unsigned short)r;
}
__device__ __forceinline__ float bf2f(unsigned short s) {
  union { float f; unsigned u; } x; x.u = ((unsigned)s) << 16; return x.f;
}

// ---------------- WT build: (4096 x 256) bf16 hi/lo of W_sims^T * sigm(fm) ----------------
__global__ void k_wt(const float* __restrict__ wsims, const float* __restrict__ fm,
                     unsigned short* __restrict__ wth, unsigned short* __restrict__ wtl) {
  int t = blockIdx.x * 256 + threadIdx.x;   // < 4096*256 = 1048576 exact
  int n = t >> 8, k = t & 255;
  int p = n >> 9, h = n & 511;
  double v = (double)wsims[(size_t)p * 131072 + (size_t)k * 512 + h] * sigm64((double)fm[k]);
  float vf = (float)v;
  unsigned short hi = f2bf(vf);
  wth[t] = hi;
  wtl[t] = f2bf(vf - bf2f(hi));
}

// ---------------- FUS build: (M x 256) bf16 hi/lo of [Hb | DDg] ----------------
__global__ void k_fus(const float* __restrict__ Hb, const float* __restrict__ DD,
                      unsigned short* __restrict__ fh, unsigned short* __restrict__ fl) {
  int t = blockIdx.x * 256 + threadIdx.x;   // < M*256 exact
  int k = t & 255;
  int row = t >> 8;
  int b = row / N;
  float v = (k < 128) ? Hb[(size_t)row * 128 + k] : DD[(size_t)b * 128 + (k - 128)];
  unsigned short hi = f2bf(v);
  fh[t] = hi;
  fl[t] = f2bf(v - bf2f(hi));
}

__global__ void k_gate_emb(const float* __restrict__ x1, const float* __restrict__ gW,
                           const float* __restrict__ gb, const float* __restrict__ emb,
                           float* __restrict__ A) {
  size_t t = (size_t)blockIdx.x * 256 + threadIdx.x;  // < M*512 exact
  int e = (int)(t & 511);
  size_t bn = t >> 9;
  int n = (int)(bn % N);
  float g = sigm(x1[bn] * gW[e] + gb[e]);
  A[t] = g * emb[(size_t)n * 512 + e];
}

__global__ void k_zero(float* __restrict__ p, int n) {
  int t = blockIdx.x * 256 + threadIdx.x;
  if (t < n) p[t] = 0.f;
}

__global__ void k_scatter(const int* __restrict__ ei, float* __restrict__ adj) {
  int t = blockIdx.x * 256 + threadIdx.x;
  if (t < NEDGE) {
    int r = ei[t], c = ei[NEDGE + t];
    adj[(size_t)r * N + c] = 1.f;
  }
}

// ---------------- generic fp32 GEMM (encoder / GCN XW) ----------------
template <int ACT, bool HASBIAS>
__global__ __launch_bounds__(256) void k_gemm(const float* __restrict__ A,
                                              const float* __restrict__ W, const float* __restrict__ bias,
                                              float* __restrict__ C,
                                              int Mm, int K, int Nc, int ldw) {
  __shared__ float As[16][132];
  __shared__ float Ws[16][132];
  const int tid = threadIdx.x;
  const int m0 = blockIdx.x * 128;
  const int n0 = blockIdx.y * 128;
  const int ty = tid >> 4, tx = tid & 15;
  float acc[8][8];
#pragma unroll
  for (int i = 0; i < 8; i++)
#pragma unroll
    for (int j = 0; j < 8; j++) acc[i][j] = 0.f;

  for (int k0 = 0; k0 < K; k0 += 16) {
#pragma unroll
    for (int l = 0; l < 2; l++) {
      int idx4 = tid + l * 256;
      int r = idx4 >> 2, c4 = idx4 & 3;
      int row = m0 + r;
      float4 v = make_float4(0.f, 0.f, 0.f, 0.f);
      if (row < Mm) v = *reinterpret_cast<const float4*>(&A[(size_t)row * K + k0 + c4 * 4]);
      As[c4 * 4 + 0][r] = v.x;
      As[c4 * 4 + 1][r] = v.y;
      As[c4 * 4 + 2][r] = v.z;
      As[c4 * 4 + 3][r] = v.w;
    }
#pragma unroll
    for (int l = 0; l < 2; l++) {
      int idx4 = tid + l * 256;
      int r = idx4 >> 5, c4 = idx4 & 31;
      float4 v = *reinterpret_cast<const float4*>(&W[(size_t)(k0 + r) * ldw + n0 + c4 * 4]);
      *reinterpret_cast<float4*>(&Ws[r][c4 * 4]) = v;
    }
    __syncthreads();
#pragma unroll
    for (int k = 0; k < 16; k++) {
      float a[8], bb[8];
      *reinterpret_cast<float4*>(&a[0]) = *reinterpret_cast<const float4*>(&As[k][ty * 8]);
      *reinterpret_cast<float4*>(&a[4]) = *reinterpret_cast<const float4*>(&As[k][ty * 8 + 4]);
      *reinterpret_cast<float4*>(&bb[0]) = *reinterpret_cast<const float4*>(&Ws[k][tx * 8]);
      *reinterpret_cast<float4*>(&bb[4]) = *reinterpret_cast<const float4*>(&Ws[k][tx * 8 + 4]);
#pragma unroll
      for (int i = 0; i < 8; i++)
#pragma unroll
        for (int j = 0; j < 8; j++) acc[i][j] = fmaf(a[i], bb[j], acc[i][j]);
    }
    __syncthreads();
  }
#pragma unroll
  for (int i = 0; i < 8; i++) {
    int row = m0 + ty * 8 + i;
    if (row >= Mm) continue;
#pragma unroll
    for (int j4 = 0; j4 < 2; j4++) {
      float4 v;
      float* vv = reinterpret_cast<float*>(&v);
#pragma unroll
      for (int j = 0; j < 4; j++) {
        float x = acc[i][j4 * 4 + j];
        if (HASBIAS) x += bias[n0 + tx * 8 + j4 * 4 + j];
        if (ACT == 1) x = geluf(x);
        if (ACT == 2) x = fmaxf(x, 0.f);
        vv[j] = x;
      }
      *reinterpret_cast<float4*>(&C[(size_t)row * Nc + n0 + tx * 8 + j4 * 4]) = v;
    }
  }
}

// ------- MFMA staging: 128x32 bf16 tile, XOR-swizzled ((r&7)<<4 on 64B rows) -------
__device__ __forceinline__ void stage_tile(const unsigned short* __restrict__ gbase, int grow0,
                                           int rowmax, int k0, int ldk, char* lds, int tid) {
#pragma unroll
  for (int it = 0; it < 2; it++) {
    int r = (tid >> 2) + it * 64;
    int c8 = tid & 3;
    int gr = grow0 + r;
    uint4 v = make_uint4(0u, 0u, 0u, 0u);
    if (gr < rowmax) v = *reinterpret_cast<const uint4*>(&gbase[(size_t)gr * ldk + k0 + c8 * 8]);
    int off = (r * 64 + c8 * 16) ^ ((r & 7) << 4);
    *reinterpret_cast<uint4*>(lds + off) = v;
  }
}

__device__ __forceinline__ bf16x8 frag(const char* lds, int r, int k8) {
  int off = (r * 64 + k8 * 16) ^ ((r & 7) << 4);
  return *reinterpret_cast<const bf16x8*>(lds + off);
}

// ------- hp chunk GEMM, split-bf16 (fp32-equivalent): CH = relu(FUS @ WT_chunk^T) -------
__global__ __launch_bounds__(256) void k_hp_mma(const unsigned short* __restrict__ FH,
                                                const unsigned short* __restrict__ FL,
                                                const unsigned short* __restrict__ WTHc,
                                                const unsigned short* __restrict__ WTLc,
                                                float* __restrict__ CH) {
  __shared__ __align__(16) char Ah[8192];
  __shared__ __align__(16) char Al[8192];
  __shared__ __align__(16) char Bh[8192];
  __shared__ __align__(16) char Bl[8192];
  const int m0 = blockIdx.x * 128;
  const int n0 = blockIdx.y * 128;   // within chunk (512)
  const int tid = threadIdx.x;
  const int wave = tid >> 6, lane = tid & 63;
  f32x4 acc[2][8];
#pragma unroll
  for (int i = 0; i < 2; i++)
#pragma unroll
    for (int j = 0; j < 8; j++) acc[i][j] = (f32x4){0.f, 0.f, 0.f, 0.f};

  for (int k0 = 0; k0 < 256; k0 += 32) {
    stage_tile(FH, m0, M, k0, 256, Ah, tid);
    stage_tile(FL, m0, M, k0, 256, Al, tid);
    stage_tile(WTHc, n0, 512, k0, 256, Bh, tid);
    stage_tile(WTLc, n0, 512, k0, 256, Bl, tid);
    __syncthreads();
    bf16x8 ah[2], al[2];
#pragma unroll
    for (int rf = 0; rf < 2; rf++) {
      int r = wave * 32 + rf * 16 + (lane & 15);
      ah[rf] = frag(Ah, r, lane >> 4);
      al[rf] = frag(Al, r, lane >> 4);
    }
#pragma unroll
    for (int cf = 0; cf < 8; cf++) {
      int rB = cf * 16 + (lane & 15);
      bf16x8 bh = frag(Bh, rB, lane >> 4);
      bf16x8 bl = frag(Bl, rB, lane >> 4);
#pragma unroll
      for (int rf = 0; rf < 2; rf++) {
        acc[rf][cf] = __builtin_amdgcn_mfma_f32_16x16x32_bf16(ah[rf], bh, acc[rf][cf], 0, 0, 0);
        acc[rf][cf] = __builtin_amdgcn_mfma_f32_16x16x32_bf16(ah[rf], bl, acc[rf][cf], 0, 0, 0);
        acc[rf][cf] = __builtin_amdgcn_mfma_f32_16x16x32_bf16(al[rf], bh, acc[rf][cf], 0, 0, 0);
      }
    }
    __syncthreads();
  }
#pragma unroll
  for (int rf = 0; rf < 2; rf++)
#pragma unroll
    for (int cf = 0; cf < 8; cf++)
#pragma unroll
      for (int r4 = 0; r4 < 4; r4++) {
        int row = m0 + wave * 32 + rf * 16 + ((lane >> 4) << 2) + r4;
        int col = n0 + cf * 16 + (lane & 15);
        if (row < M) CH[(size_t)row * 512 + col] = fmaxf(acc[rf][cf][r4], 0.f);
      }
}

// ---------------- per-chunk column means (parallel, deterministic) ----------------
__global__ __launch_bounds__(256) void k_mu(const float* __restrict__ CH, float* __restrict__ MU) {
  __shared__ double red[8][33];
  int b = blockIdx.y, jg = blockIdx.x;
  int jloc = threadIdx.x & 31, s = threadIdx.x >> 5;
  int j = jg * 32 + jloc;
  const float* p = CH + (size_t)b * N * KCH + j;
  double acc = 0.0;
  for (int n = s; n < N; n += 8) acc += (double)p[(size_t)n * KCH];
  red[s][jloc] = acc;
  __syncthreads();
  if (s == 0) {
    double t = 0.0;
#pragma unroll
    for (int k = 0; k < 8; k++) t += red[k][jloc];
    MU[b * KCH + j] = (float)(t * (1.0 / (double)N));
  }
}

// ------- fused center+q: CHB = bf16(CH - MU); qv[r] += <MU[b], CH[r]> (f64) -------
__global__ __launch_bounds__(256) void k_centerq(const float* __restrict__ CH,
                                                 const float* __restrict__ MU,
                                                 unsigned short* __restrict__ CHB,
                                                 double* __restrict__ qv) {
  int r = blockIdx.x * 4 + (threadIdx.x >> 6);   // grid = M/4 = 3912 exact
  int lane = threadIdx.x & 63;
  int b = r / N;
  const float* row = CH + (size_t)r * KCH;
  const float* mu = MU + (size_t)b * KCH;
  int j0 = lane * 8;
  float4 v0 = *reinterpret_cast<const float4*>(&row[j0]);
  float4 v1 = *reinterpret_cast<const float4*>(&row[j0 + 4]);
  float4 m0 = *reinterpret_cast<const float4*>(&mu[j0]);
  float4 m1 = *reinterpret_cast<const float4*>(&mu[j0 + 4]);
  unsigned short cb[8];
  cb[0] = f2bf(v0.x - m0.x); cb[1] = f2bf(v0.y - m0.y);
  cb[2] = f2bf(v0.z - m0.z); cb[3] = f2bf(v0.w - m0.w);
  cb[4] = f2bf(v1.x - m1.x); cb[5] = f2bf(v1.y - m1.y);
  cb[6] = f2bf(v1.z - m1.z); cb[7] = f2bf(v1.w - m1.w);
  *reinterpret_cast<uint4*>(&CHB[(size_t)r * KCH + j0]) = *reinterpret_cast<uint4*>(cb);
  double q = (double)m0.x * v0.x + (double)m0.y * v0.y + (double)m0.z * v0.z + (double)m0.w * v0.w
           + (double)m1.x * v1.x + (double)m1.y * v1.y + (double)m1.z * v1.z + (double)m1.w * v1.w;
  for (int off = 32; off > 0; off >>= 1) q += __shfl_down(q, off);
  if (lane == 0) qv[r] += q;
}

// ------- centered Gram via bf16 MFMA: G[b] (+)= CHBc @ CHBc^T -------
template <bool ACC>
__global__ __launch_bounds__(256) void k_syrk_mma(const unsigned short* __restrict__ CHB,
                                                  float* __restrict__ ATT) {
  __shared__ __align__(16) char At[8192];
  __shared__ __align__(16) char Bt[8192];
  const int T = 8;
  int pr = blockIdx.x;
  int ti = 0, rem = pr;
  while (rem >= T - ti) { rem -= T - ti; ti++; }
  int tj = ti + rem;
  int b = blockIdx.y;
  const unsigned short* base = CHB + (size_t)b * N * 512;
  const int tid = threadIdx.x;
  const int wave = tid >> 6, lane = tid & 63;
  f32x4 acc[2][8];
#pragma unroll
  for (int i = 0; i < 2; i++)
#pragma unroll
    for (int j = 0; j < 8; j++) acc[i][j] = (f32x4){0.f, 0.f, 0.f, 0.f};

  for (int k0 = 0; k0 < 512; k0 += 32) {
    stage_tile(base, ti * 128, N, k0, 512, At, tid);
    stage_tile(base, tj * 128, N, k0, 512, Bt, tid);
    __syncthreads();
    bf16x8 af[2];
#pragma unroll
    for (int rf = 0; rf < 2; rf++)
      af[rf] = frag(At, wave * 32 + rf * 16 + (lane & 15), lane >> 4);
#pragma unroll
    for (int cf = 0; cf < 8; cf++) {
      bf16x8 bf_ = frag(Bt, cf * 16 + (lane & 15), lane >> 4);
#pragma unroll
      for (int rf = 0; rf < 2; rf++)
        acc[rf][cf] = __builtin_amdgcn_mfma_f32_16x16x32_bf16(af[rf], bf_, acc[rf][cf], 0, 0, 0);
    }
    __syncthreads();
  }
  float* att = ATT + (size_t)b * N * N;
#pragma unroll
  for (int rf = 0; rf < 2; rf++)
#pragma unroll
    for (int cf = 0; cf < 8; cf++)
#pragma unroll
      for (int r4 = 0; r4 < 4; r4++) {
        int row = ti * 128 + wave * 32 + rf * 16 + ((lane >> 4) << 2) + r4;
        int col = tj * 128 + cf * 16 + (lane & 15);
        if (row < N && col < N) {
          float v = acc[rf][cf][r4];
          if (ACC) {
            att[(size_t)row * N + col] += v;
            if (ti != tj) att[(size_t)col * N + row] += v;
          } else {
            att[(size_t)row * N + col] = v;
            if (ti != tj) att[(size_t)col * N + row] = v;
          }
        }
      }
}

// -------- top-50 on s = G + q_m - q_n, softmax(s/8), flagging --------
// 256 thr bitonic. Element e always handled by thread e%256 (wave = bits 6-7).
// Writer of e in pass j = thread (e&~j)%256, so a pass touches OTHER waves' data
// only when j==64 or j==128. Exact rule: barrier before pass B iff j_B or the
// previous pass j_A is in {64,128}. 11 barriers vs 55. volatile blocks compiler
// caching; same-wave LDS ops are in-order.
__global__ __launch_bounds__(256) void k_topk(float* __restrict__ ATT, const double* __restrict__ qv,
                                              const float* __restrict__ INITA,
                                              int* __restrict__ fcnt, int* __restrict__ frow,
                                              int* __restrict__ fcw, int* __restrict__ fidx,
                                              float* __restrict__ fv32) {
  int row = blockIdx.x;  // b*N + n
  int n = row % N;
  int b = row / N;
  float* arow = ATT + (size_t)row * N;
  __shared__ unsigned long long keys_s[1024];
  volatile unsigned long long* keys = keys_s;
  __shared__ float outr[N];
  __shared__ float sred;
  __shared__ int s_slot, s_cw;
  int tid = threadIdx.x;
  double qn = qv[row];
  for (int i = tid; i < 1024; i += 256) {
    unsigned long long kk = 0xFFFFFFFFFFFFFFFFull;
    if (i < N) {
      float sv = (float)((double)arow[i] + qv[(size_t)b * N + i] - qn);
      unsigned u = __float_as_uint(sv);
      u ^= (u >> 31) ? 0xFFFFFFFFu : 0x80000000u;
      kk = ((unsigned long long)(~u) << 32) | (unsigned)i;
    }
    keys[i] = kk;
  }
  __syncthreads();
  bool prev_cross = false;
  for (int ksz = 2; ksz <= 1024; ksz <<= 1) {
    for (int j = ksz >> 1; j > 0; j >>= 1) {
      bool cross = (j == 64) || (j == 128);
      if (cross || prev_cross) __syncthreads();
      for (int t = tid; t < 1024; t += 256) {
        int ixj = t ^ j;
        if (ixj > t) {
          unsigned long long a = keys[t], bb = keys[ixj];
          bool up = ((t & ksz) == 0);
          if ((a > bb) == up) { keys[t] = bb; keys[ixj] = a; }
        }
      }
      prev_cross = cross;
    }
  }
  __syncthreads();  // final visibility for cross-wave reads below
  auto dec = [](unsigned long long kk) {
    unsigned y = ~(unsigned)(kk >> 32);
    unsigned u = (y & 0x80000000u) ? (y ^ 0x80000000u) : ~y;
    return __uint_as_float(u);
  };

  float v49 = dec(keys[49]);
  float v50v = dec(keys[50]);
  float FLAGW = 8e-3f + 2e-5f * fabsf(v49);   // s-units
  bool flag = (v50v >= v49 - FLAGW);
  if (flag) {
    if (tid == 0) {
      int cin = 0;
      for (int r = 0; r < 50; r++)
        if (dec(keys[r]) > v49 + FLAGW) cin++;
      int rhi = 50;
      while (rhi < 113) {
        float vv = dec(keys[rhi + 1]);
        if (vv >= v49 - FLAGW) rhi++; else break;
      }
      int w = rhi - cin + 1;
      if (w > CANDMAX) w = CANDMAX;
      if (cin + w < 50) w = 50 - cin;
      int slot = atomicAdd(fcnt, 1);
      frow[slot] = row;
      fcw[slot] = cin | (w << 8);
      s_slot = slot;
      s_cw = cin | (w << 8);
    }
    __syncthreads();
    int slot = s_slot;
    int tot = (s_cw & 255) + (s_cw >> 8);
    for (int r = tid; r < tot; r += 256) {
      unsigned long long kk = keys[r];
      fidx[(size_t)slot * WST + r] = (int)(unsigned)(kk & 0xFFFFFFFFull);
      fv32[(size_t)slot * WST + r] = dec(kk);
    }
    __syncthreads();
  }

  float vmax = dec(keys[0]);
  float e = 0.f;
  int myidx = 0;
  if (tid < TOPKK) {
    unsigned long long kk = keys[tid];
    myidx = (int)(unsigned)(kk & 0xFFFFFFFFull);
    e = expf((dec(kk) - vmax) * 0.125f);
  }
  float s = e;
  for (int off = 32; off > 0; off >>= 1) s += __shfl_down(s, off);
  if (tid == 0) sred = s;
  for (int m2 = tid; m2 < N; m2 += 256) outr[m2] = 0.2f * INITA[(size_t)n * N + m2];
  __syncthreads();
  if (tid < TOPKK) outr[myidx] = 0.2f * INITA[(size_t)n * N + myidx] + 0.8f * (e / sred);
  __syncthreads();
  for (int m2 = tid; m2 < N; m2 += 256) arow[m2] = outr[m2];
}

// -------- fixup: fv32 ranking + minimax mass-split at near-tied boundaries --------
__global__ __launch_bounds__(256) void k_fixup(float* __restrict__ ATT, const float* __restrict__ INITA,
                                               const int* __restrict__ fcnt, const int* __restrict__ frow,
                                               const int* __restrict__ fcw, const int* __restrict__ fidx,
                                               const float* __restrict__ fv32) {
  __shared__ double wts[56];
  __shared__ int mm[56];
  __shared__ int s_tot;
  int tid = threadIdx.x;
  int cnt = *fcnt;
  for (int slot = blockIdx.x; slot < cnt; slot += gridDim.x) {
    int row = frow[slot];
    int cw = fcw[slot];
    int cin = cw & 255, w = cw >> 8;
    int n = row % N;
    __syncthreads();
    if (tid == 0) {
      int need = 50 - cin;
      if (need > w) need = w;
      double cv[CANDMAX]; int cm[CANDMAX]; float cs[CANDMAX];
      for (int c = 0; c < w; c++) {
        float sv = fv32[(size_t)slot * WST + cin + c];
        cv[c] = (double)sv * 0.125;
        cm[c] = fidx[(size_t)slot * WST + cin + c];
        cs[c] = sv;
      }
      int ord[CANDMAX];
      for (int c = 0; c < w; c++) ord[c] = c;
      for (int a2 = 0; a2 < w; a2++) {
        int best = a2;
        for (int c2 = a2 + 1; c2 < w; c2++) {
          int i1 = ord[c2], i0 = ord[best];
          if (cv[i1] > cv[i0] || (cv[i1] == cv[i0] && cm[i1] < cm[i0])) best = c2;
        }
        int tswap = ord[a2]; ord[a2] = ord[best]; ord[best] = tswap;
      }
      double b_in = cv[ord[need - 1]];
      double b_out = (need < w) ? cv[ord[need]] : -1e300;
      const double DATT = 1e-3;
      double fac[56];
      int tot = 0;
      for (int r = 0; r < cin; r++) {
        wts[tot] = (double)fv32[(size_t)slot * WST + r];
        mm[tot] = fidx[(size_t)slot * WST + r];
        fac[tot++] = 1.0;
      }
      if (need == w || b_in - b_out > DATT) {
        for (int t3 = 0; t3 < need; t3++) {
          wts[tot] = (double)cs[ord[t3]];
          mm[tot] = cm[ord[t3]];
          fac[tot++] = 1.0;
        }
      } else {
        int gs = 0;
        while (gs < w && cv[ord[gs]] > b_in + DATT) gs++;
        int ge = w - 1;
        while (ge >= 0 && cv[ord[ge]] < b_out - DATT) ge--;
        double mid = 0.5 * (b_in + b_out);
        while (ge - gs + 1 > 3) {
          if (cv[ord[gs]] - mid >= mid - cv[ord[ge]]) gs++;
          else ge--;
        }
        int fullc = gs;
        int gcount = ge - gs + 1;
        int gneed = need - fullc;
        if (gneed < 0) gneed = 0;
        if (gneed > gcount) gneed = gcount;
        double frac = (gcount > 0) ? (double)gneed / (double)gcount : 0.0;
        for (int t3 = 0; t3 < fullc; t3++) {
          wts[tot] = (double)cs[ord[t3]];
          mm[tot] = cm[ord[t3]];
          fac[tot++] = 1.0;
        }
        for (int t3 = gs; t3 <= ge; t3++) {
          wts[tot] = (double)cs[ord[t3]];
          mm[tot] = cm[ord[t3]];
          fac[tot++] = frac;
        }
      }
      double vmax = -1e300;
      for (int r = 0; r < tot; r++)
        if (fac[r] > 0.0 && wts[r] > vmax) vmax = wts[r];
      double S = 0.0;
      for (int r = 0; r < tot; r++) {
        double e = fac[r] * exp((wts[r] - vmax) * 0.125);
        wts[r] = e;
        S += e;
      }
      double inv = 1.0 / S;
      for (int r = 0; r < tot; r++) wts[r] *= inv;
      s_tot = tot;
    }
    __syncthreads();
    int tot = s_tot;
    float* arow = ATT + (size_t)row * N;
    for (int m2 = tid; m2 < N; m2 += 256) arow[m2] = 0.2f * INITA[(size_t)n * N + m2];
    __syncthreads();
    if (tid < tot && wts[tid] > 0.0)
      arow[mm[tid]] = 0.2f * INITA[(size_t)n * N + mm[tid]] + 0.8f * (float)wts[tid];
    __syncthreads();
  }
}

// ---------------- GCN ----------------
__global__ void k_deg(const float* __restrict__ ADJ, float* __restrict__ DINV) {
  int t = blockIdx.x * 256 + threadIdx.x;
  if (t >= M) return;
  int b = t / N, i = t - b * N;
  const float* p = ADJ + (size_t)b * N * N + i;
  float s = 1.f;
  for (int j = 0; j < N; j++) s += p[(size_t)j * N];
  DINV[t] = rsqrtf(s);
}

template <int ACT>
__global__ __launch_bounds__(256) void k_spmm(const float* __restrict__ ADJ, const float* __restrict__ DINV,
                                              const float* __restrict__ XW, const float* __restrict__ bias,
                                              float* __restrict__ OUT, int F) {
  __shared__ float As[16][132];
  __shared__ float Ws[16][132];
  const int tid = threadIdx.x;
  const int i0 = blockIdx.x * 128;
  const int f0 = blockIdx.y * 128;
  const int b = blockIdx.z;
  const float* adj = ADJ + (size_t)b * N * N;
  const float* dv = DINV + b * N;
  const float* xw = XW + (size_t)b * N * F;
  const int ty = tid >> 4, tx = tid & 15;
  float acc[8][8];
#pragma unroll
  for (int i = 0; i < 8; i++)
#pragma unroll
    for (int j = 0; j < 8; j++) acc[i][j] = 0.f;

  for (int j0 = 0; j0 < N; j0 += 16) {
#pragma unroll
    for (int l = 0; l < 8; l++) {
      int idx = tid + l * 256;
      int r = idx >> 7, c = idx & 127;
      int j = j0 + r, i = i0 + c;
      float v = 0.f;
      if (j < N && i < N) {
        float dj = dv[j];
        v = adj[(size_t)j * N + i] * dj;
        if (i == j) v += dj;
      }
      As[r][c] = v;
      float w = 0.f;
      if (j < N) w = xw[(size_t)j * F + f0 + c];
      Ws[r][c] = w;
    }
    __syncthreads();
#pragma unroll
    for (int k = 0; k < 16; k++) {
      float a[8], bb[8];
      *reinterpret_cast<float4*>(&a[0]) = *reinterpret_cast<const float4*>(&As[k][ty * 8]);
      *reinterpret_cast<float4*>(&a[4]) = *reinterpret_cast<const float4*>(&As[k][ty * 8 + 4]);
      *reinterpret_cast<float4*>(&bb[0]) = *reinterpret_cast<const float4*>(&Ws[k][tx * 8]);
      *reinterpret_cast<float4*>(&bb[4]) = *reinterpret_cast<const float4*>(&Ws[k][tx * 8 + 4]);
#pragma unroll
      for (int i = 0; i < 8; i++)
#pragma unroll
        for (int j = 0; j < 8; j++) acc[i][j] = fmaf(a[i], bb[j], acc[i][j]);
    }
    __syncthreads();
  }
#pragma unroll
  for (int i = 0; i < 8; i++) {
    int row = i0 + ty * 8 + i;
    if (row >= N) continue;
    float di = dv[row];
#pragma unroll
    for (int j4 = 0; j4 < 2; j4++) {
      float4 v;
      float* vv = reinterpret_cast<float*>(&v);
#pragma unroll
      for (int j = 0; j < 4; j++) {
        float x = acc[i][j4 * 4 + j] * di + bias[f0 + tx * 8 + j4 * 4 + j];
        if (ACT == 2) x = fmaxf(x, 0.f);
        vv[j] = x;
      }
      *reinterpret_cast<float4*>(&OUT[((size_t)b * N + row) * F + f0 + tx * 8 + j4 * 4]) = v;
    }
  }
}

// ---------------- drug embed (fp32) ----------------
__global__ __launch_bounds__(256) void k_drug_l1(const float* __restrict__ d1, const float* __restrict__ d2,
                                                 const float* __restrict__ W, const float* __restrict__ bias,
                                                 float* __restrict__ T1) {
  __shared__ float row[DF];
  int blk = blockIdx.x;
  const float* dr = ((blk & 16) ? d2 : d1) + (size_t)(blk & 15) * DF;
  for (int i = threadIdx.x; i < DF; i += 256) row[i] = dr[i];
  __syncthreads();
  for (int e = threadIdx.x; e < 512; e += 256) {
    float s = bias[e];
    for (int k = 0; k < DF; k++) s = fmaf(row[k], W[(size_t)k * 512 + e], s);
    T1[(size_t)blk * 512 + e] = fmaxf(s, 0.f);
  }
}

__global__ __launch_bounds__(128) void k_drug_l2(const float* __restrict__ T1, const float* __restrict__ W,
                                                 const float* __restrict__ bias, const float* __restrict__ lg,
                                                 const float* __restrict__ lb, float* __restrict__ D) {
  __shared__ float row[512];
  __shared__ float red[4];
  int blk = blockIdx.x;
  int e = threadIdx.x;
  for (int i = e; i < 512; i += 128) row[i] = T1[(size_t)blk * 512 + i];
  __syncthreads();
  float s = bias[e];
  for (int k = 0; k < 512; k++) s = fmaf(row[k], W[k * 128 + e], s);
  float t = s;
  for (int off = 32; off > 0; off >>= 1) t += __shfl_down(t, off);
  if ((e & 63) == 0) red[e >> 6] = t;
  __syncthreads();
  float mean = (red[0] + red[1]) * (1.f / 128.f);
  float dd = s - mean;
  float wv = dd * dd;
  for (int off = 32; off > 0; off >>= 1) wv += __shfl_down(wv, off);
  if ((e & 63) == 0) red[2 + (e >> 6)] = wv;
  __syncthreads();
  float var = (red[2] + red[3]) * (1.f / 128.f);
  D[(size_t)blk * 128 + e] = dd * rsqrtf(var + 1e-5f) * lg[e] + lb[e];
}

// ---------------- head + decoder ----------------
__global__ void k_gemb(const float* __restrict__ NODE, float* __restrict__ GEMB) {
  int t = blockIdx.x * 256 + threadIdx.x;
  int b = t >> 7, f = t & 127;
  const float* p = NODE + (size_t)b * N * IB2 + f;
  float s = 0.f;
  for (int n2 = 0; n2 < N; n2++) s += p[(size_t)n2 * IB2];
  GEMB[t] = s * (1.f / (float)N);
}

__global__ void k_heads(const float* __restrict__ GEMB, const float* __restrict__ EPS,
                        float* __restrict__ out_mu, float* __restrict__ out_std, float* __restrict__ Z) {
  int t = blockIdx.x * 256 + threadIdx.x;
  int b = t >> 6, q = t & 63;
  float mu = GEMB[b * 128 + q];
  float xs = GEMB[b * 128 + 64 + q] - 64.f;
  float sp = (xs > 20.f) ? xs : log1pf(expf(xs));
  out_mu[t] = mu;
  out_std[t] = sp;
  Z[t] = mu + EPS[t] * sp;
}

__global__ __launch_bounds__(512) void k_dec1(const float* __restrict__ Z, const float* __restrict__ W1,
                                              const float* __restrict__ b1, const float* __restrict__ bg,
                                              const float* __restrict__ bb, float* __restrict__ DEC) {
  int f = threadIdx.x;
  float d[16];
  for (int b = 0; b < 16; b++) {
    float s = b1[f];
    for (int k = 0; k < 64; k++) s = fmaf(Z[b * 64 + k], W1[k * 512 + f], s);
    d[b] = s;
  }
  float m = 0.f;
  for (int b = 0; b < 16; b++) m += d[b];
  m *= (1.f / 16.f);
  float v = 0.f;
  for (int b = 0; b < 16; b++) { float t = d[b] - m; v += t * t; }
  v *= (1.f / 16.f);
  float sc = rsqrtf(v + 1e-5f) * bg[f];
  float sh = bb[f];
  for (int b = 0; b < 16; b++) {
    float x = (d[b] - m) * sc + sh;
    DEC[b * 512 + f] = fmaxf(x, 0.f);
  }
}

__global__ void k_dec2(const float* __restrict__ DEC, const float* __restrict__ W2,
                       const float* __restrict__ b2, float* __restrict__ X2) {
  int t = blockIdx.x * 256 + threadIdx.x;
  if (t >= M) return;
  int b = t / N, n2 = t - b * N;
  float s = b2[n2];
  const float* db = DEC + b * 512;
  for (int f = 0; f < 512; f++) s = fmaf(db[f], W2[(size_t)f * N + n2], s);
  X2[t] = fmaxf(s, 0.f);
}

}  // namespace

extern "C" void kernel_launch(void* const* d_in, const int* in_sizes, int n_in,
                              void* d_out, int out_size, void* d_ws, size_t ws_size,
                              hipStream_t stream) {
  const float* x1 = (const float*)d_in[0];
  const float* drug1 = (const float*)d_in[1];
  const float* drug2 = (const float*)d_in[2];
  const float* eps = (const float*)d_in[3];
  const int* ei = (const int*)d_in[4];
  const float* gate_W = (const float*)d_in[5];
  const float* gate_b = (const float*)d_in[6];
  const float* emb = (const float*)d_in[7];
  const float* encW1 = (const float*)d_in[8];
  const float* encb1 = (const float*)d_in[9];
  const float* encW2 = (const float*)d_in[10];
  const float* encb2 = (const float*)d_in[11];
  const float* netW1 = (const float*)d_in[12];
  const float* netb1 = (const float*)d_in[13];
  const float* netW2 = (const float*)d_in[14];
  const float* netb2 = (const float*)d_in[15];
  const float* ln_g = (const float*)d_in[16];
  const float* ln_b = (const float*)d_in[17];
  const float* feat_mask = (const float*)d_in[18];
  const float* W_sims = (const float*)d_in[19];
  const float* gcnW1 = (const float*)d_in[20];
  const float* gcnb1 = (const float*)d_in[21];
  const float* gcnW2 = (const float*)d_in[22];
  const float* gcnb2 = (const float*)d_in[23];
  const float* decW1 = (const float*)d_in[24];
  const float* decb1 = (const float*)d_in[25];
  const float* bn_g = (const float*)d_in[26];
  const float* bn_b = (const float*)d_in[27];
  const float* decW2 = (const float*)d_in[28];
  const float* decb2 = (const float*)d_in[29];
  (void)in_sizes; (void)n_in; (void)out_size; (void)ws_size;

  // Workspace layout (~192 MB)
  size_t o = 0;
  auto A = [&](size_t bytes) { char* p = (char*)d_ws + o; o += (bytes + 255) & ~(size_t)255; return p; };
  unsigned short* WTH = (unsigned short*)A((size_t)KATT * 256 * 2);  // 2 MB
  unsigned short* WTL = (unsigned short*)A((size_t)KATT * 256 * 2);  // 2 MB
  char* RBIG = A((size_t)64 * 1024 * 1024);                          // 64 MB
  float* Hb = (float*)A((size_t)M * 128 * 4);                        // 8 MB
  float* ADJ1 = (float*)A((size_t)B * N * N * 4);                    // 61 MB
  float* INITA = (float*)A((size_t)N * N * 4);                       // 3.8 MB
  float* RN2 = (float*)A((size_t)2 * M * 128 * 4);                   // 16 MB
  float* T1 = (float*)A(32 * 512 * 4);
  float* Dd32 = (float*)A(32 * 128 * 4);
  float* DINV = (float*)A(M * 4);
  float* GEMB = (float*)A(B * 128 * 4);
  float* Zb = (float*)A(B * 64 * 4);
  float* DEC = (float*)A(B * 512 * 4);
  int* fcnt = (int*)A(256);
  float* MU = (float*)A((size_t)B * KCH * 4);
  double* qv = (double*)A((size_t)M * 8);
  unsigned short* FUSH = (unsigned short*)A((size_t)M * 256 * 2);    // 8 MB
  unsigned short* FUSL = (unsigned short*)A((size_t)M * 256 * 2);    // 8 MB
  unsigned short* CHB = (unsigned short*)A((size_t)M * 512 * 2);     // 16 MB

  // RBIG unions (phases don't overlap)
  float* buf1 = (float*)RBIG;                                 // encoder: gate*emb (32 MB)
  float* buf2 = (float*)(RBIG + (size_t)32 * 1024 * 1024);    // encoder: h1 (32 MB)
  float* CH = (float*)RBIG;                                   // g-loop: hp chunk fp32 (30.6 MB)
  char* FLAGS = RBIG + (size_t)32 * 1024 * 1024;              // g-loop: flags (~15 MB)
  int* frow = (int*)FLAGS;
  int* fcw = (int*)(FLAGS + (size_t)M * 4);
  int* fidx = (int*)(FLAGS + (size_t)2 * M * 4);
  float* fv32 = (float*)(FLAGS + (size_t)2 * M * 4 + (size_t)M * WST * 4);
  float* XW = (float*)RBIG;                                   // GCN phase
  float* Tt = (float*)(RBIG + (size_t)32 * 1024 * 1024);      // GCN phase
  float* TW2 = RN2;
  float* NODE = RN2 + (size_t)M * 128;

  float* out = (float*)d_out;
  float* out_x2 = out;
  float* out_adj2 = out + M;
  float* out_mu = out + M + (size_t)B * N * N;
  float* out_std = out_mu + B * 64;

  k_wt<<<4096, 256, 0, stream>>>(W_sims, feat_mask, WTH, WTL);
  k_gate_emb<<<31296, 256, 0, stream>>>(x1, gate_W, gate_b, emb, buf1);
  k_gemm<1, true><<<dim3(123, 4), 256, 0, stream>>>(buf1, encW1, encb1, buf2, M, 512, 512, 512);
  k_gemm<0, true><<<dim3(123, 1), 256, 0, stream>>>(buf2, encW2, encb2, Hb, M, 512, 128, 128);
  k_drug_l1<<<32, 256, 0, stream>>>(drug1, drug2, netW1, netb1, T1);
  k_drug_l2<<<32, 128, 0, stream>>>(T1, netW2, netb2, ln_g, ln_b, Dd32);
  k_zero<<<(N * N + 255) / 256, 256, 0, stream>>>(INITA, N * N);
  k_scatter<<<(NEDGE + 255) / 256, 256, 0, stream>>>(ei, INITA);

  for (int g = 0; g < 2; g++) {
    float* att = (g == 0) ? ADJ1 : out_adj2;
    const float* DDg = Dd32 + (size_t)g * 16 * 128;
    hipMemsetAsync(fcnt, 0, 4, stream);
    hipMemsetAsync(qv, 0, (size_t)M * 8, stream);
    k_fus<<<15648, 256, 0, stream>>>(Hb, DDg, FUSH, FUSL);
    for (int c = 0; c < KATT / KCH; c++) {
      k_hp_mma<<<dim3(123, 4), 256, 0, stream>>>(FUSH, FUSL, WTH + (size_t)c * KCH * 256,
                                                 WTL + (size_t)c * KCH * 256, CH);
      k_mu<<<dim3(16, 16), 256, 0, stream>>>(CH, MU);
      k_centerq<<<M / 4, 256, 0, stream>>>(CH, MU, CHB, qv);
      if (c == 0)
        k_syrk_mma<false><<<dim3(36, 16), 256, 0, stream>>>(CHB, att);
      else
        k_syrk_mma<true><<<dim3(36, 16), 256, 0, stream>>>(CHB, att);
    }
    k_topk<<<M, 256, 0, stream>>>(att, qv, INITA, fcnt, frow, fcw, fidx, fv32);
    k_fixup<<<1024, 256, 0, stream>>>(att, INITA, fcnt, frow, fcw, fidx, fv32);
  }

  k_deg<<<(M + 255) / 256, 256, 0, stream>>>(ADJ1, DINV);
  k_gemm<0, false><<<dim3(123, 4), 256, 0, stream>>>(Hb, gcnW1, nullptr, XW, M, 128, 512, 512);
  k_spmm<2><<<dim3(8, 4, 16), 256, 0, stream>>>(ADJ1, DINV, XW, gcnb1, Tt, 512);
  k_gemm<0, false><<<dim3(123, 1), 256, 0, stream>>>(Tt, gcnW2, nullptr, TW2, M, 512, 128, 128);
  k_spmm<0><<<dim3(8, 1, 16), 256, 0, stream>>>(ADJ1, DINV, TW2, gcnb2, NODE, 128);
  k_gemb<<<8, 256, 0, stream>>>(NODE, GEMB);
  k_heads<<<4, 256, 0, stream>>>(GEMB, eps, out_mu, out_std, Zb);
  k_dec1<<<1, 512, 0, stream>>>(Zb, decW1, decb1, bn_g, bn_b, DEC);
  k_dec2<<<(M + 255) / 256, 256, 0, stream>>>(DEC, decW2, decb2, out_x2);
}

// Round 11
// 4973.518 us; speedup vs baseline: 1.4006x; 1.4006x over previous
//
#include <hip/hip_runtime.h>
#include <cmath>

namespace {

constexpr int B = 16;
constexpr int N = 978;
constexpr int M = B * N;          // 15648
constexpr int IB2 = 128;          // 2*IB
constexpr int KATT = 4096;        // P*HID
constexpr int KCH = 512;          // hp column chunk
constexpr int DF = 2304;
constexpr int TOPKK = 50;
constexpr int NEDGE = 50000;
constexpr int CANDMAX = 64;
constexpr int WST = 120;

typedef __attribute__((ext_vector_type(8))) short bf16x8;
typedef __attribute__((ext_vector_type(4))) float f32x4;

__device__ __forceinline__ float geluf(float x) {
  return 0.5f * x * (1.f + erff(x * 0.7071067811865476f));
}
__device__ __forceinline__ float sigm(float x) { return 1.f / (1.f + expf(-x)); }
__device__ __forceinline__ double sigm64(double x) { return 1.0 / (1.0 + exp(-x)); }

__device__ __forceinline__ unsigned short f2bf(float f) {
  union { float f; unsigned u; } x; x.f = f;
  unsigned r = (x.u + 0x7FFFu + ((x.u >> 16) & 1u)) >> 16;
  return (unsigned short)r;
}
__device__ __forceinline__ float bf2f(unsigned short s) {
  union { float f; unsigned u; } x; x.u = ((unsigned)s) << 16; return x.f;
}

// ---------------- WT build: (4096 x 256) bf16 hi/lo of W_sims^T * sigm(fm) ----------------
__global__ void k_wt(const float* __restrict__ wsims, const float* __restrict__ fm,
                     unsigned short* __restrict__ wth, unsigned short* __restrict__ wtl) {
  int t = blockIdx.x * 256 + threadIdx.x;   // < 4096*256 = 1048576 exact
  int n = t >> 8, k = t & 255;
  int p = n >> 9, h = n & 511;
  double v = (double)wsims[(size_t)p * 131072 + (size_t)k * 512 + h] * sigm64((double)fm[k]);
  float vf = (float)v;
  unsigned short hi = f2bf(vf);
  wth[t] = hi;
  wtl[t] = f2bf(vf - bf2f(hi));
}

// ---------------- FUS build: (M x 256) bf16 hi/lo of [Hb | DDg] ----------------
__global__ void k_fus(const float* __restrict__ Hb, const float* __restrict__ DD,
                      unsigned short* __restrict__ fh, unsigned short* __restrict__ fl) {
  int t = blockIdx.x * 256 + threadIdx.x;   // < M*256 exact
  int k = t & 255;
  int row = t >> 8;
  int b = row / N;
  float v = (k < 128) ? Hb[(size_t)row * 128 + k] : DD[(size_t)b * 128 + (k - 128)];
  unsigned short hi = f2bf(v);
  fh[t] = hi;
  fl[t] = f2bf(v - bf2f(hi));
}

__global__ void k_gate_emb(const float* __restrict__ x1, const float* __restrict__ gW,
                           const float* __restrict__ gb, const float* __restrict__ emb,
                           float* __restrict__ A) {
  size_t t = (size_t)blockIdx.x * 256 + threadIdx.x;  // < M*512 exact
  int e = (int)(t & 511);
  size_t bn = t >> 9;
  int n = (int)(bn % N);
  float g = sigm(x1[bn] * gW[e] + gb[e]);
  A[t] = g * emb[(size_t)n * 512 + e];
}

__global__ void k_zero(float* __restrict__ p, int n) {
  int t = blockIdx.x * 256 + threadIdx.x;
  if (t < n) p[t] = 0.f;
}

__global__ void k_scatter(const int* __restrict__ ei, float* __restrict__ adj) {
  int t = blockIdx.x * 256 + threadIdx.x;
  if (t < NEDGE) {
    int r = ei[t], c = ei[NEDGE + t];
    adj[(size_t)r * N + c] = 1.f;
  }
}

// ---------------- generic fp32 GEMM (encoder / GCN XW) ----------------
template <int ACT, bool HASBIAS>
__global__ __launch_bounds__(256) void k_gemm(const float* __restrict__ A,
                                              const float* __restrict__ W, const float* __restrict__ bias,
                                              float* __restrict__ C,
                                              int Mm, int K, int Nc, int ldw) {
  __shared__ float As[16][132];
  __shared__ float Ws[16][132];
  const int tid = threadIdx.x;
  const int m0 = blockIdx.x * 128;
  const int n0 = blockIdx.y * 128;
  const int ty = tid >> 4, tx = tid & 15;
  float acc[8][8];
#pragma unroll
  for (int i = 0; i < 8; i++)
#pragma unroll
    for (int j = 0; j < 8; j++) acc[i][j] = 0.f;

  for (int k0 = 0; k0 < K; k0 += 16) {
#pragma unroll
    for (int l = 0; l < 2; l++) {
      int idx4 = tid + l * 256;
      int r = idx4 >> 2, c4 = idx4 & 3;
      int row = m0 + r;
      float4 v = make_float4(0.f, 0.f, 0.f, 0.f);
      if (row < Mm) v = *reinterpret_cast<const float4*>(&A[(size_t)row * K + k0 + c4 * 4]);
      As[c4 * 4 + 0][r] = v.x;
      As[c4 * 4 + 1][r] = v.y;
      As[c4 * 4 + 2][r] = v.z;
      As[c4 * 4 + 3][r] = v.w;
    }
#pragma unroll
    for (int l = 0; l < 2; l++) {
      int idx4 = tid + l * 256;
      int r = idx4 >> 5, c4 = idx4 & 31;
      float4 v = *reinterpret_cast<const float4*>(&W[(size_t)(k0 + r) * ldw + n0 + c4 * 4]);
      *reinterpret_cast<float4*>(&Ws[r][c4 * 4]) = v;
    }
    __syncthreads();
#pragma unroll
    for (int k = 0; k < 16; k++) {
      float a[8], bb[8];
      *reinterpret_cast<float4*>(&a[0]) = *reinterpret_cast<const float4*>(&As[k][ty * 8]);
      *reinterpret_cast<float4*>(&a[4]) = *reinterpret_cast<const float4*>(&As[k][ty * 8 + 4]);
      *reinterpret_cast<float4*>(&bb[0]) = *reinterpret_cast<const float4*>(&Ws[k][tx * 8]);
      *reinterpret_cast<float4*>(&bb[4]) = *reinterpret_cast<const float4*>(&Ws[k][tx * 8 + 4]);
#pragma unroll
      for (int i = 0; i < 8; i++)
#pragma unroll
        for (int j = 0; j < 8; j++) acc[i][j] = fmaf(a[i], bb[j], acc[i][j]);
    }
    __syncthreads();
  }
#pragma unroll
  for (int i = 0; i < 8; i++) {
    int row = m0 + ty * 8 + i;
    if (row >= Mm) continue;
#pragma unroll
    for (int j4 = 0; j4 < 2; j4++) {
      float4 v;
      float* vv = reinterpret_cast<float*>(&v);
#pragma unroll
      for (int j = 0; j < 4; j++) {
        float x = acc[i][j4 * 4 + j];
        if (HASBIAS) x += bias[n0 + tx * 8 + j4 * 4 + j];
        if (ACT == 1) x = geluf(x);
        if (ACT == 2) x = fmaxf(x, 0.f);
        vv[j] = x;
      }
      *reinterpret_cast<float4*>(&C[(size_t)row * Nc + n0 + tx * 8 + j4 * 4]) = v;
    }
  }
}

// ------- MFMA staging: 128x32 bf16 tile, XOR-swizzled ((r&7)<<4 on 64B rows) -------
__device__ __forceinline__ void stage_tile(const unsigned short* __restrict__ gbase, int grow0,
                                           int rowmax, int k0, int ldk, char* lds, int tid) {
#pragma unroll
  for (int it = 0; it < 2; it++) {
    int r = (tid >> 2) + it * 64;
    int c8 = tid & 3;
    int gr = grow0 + r;
    uint4 v = make_uint4(0u, 0u, 0u, 0u);
    if (gr < rowmax) v = *reinterpret_cast<const uint4*>(&gbase[(size_t)gr * ldk + k0 + c8 * 8]);
    int off = (r * 64 + c8 * 16) ^ ((r & 7) << 4);
    *reinterpret_cast<uint4*>(lds + off) = v;
  }
}

__device__ __forceinline__ bf16x8 frag(const char* lds, int r, int k8) {
  int off = (r * 64 + k8 * 16) ^ ((r & 7) << 4);
  return *reinterpret_cast<const bf16x8*>(lds + off);
}

// ------- hp chunk GEMM, split-bf16 (fp32-equivalent): CH = relu(FUS @ WT_chunk^T) -------
__global__ __launch_bounds__(256) void k_hp_mma(const unsigned short* __restrict__ FH,
                                                const unsigned short* __restrict__ FL,
                                                const unsigned short* __restrict__ WTHc,
                                                const unsigned short* __restrict__ WTLc,
                                                float* __restrict__ CH) {
  __shared__ __align__(16) char Ah[8192];
  __shared__ __align__(16) char Al[8192];
  __shared__ __align__(16) char Bh[8192];
  __shared__ __align__(16) char Bl[8192];
  const int m0 = blockIdx.x * 128;
  const int n0 = blockIdx.y * 128;   // within chunk (512)
  const int tid = threadIdx.x;
  const int wave = tid >> 6, lane = tid & 63;
  f32x4 acc[2][8];
#pragma unroll
  for (int i = 0; i < 2; i++)
#pragma unroll
    for (int j = 0; j < 8; j++) acc[i][j] = (f32x4){0.f, 0.f, 0.f, 0.f};

  for (int k0 = 0; k0 < 256; k0 += 32) {
    stage_tile(FH, m0, M, k0, 256, Ah, tid);
    stage_tile(FL, m0, M, k0, 256, Al, tid);
    stage_tile(WTHc, n0, 512, k0, 256, Bh, tid);
    stage_tile(WTLc, n0, 512, k0, 256, Bl, tid);
    __syncthreads();
    bf16x8 ah[2], al[2];
#pragma unroll
    for (int rf = 0; rf < 2; rf++) {
      int r = wave * 32 + rf * 16 + (lane & 15);
      ah[rf] = frag(Ah, r, lane >> 4);
      al[rf] = frag(Al, r, lane >> 4);
    }
#pragma unroll
    for (int cf = 0; cf < 8; cf++) {
      int rB = cf * 16 + (lane & 15);
      bf16x8 bh = frag(Bh, rB, lane >> 4);
      bf16x8 bl = frag(Bl, rB, lane >> 4);
#pragma unroll
      for (int rf = 0; rf < 2; rf++) {
        acc[rf][cf] = __builtin_amdgcn_mfma_f32_16x16x32_bf16(ah[rf], bh, acc[rf][cf], 0, 0, 0);
        acc[rf][cf] = __builtin_amdgcn_mfma_f32_16x16x32_bf16(ah[rf], bl, acc[rf][cf], 0, 0, 0);
        acc[rf][cf] = __builtin_amdgcn_mfma_f32_16x16x32_bf16(al[rf], bh, acc[rf][cf], 0, 0, 0);
      }
    }
    __syncthreads();
  }
#pragma unroll
  for (int rf = 0; rf < 2; rf++)
#pragma unroll
    for (int cf = 0; cf < 8; cf++)
#pragma unroll
      for (int r4 = 0; r4 < 4; r4++) {
        int row = m0 + wave * 32 + rf * 16 + ((lane >> 4) << 2) + r4;
        int col = n0 + cf * 16 + (lane & 15);
        if (row < M) CH[(size_t)row * 512 + col] = fmaxf(acc[rf][cf][r4], 0.f);
      }
}

// ---------------- per-chunk column means (parallel, deterministic) ----------------
__global__ __launch_bounds__(256) void k_mu(const float* __restrict__ CH, float* __restrict__ MU) {
  __shared__ double red[8][33];
  int b = blockIdx.y, jg = blockIdx.x;
  int jloc = threadIdx.x & 31, s = threadIdx.x >> 5;
  int j = jg * 32 + jloc;
  const float* p = CH + (size_t)b * N * KCH + j;
  double acc = 0.0;
  for (int n = s; n < N; n += 8) acc += (double)p[(size_t)n * KCH];
  red[s][jloc] = acc;
  __syncthreads();
  if (s == 0) {
    double t = 0.0;
#pragma unroll
    for (int k = 0; k < 8; k++) t += red[k][jloc];
    MU[b * KCH + j] = (float)(t * (1.0 / (double)N));
  }
}

// ------- fused center+q: CHB = bf16(CH - MU); qv[r] += <MU[b], CH[r]> (f64) -------
__global__ __launch_bounds__(256) void k_centerq(const float* __restrict__ CH,
                                                 const float* __restrict__ MU,
                                                 unsigned short* __restrict__ CHB,
                                                 double* __restrict__ qv) {
  int r = blockIdx.x * 4 + (threadIdx.x >> 6);   // grid = M/4 = 3912 exact
  int lane = threadIdx.x & 63;
  int b = r / N;
  const float* row = CH + (size_t)r * KCH;
  const float* mu = MU + (size_t)b * KCH;
  int j0 = lane * 8;
  float4 v0 = *reinterpret_cast<const float4*>(&row[j0]);
  float4 v1 = *reinterpret_cast<const float4*>(&row[j0 + 4]);
  float4 m0 = *reinterpret_cast<const float4*>(&mu[j0]);
  float4 m1 = *reinterpret_cast<const float4*>(&mu[j0 + 4]);
  unsigned short cb[8];
  cb[0] = f2bf(v0.x - m0.x); cb[1] = f2bf(v0.y - m0.y);
  cb[2] = f2bf(v0.z - m0.z); cb[3] = f2bf(v0.w - m0.w);
  cb[4] = f2bf(v1.x - m1.x); cb[5] = f2bf(v1.y - m1.y);
  cb[6] = f2bf(v1.z - m1.z); cb[7] = f2bf(v1.w - m1.w);
  *reinterpret_cast<uint4*>(&CHB[(size_t)r * KCH + j0]) = *reinterpret_cast<uint4*>(cb);
  double q = (double)m0.x * v0.x + (double)m0.y * v0.y + (double)m0.z * v0.z + (double)m0.w * v0.w
           + (double)m1.x * v1.x + (double)m1.y * v1.y + (double)m1.z * v1.z + (double)m1.w * v1.w;
  for (int off = 32; off > 0; off >>= 1) q += __shfl_down(q, off);
  if (lane == 0) qv[r] += q;
}

// ------- centered Gram via bf16 MFMA: G[b] (+)= CHBc @ CHBc^T -------
template <bool ACC>
__global__ __launch_bounds__(256) void k_syrk_mma(const unsigned short* __restrict__ CHB,
                                                  float* __restrict__ ATT) {
  __shared__ __align__(16) char At[8192];
  __shared__ __align__(16) char Bt[8192];
  const int T = 8;
  int pr = blockIdx.x;
  int ti = 0, rem = pr;
  while (rem >= T - ti) { rem -= T - ti; ti++; }
  int tj = ti + rem;
  int b = blockIdx.y;
  const unsigned short* base = CHB + (size_t)b * N * 512;
  const int tid = threadIdx.x;
  const int wave = tid >> 6, lane = tid & 63;
  f32x4 acc[2][8];
#pragma unroll
  for (int i = 0; i < 2; i++)
#pragma unroll
    for (int j = 0; j < 8; j++) acc[i][j] = (f32x4){0.f, 0.f, 0.f, 0.f};

  for (int k0 = 0; k0 < 512; k0 += 32) {
    stage_tile(base, ti * 128, N, k0, 512, At, tid);
    stage_tile(base, tj * 128, N, k0, 512, Bt, tid);
    __syncthreads();
    bf16x8 af[2];
#pragma unroll
    for (int rf = 0; rf < 2; rf++)
      af[rf] = frag(At, wave * 32 + rf * 16 + (lane & 15), lane >> 4);
#pragma unroll
    for (int cf = 0; cf < 8; cf++) {
      bf16x8 bf_ = frag(Bt, cf * 16 + (lane & 15), lane >> 4);
#pragma unroll
      for (int rf = 0; rf < 2; rf++)
        acc[rf][cf] = __builtin_amdgcn_mfma_f32_16x16x32_bf16(af[rf], bf_, acc[rf][cf], 0, 0, 0);
    }
    __syncthreads();
  }
  float* att = ATT + (size_t)b * N * N;
#pragma unroll
  for (int rf = 0; rf < 2; rf++)
#pragma unroll
    for (int cf = 0; cf < 8; cf++)
#pragma unroll
      for (int r4 = 0; r4 < 4; r4++) {
        int row = ti * 128 + wave * 32 + rf * 16 + ((lane >> 4) << 2) + r4;
        int col = tj * 128 + cf * 16 + (lane & 15);
        if (row < N && col < N) {
          float v = acc[rf][cf][r4];
          if (ACC) {
            att[(size_t)row * N + col] += v;
            if (ti != tj) att[(size_t)col * N + row] += v;
          } else {
            att[(size_t)row * N + col] = v;
            if (ti != tj) att[(size_t)col * N + row] = v;
          }
        }
      }
}

// -------- top-50 on s = G + q_m - q_n, softmax(s/8), flagging --------
// Register-resident bitonic: 256 thr x 4 elements (e = tid + 256c, thread owns e%256).
// j>=256: same-thread register slots. j<=32: same-wave shfl_xor. j in {64,128}: LDS
// (write-all, barrier, read partner, barrier) -- 7 passes x 2 barriers vs 55.
// Identical comparison network to the full-barrier version -> bit-identical output.
__global__ __launch_bounds__(256) void k_topk(float* __restrict__ ATT, const double* __restrict__ qv,
                                              const float* __restrict__ INITA,
                                              int* __restrict__ fcnt, int* __restrict__ frow,
                                              int* __restrict__ fcw, int* __restrict__ fidx,
                                              float* __restrict__ fv32) {
  int row = blockIdx.x;  // b*N + n
  int n = row % N;
  int b = row / N;
  float* arow = ATT + (size_t)row * N;
  __shared__ unsigned long long keys[1024];
  __shared__ float outr[N];
  __shared__ float sred;
  __shared__ int s_slot, s_cw;
  int tid = threadIdx.x;
  double qn = qv[row];
  unsigned long long kreg[4];
#pragma unroll
  for (int c = 0; c < 4; c++) {
    int i = tid + 256 * c;
    unsigned long long kk = 0xFFFFFFFFFFFFFFFFull;
    if (i < N) {
      float sv = (float)((double)arow[i] + qv[(size_t)b * N + i] - qn);
      unsigned u = __float_as_uint(sv);
      u ^= (u >> 31) ? 0xFFFFFFFFu : 0x80000000u;
      kk = ((unsigned long long)(~u) << 32) | (unsigned)i;
    }
    kreg[c] = kk;
  }
  for (int ksz = 2; ksz <= 1024; ksz <<= 1) {
    for (int j = ksz >> 1; j > 0; j >>= 1) {
      if (j <= 32) {
        // same-wave: shuffle exchange
#pragma unroll
        for (int c = 0; c < 4; c++) {
          int e = tid + 256 * c;
          unsigned long long pk = __shfl_xor(kreg[c], j);
          bool takemin = (((e & j) == 0) == ((e & ksz) == 0));
          unsigned long long mn = kreg[c] < pk ? kreg[c] : pk;
          unsigned long long mx = kreg[c] < pk ? pk : kreg[c];
          kreg[c] = takemin ? mn : mx;
        }
      } else if (j >= 256) {
        // same-thread: register slots c and c^(j>>8)
        int sw = j >> 8;
#pragma unroll
        for (int c = 0; c < 4; c++) {
          if ((c & sw) == 0) {
            int e = tid + 256 * c;
            bool up = (e & ksz) == 0;
            unsigned long long a = kreg[c], b2 = kreg[c | sw];
            if ((a > b2) == up) { kreg[c] = b2; kreg[c | sw] = a; }
          }
        }
      } else {
        // j == 64 or 128: cross-wave via LDS
#pragma unroll
        for (int c = 0; c < 4; c++) keys[tid + 256 * c] = kreg[c];
        __syncthreads();
#pragma unroll
        for (int c = 0; c < 4; c++) {
          int e = tid + 256 * c;
          unsigned long long pk = keys[e ^ j];
          bool takemin = (((e & j) == 0) == ((e & ksz) == 0));
          unsigned long long mn = kreg[c] < pk ? kreg[c] : pk;
          unsigned long long mx = kreg[c] < pk ? pk : kreg[c];
          kreg[c] = takemin ? mn : mx;
        }
        __syncthreads();
      }
    }
  }
#pragma unroll
  for (int c = 0; c < 4; c++) keys[tid + 256 * c] = kreg[c];
  __syncthreads();
  auto dec = [](unsigned long long kk) {
    unsigned y = ~(unsigned)(kk >> 32);
    unsigned u = (y & 0x80000000u) ? (y ^ 0x80000000u) : ~y;
    return __uint_as_float(u);
  };

  float v49 = dec(keys[49]);
  float v50v = dec(keys[50]);
  float FLAGW = 8e-3f + 2e-5f * fabsf(v49);   // s-units
  bool flag = (v50v >= v49 - FLAGW);
  if (flag) {
    if (tid == 0) {
      int cin = 0;
      for (int r = 0; r < 50; r++)
        if (dec(keys[r]) > v49 + FLAGW) cin++;
      int rhi = 50;
      while (rhi < 113) {
        float vv = dec(keys[rhi + 1]);
        if (vv >= v49 - FLAGW) rhi++; else break;
      }
      int w = rhi - cin + 1;
      if (w > CANDMAX) w = CANDMAX;
      if (cin + w < 50) w = 50 - cin;
      int slot = atomicAdd(fcnt, 1);
      frow[slot] = row;
      fcw[slot] = cin | (w << 8);
      s_slot = slot;
      s_cw = cin | (w << 8);
    }
    __syncthreads();
    int slot = s_slot;
    int tot = (s_cw & 255) + (s_cw >> 8);
    for (int r = tid; r < tot; r += 256) {
      unsigned long long kk = keys[r];
      fidx[(size_t)slot * WST + r] = (int)(unsigned)(kk & 0xFFFFFFFFull);
      fv32[(size_t)slot * WST + r] = dec(kk);
    }
    __syncthreads();
  }

  float vmax = dec(keys[0]);
  float e = 0.f;
  int myidx = 0;
  if (tid < TOPKK) {
    unsigned long long kk = keys[tid];
    myidx = (int)(unsigned)(kk & 0xFFFFFFFFull);
    e = expf((dec(kk) - vmax) * 0.125f);
  }
  float s = e;
  for (int off = 32; off > 0; off >>= 1) s += __shfl_down(s, off);
  if (tid == 0) sred = s;
  for (int m2 = tid; m2 < N; m2 += 256) outr[m2] = 0.2f * INITA[(size_t)n * N + m2];
  __syncthreads();
  if (tid < TOPKK) outr[myidx] = 0.2f * INITA[(size_t)n * N + myidx] + 0.8f * (e / sred);
  __syncthreads();
  for (int m2 = tid; m2 < N; m2 += 256) arow[m2] = outr[m2];
}

// -------- fixup: fv32 ranking + minimax mass-split at near-tied boundaries --------
__global__ __launch_bounds__(256) void k_fixup(float* __restrict__ ATT, const float* __restrict__ INITA,
                                               const int* __restrict__ fcnt, const int* __restrict__ frow,
                                               const int* __restrict__ fcw, const int* __restrict__ fidx,
                                               const float* __restrict__ fv32) {
  __shared__ double wts[56];
  __shared__ int mm[56];
  __shared__ int s_tot;
  int tid = threadIdx.x;
  int cnt = *fcnt;
  for (int slot = blockIdx.x; slot < cnt; slot += gridDim.x) {
    int row = frow[slot];
    int cw = fcw[slot];
    int cin = cw & 255, w = cw >> 8;
    int n = row % N;
    __syncthreads();
    if (tid == 0) {
      int need = 50 - cin;
      if (need > w) need = w;
      double cv[CANDMAX]; int cm[CANDMAX]; float cs[CANDMAX];
      for (int c = 0; c < w; c++) {
        float sv = fv32[(size_t)slot * WST + cin + c];
        cv[c] = (double)sv * 0.125;
        cm[c] = fidx[(size_t)slot * WST + cin + c];
        cs[c] = sv;
      }
      int ord[CANDMAX];
      for (int c = 0; c < w; c++) ord[c] = c;
      for (int a2 = 0; a2 < w; a2++) {
        int best = a2;
        for (int c2 = a2 + 1; c2 < w; c2++) {
          int i1 = ord[c2], i0 = ord[best];
          if (cv[i1] > cv[i0] || (cv[i1] == cv[i0] && cm[i1] < cm[i0])) best = c2;
        }
        int tswap = ord[a2]; ord[a2] = ord[best]; ord[best] = tswap;
      }
      double b_in = cv[ord[need - 1]];
      double b_out = (need < w) ? cv[ord[need]] : -1e300;
      const double DATT = 1e-3;
      double fac[56];
      int tot = 0;
      for (int r = 0; r < cin; r++) {
        wts[tot] = (double)fv32[(size_t)slot * WST + r];
        mm[tot] = fidx[(size_t)slot * WST + r];
        fac[tot++] = 1.0;
      }
      if (need == w || b_in - b_out > DATT) {
        for (int t3 = 0; t3 < need; t3++) {
          wts[tot] = (double)cs[ord[t3]];
          mm[tot] = cm[ord[t3]];
          fac[tot++] = 1.0;
        }
      } else {
        int gs = 0;
        while (gs < w && cv[ord[gs]] > b_in + DATT) gs++;
        int ge = w - 1;
        while (ge >= 0 && cv[ord[ge]] < b_out - DATT) ge--;
        double mid = 0.5 * (b_in + b_out);
        while (ge - gs + 1 > 3) {
          if (cv[ord[gs]] - mid >= mid - cv[ord[ge]]) gs++;
          else ge--;
        }
        int fullc = gs;
        int gcount = ge - gs + 1;
        int gneed = need - fullc;
        if (gneed < 0) gneed = 0;
        if (gneed > gcount) gneed = gcount;
        double frac = (gcount > 0) ? (double)gneed / (double)gcount : 0.0;
        for (int t3 = 0; t3 < fullc; t3++) {
          wts[tot] = (double)cs[ord[t3]];
          mm[tot] = cm[ord[t3]];
          fac[tot++] = 1.0;
        }
        for (int t3 = gs; t3 <= ge; t3++) {
          wts[tot] = (double)cs[ord[t3]];
          mm[tot] = cm[ord[t3]];
          fac[tot++] = frac;
        }
      }
      double vmax = -1e300;
      for (int r = 0; r < tot; r++)
        if (fac[r] > 0.0 && wts[r] > vmax) vmax = wts[r];
      double S = 0.0;
      for (int r = 0; r < tot; r++) {
        double e = fac[r] * exp((wts[r] - vmax) * 0.125);
        wts[r] = e;
        S += e;
      }
      double inv = 1.0 / S;
      for (int r = 0; r < tot; r++) wts[r] *= inv;
      s_tot = tot;
    }
    __syncthreads();
    int tot = s_tot;
    float* arow = ATT + (size_t)row * N;
    for (int m2 = tid; m2 < N; m2 += 256) arow[m2] = 0.2f * INITA[(size_t)n * N + m2];
    __syncthreads();
    if (tid < tot && wts[tid] > 0.0)
      arow[mm[tid]] = 0.2f * INITA[(size_t)n * N + mm[tid]] + 0.8f * (float)wts[tid];
    __syncthreads();
  }
}

// ---------------- GCN ----------------
__global__ void k_deg(const float* __restrict__ ADJ, float* __restrict__ DINV) {
  int t = blockIdx.x * 256 + threadIdx.x;
  if (t >= M) return;
  int b = t / N, i = t - b * N;
  const float* p = ADJ + (size_t)b * N * N + i;
  float s = 1.f;
  for (int j = 0; j < N; j++) s += p[(size_t)j * N];
  DINV[t] = rsqrtf(s);
}

template <int ACT>
__global__ __launch_bounds__(256) void k_spmm(const float* __restrict__ ADJ, const float* __restrict__ DINV,
                                              const float* __restrict__ XW, const float* __restrict__ bias,
                                              float* __restrict__ OUT, int F) {
  __shared__ float As[16][132];
  __shared__ float Ws[16][132];
  const int tid = threadIdx.x;
  const int i0 = blockIdx.x * 128;
  const int f0 = blockIdx.y * 128;
  const int b = blockIdx.z;
  const float* adj = ADJ + (size_t)b * N * N;
  const float* dv = DINV + b * N;
  const float* xw = XW + (size_t)b * N * F;
  const int ty = tid >> 4, tx = tid & 15;
  float acc[8][8];
#pragma unroll
  for (int i = 0; i < 8; i++)
#pragma unroll
    for (int j = 0; j < 8; j++) acc[i][j] = 0.f;

  for (int j0 = 0; j0 < N; j0 += 16) {
#pragma unroll
    for (int l = 0; l < 8; l++) {
      int idx = tid + l * 256;
      int r = idx >> 7, c = idx & 127;
      int j = j0 + r, i = i0 + c;
      float v = 0.f;
      if (j < N && i < N) {
        float dj = dv[j];
        v = adj[(size_t)j * N + i] * dj;
        if (i == j) v += dj;
      }
      As[r][c] = v;
      float w = 0.f;
      if (j < N) w = xw[(size_t)j * F + f0 + c];
      Ws[r][c] = w;
    }
    __syncthreads();
#pragma unroll
    for (int k = 0; k < 16; k++) {
      float a[8], bb[8];
      *reinterpret_cast<float4*>(&a[0]) = *reinterpret_cast<const float4*>(&As[k][ty * 8]);
      *reinterpret_cast<float4*>(&a[4]) = *reinterpret_cast<const float4*>(&As[k][ty * 8 + 4]);
      *reinterpret_cast<float4*>(&bb[0]) = *reinterpret_cast<const float4*>(&Ws[k][tx * 8]);
      *reinterpret_cast<float4*>(&bb[4]) = *reinterpret_cast<const float4*>(&Ws[k][tx * 8 + 4]);
#pragma unroll
      for (int i = 0; i < 8; i++)
#pragma unroll
        for (int j = 0; j < 8; j++) acc[i][j] = fmaf(a[i], bb[j], acc[i][j]);
    }
    __syncthreads();
  }
#pragma unroll
  for (int i = 0; i < 8; i++) {
    int row = i0 + ty * 8 + i;
    if (row >= N) continue;
    float di = dv[row];
#pragma unroll
    for (int j4 = 0; j4 < 2; j4++) {
      float4 v;
      float* vv = reinterpret_cast<float*>(&v);
#pragma unroll
      for (int j = 0; j < 4; j++) {
        float x = acc[i][j4 * 4 + j] * di + bias[f0 + tx * 8 + j4 * 4 + j];
        if (ACT == 2) x = fmaxf(x, 0.f);
        vv[j] = x;
      }
      *reinterpret_cast<float4*>(&OUT[((size_t)b * N + row) * F + f0 + tx * 8 + j4 * 4]) = v;
    }
  }
}

// ---------------- drug embed (fp32) ----------------
__global__ __launch_bounds__(256) void k_drug_l1(const float* __restrict__ d1, const float* __restrict__ d2,
                                                 const float* __restrict__ W, const float* __restrict__ bias,
                                                 float* __restrict__ T1) {
  __shared__ float row[DF];
  int blk = blockIdx.x;
  const float* dr = ((blk & 16) ? d2 : d1) + (size_t)(blk & 15) * DF;
  for (int i = threadIdx.x; i < DF; i += 256) row[i] = dr[i];
  __syncthreads();
  for (int e = threadIdx.x; e < 512; e += 256) {
    float s = bias[e];
    for (int k = 0; k < DF; k++) s = fmaf(row[k], W[(size_t)k * 512 + e], s);
    T1[(size_t)blk * 512 + e] = fmaxf(s, 0.f);
  }
}

__global__ __launch_bounds__(128) void k_drug_l2(const float* __restrict__ T1, const float* __restrict__ W,
                                                 const float* __restrict__ bias, const float* __restrict__ lg,
                                                 const float* __restrict__ lb, float* __restrict__ D) {
  __shared__ float row[512];
  __shared__ float red[4];
  int blk = blockIdx.x;
  int e = threadIdx.x;
  for (int i = e; i < 512; i += 128) row[i] = T1[(size_t)blk * 512 + i];
  __syncthreads();
  float s = bias[e];
  for (int k = 0; k < 512; k++) s = fmaf(row[k], W[k * 128 + e], s);
  float t = s;
  for (int off = 32; off > 0; off >>= 1) t += __shfl_down(t, off);
  if ((e & 63) == 0) red[e >> 6] = t;
  __syncthreads();
  float mean = (red[0] + red[1]) * (1.f / 128.f);
  float dd = s - mean;
  float wv = dd * dd;
  for (int off = 32; off > 0; off >>= 1) wv += __shfl_down(wv, off);
  if ((e & 63) == 0) red[2 + (e >> 6)] = wv;
  __syncthreads();
  float var = (red[2] + red[3]) * (1.f / 128.f);
  D[(size_t)blk * 128 + e] = dd * rsqrtf(var + 1e-5f) * lg[e] + lb[e];
}

// ---------------- head + decoder ----------------
__global__ void k_gemb(const float* __restrict__ NODE, float* __restrict__ GEMB) {
  int t = blockIdx.x * 256 + threadIdx.x;
  int b = t >> 7, f = t & 127;
  const float* p = NODE + (size_t)b * N * IB2 + f;
  float s = 0.f;
  for (int n2 = 0; n2 < N; n2++) s += p[(size_t)n2 * IB2];
  GEMB[t] = s * (1.f / (float)N);
}

__global__ void k_heads(const float* __restrict__ GEMB, const float* __restrict__ EPS,
                        float* __restrict__ out_mu, float* __restrict__ out_std, float* __restrict__ Z) {
  int t = blockIdx.x * 256 + threadIdx.x;
  int b = t >> 6, q = t & 63;
  float mu = GEMB[b * 128 + q];
  float xs = GEMB[b * 128 + 64 + q] - 64.f;
  float sp = (xs > 20.f) ? xs : log1pf(expf(xs));
  out_mu[t] = mu;
  out_std[t] = sp;
  Z[t] = mu + EPS[t] * sp;
}

__global__ __launch_bounds__(512) void k_dec1(const float* __restrict__ Z, const float* __restrict__ W1,
                                              const float* __restrict__ b1, const float* __restrict__ bg,
                                              const float* __restrict__ bb, float* __restrict__ DEC) {
  int f = threadIdx.x;
  float d[16];
  for (int b = 0; b < 16; b++) {
    float s = b1[f];
    for (int k = 0; k < 64; k++) s = fmaf(Z[b * 64 + k], W1[k * 512 + f], s);
    d[b] = s;
  }
  float m = 0.f;
  for (int b = 0; b < 16; b++) m += d[b];
  m *= (1.f / 16.f);
  float v = 0.f;
  for (int b = 0; b < 16; b++) { float t = d[b] - m; v += t * t; }
  v *= (1.f / 16.f);
  float sc = rsqrtf(v + 1e-5f) * bg[f];
  float sh = bb[f];
  for (int b = 0; b < 16; b++) {
    float x = (d[b] - m) * sc + sh;
    DEC[b * 512 + f] = fmaxf(x, 0.f);
  }
}

__global__ void k_dec2(const float* __restrict__ DEC, const float* __restrict__ W2,
                       const float* __restrict__ b2, float* __restrict__ X2) {
  int t = blockIdx.x * 256 + threadIdx.x;
  if (t >= M) return;
  int b = t / N, n2 = t - b * N;
  float s = b2[n2];
  const float* db = DEC + b * 512;
  for (int f = 0; f < 512; f++) s = fmaf(db[f], W2[(size_t)f * N + n2], s);
  X2[t] = fmaxf(s, 0.f);
}

}  // namespace

extern "C" void kernel_launch(void* const* d_in, const int* in_sizes, int n_in,
                              void* d_out, int out_size, void* d_ws, size_t ws_size,
                              hipStream_t stream) {
  const float* x1 = (const float*)d_in[0];
  const float* drug1 = (const float*)d_in[1];
  const float* drug2 = (const float*)d_in[2];
  const float* eps = (const float*)d_in[3];
  const int* ei = (const int*)d_in[4];
  const float* gate_W = (const float*)d_in[5];
  const float* gate_b = (const float*)d_in[6];
  const float* emb = (const float*)d_in[7];
  const float* encW1 = (const float*)d_in[8];
  const float* encb1 = (const float*)d_in[9];
  const float* encW2 = (const float*)d_in[10];
  const float* encb2 = (const float*)d_in[11];
  const float* netW1 = (const float*)d_in[12];
  const float* netb1 = (const float*)d_in[13];
  const float* netW2 = (const float*)d_in[14];
  const float* netb2 = (const float*)d_in[15];
  const float* ln_g = (const float*)d_in[16];
  const float* ln_b = (const float*)d_in[17];
  const float* feat_mask = (const float*)d_in[18];
  const float* W_sims = (const float*)d_in[19];
  const float* gcnW1 = (const float*)d_in[20];
  const float* gcnb1 = (const float*)d_in[21];
  const float* gcnW2 = (const float*)d_in[22];
  const float* gcnb2 = (const float*)d_in[23];
  const float* decW1 = (const float*)d_in[24];
  const float* decb1 = (const float*)d_in[25];
  const float* bn_g = (const float*)d_in[26];
  const float* bn_b = (const float*)d_in[27];
  const float* decW2 = (const float*)d_in[28];
  const float* decb2 = (const float*)d_in[29];
  (void)in_sizes; (void)n_in; (void)out_size; (void)ws_size;

  // Workspace layout (~192 MB)
  size_t o = 0;
  auto A = [&](size_t bytes) { char* p = (char*)d_ws + o; o += (bytes + 255) & ~(size_t)255; return p; };
  unsigned short* WTH = (unsigned short*)A((size_t)KATT * 256 * 2);  // 2 MB
  unsigned short* WTL = (unsigned short*)A((size_t)KATT * 256 * 2);  // 2 MB
  char* RBIG = A((size_t)64 * 1024 * 1024);                          // 64 MB
  float* Hb = (float*)A((size_t)M * 128 * 4);                        // 8 MB
  float* ADJ1 = (float*)A((size_t)B * N * N * 4);                    // 61 MB
  float* INITA = (float*)A((size_t)N * N * 4);                       // 3.8 MB
  float* RN2 = (float*)A((size_t)2 * M * 128 * 4);                   // 16 MB
  float* T1 = (float*)A(32 * 512 * 4);
  float* Dd32 = (float*)A(32 * 128 * 4);
  float* DINV = (float*)A(M * 4);
  float* GEMB = (float*)A(B * 128 * 4);
  float* Zb = (float*)A(B * 64 * 4);
  float* DEC = (float*)A(B * 512 * 4);
  int* fcnt = (int*)A(256);
  float* MU = (float*)A((size_t)B * KCH * 4);
  double* qv = (double*)A((size_t)M * 8);
  unsigned short* FUSH = (unsigned short*)A((size_t)M * 256 * 2);    // 8 MB
  unsigned short* FUSL = (unsigned short*)A((size_t)M * 256 * 2);    // 8 MB
  unsigned short* CHB = (unsigned short*)A((size_t)M * 512 * 2);     // 16 MB

  // RBIG unions (phases don't overlap)
  float* buf1 = (float*)RBIG;                                 // encoder: gate*emb (32 MB)
  float* buf2 = (float*)(RBIG + (size_t)32 * 1024 * 1024);    // encoder: h1 (32 MB)
  float* CH = (float*)RBIG;                                   // g-loop: hp chunk fp32 (30.6 MB)
  char* FLAGS = RBIG + (size_t)32 * 1024 * 1024;              // g-loop: flags (~15 MB)
  int* frow = (int*)FLAGS;
  int* fcw = (int*)(FLAGS + (size_t)M * 4);
  int* fidx = (int*)(FLAGS + (size_t)2 * M * 4);
  float* fv32 = (float*)(FLAGS + (size_t)2 * M * 4 + (size_t)M * WST * 4);
  float* XW = (float*)RBIG;                                   // GCN phase
  float* Tt = (float*)(RBIG + (size_t)32 * 1024 * 1024);      // GCN phase
  float* TW2 = RN2;
  float* NODE = RN2 + (size_t)M * 128;

  float* out = (float*)d_out;
  float* out_x2 = out;
  float* out_adj2 = out + M;
  float* out_mu = out + M + (size_t)B * N * N;
  float* out_std = out_mu + B * 64;

  k_wt<<<4096, 256, 0, stream>>>(W_sims, feat_mask, WTH, WTL);
  k_gate_emb<<<31296, 256, 0, stream>>>(x1, gate_W, gate_b, emb, buf1);
  k_gemm<1, true><<<dim3(123, 4), 256, 0, stream>>>(buf1, encW1, encb1, buf2, M, 512, 512, 512);
  k_gemm<0, true><<<dim3(123, 1), 256, 0, stream>>>(buf2, encW2, encb2, Hb, M, 512, 128, 128);
  k_drug_l1<<<32, 256, 0, stream>>>(drug1, drug2, netW1, netb1, T1);
  k_drug_l2<<<32, 128, 0, stream>>>(T1, netW2, netb2, ln_g, ln_b, Dd32);
  k_zero<<<(N * N + 255) / 256, 256, 0, stream>>>(INITA, N * N);
  k_scatter<<<(NEDGE + 255) / 256, 256, 0, stream>>>(ei, INITA);

  for (int g = 0; g < 2; g++) {
    float* att = (g == 0) ? ADJ1 : out_adj2;
    const float* DDg = Dd32 + (size_t)g * 16 * 128;
    hipMemsetAsync(fcnt, 0, 4, stream);
    hipMemsetAsync(qv, 0, (size_t)M * 8, stream);
    k_fus<<<15648, 256, 0, stream>>>(Hb, DDg, FUSH, FUSL);
    for (int c = 0; c < KATT / KCH; c++) {
      k_hp_mma<<<dim3(123, 4), 256, 0, stream>>>(FUSH, FUSL, WTH + (size_t)c * KCH * 256,
                                                 WTL + (size_t)c * KCH * 256, CH);
      k_mu<<<dim3(16, 16), 256, 0, stream>>>(CH, MU);
      k_centerq<<<M / 4, 256, 0, stream>>>(CH, MU, CHB, qv);
      if (c == 0)
        k_syrk_mma<false><<<dim3(36, 16), 256, 0, stream>>>(CHB, att);
      else
        k_syrk_mma<true><<<dim3(36, 16), 256, 0, stream>>>(CHB, att);
    }
    k_topk<<<M, 256, 0, stream>>>(att, qv, INITA, fcnt, frow, fcw, fidx, fv32);
    k_fixup<<<1024, 256, 0, stream>>>(att, INITA, fcnt, frow, fcw, fidx, fv32);
  }

  k_deg<<<(M + 255) / 256, 256, 0, stream>>>(ADJ1, DINV);
  k_gemm<0, false><<<dim3(123, 4), 256, 0, stream>>>(Hb, gcnW1, nullptr, XW, M, 128, 512, 512);
  k_spmm<2><<<dim3(8, 4, 16), 256, 0, stream>>>(ADJ1, DINV, XW, gcnb1, Tt, 512);
  k_gemm<0, false><<<dim3(123, 1), 256, 0, stream>>>(Tt, gcnW2, nullptr, TW2, M, 512, 128, 128);
  k_spmm<0><<<dim3(8, 1, 16), 256, 0, stream>>>(ADJ1, DINV, TW2, gcnb2, NODE, 128);
  k_gemb<<<8, 256, 0, stream>>>(NODE, GEMB);
  k_heads<<<4, 256, 0, stream>>>(GEMB, eps, out_mu, out_std, Zb);
  k_dec1<<<1, 512, 0, stream>>>(Zb, decW1, decb1, bn_g, bn_b, DEC);
  k_dec2<<<(M + 255) / 256, 256, 0, stream>>>(DEC, decW2, decb2, out_x2);
}

// Round 12
// 4276.903 us; speedup vs baseline: 1.6287x; 1.1629x over previous
//
#include <hip/hip_runtime.h>
#include <cmath>

namespace {

constexpr int B = 16;
constexpr int N = 978;
constexpr int M = B * N;          // 15648
constexpr int IB2 = 128;          // 2*IB
constexpr int KATT = 4096;        // P*HID
constexpr int KCH = 1024;         // hp column chunk (1024: halves ATT RMW passes)
constexpr int NCH = KATT / KCH;   // 4
constexpr int DF = 2304;
constexpr int TOPKK = 50;
constexpr int NEDGE = 50000;
constexpr int CANDMAX = 64;
constexpr int WST = 120;

typedef __attribute__((ext_vector_type(8))) short bf16x8;
typedef __attribute__((ext_vector_type(4))) float f32x4;

__device__ __forceinline__ float geluf(float x) {
  return 0.5f * x * (1.f + erff(x * 0.7071067811865476f));
}
__device__ __forceinline__ float sigm(float x) { return 1.f / (1.f + expf(-x)); }
__device__ __forceinline__ double sigm64(double x) { return 1.0 / (1.0 + exp(-x)); }

__device__ __forceinline__ unsigned short f2bf(float f) {
  union { float f; unsigned u; } x; x.f = f;
  unsigned r = (x.u + 0x7FFFu + ((x.u >> 16) & 1u)) >> 16;
  return (unsigned short)r;
}
__device__ __forceinline__ float bf2f(unsigned short s) {
  union { float f; unsigned u; } x; x.u = ((unsigned)s) << 16; return x.f;
}

// ---------------- WT build: (4096 x 256) bf16 hi/lo of W_sims^T * sigm(fm) ----------------
__global__ void k_wt(const float* __restrict__ wsims, const float* __restrict__ fm,
                     unsigned short* __restrict__ wth, unsigned short* __restrict__ wtl) {
  int t = blockIdx.x * 256 + threadIdx.x;   // < 4096*256 = 1048576 exact
  int n = t >> 8, k = t & 255;
  int p = n >> 9, h = n & 511;
  double v = (double)wsims[(size_t)p * 131072 + (size_t)k * 512 + h] * sigm64((double)fm[k]);
  float vf = (float)v;
  unsigned short hi = f2bf(vf);
  wth[t] = hi;
  wtl[t] = f2bf(vf - bf2f(hi));
}

// ---------------- FUS build: (M x 256) bf16 hi/lo of [Hb | DDg] ----------------
__global__ void k_fus(const float* __restrict__ Hb, const float* __restrict__ DD,
                      unsigned short* __restrict__ fh, unsigned short* __restrict__ fl) {
  int t = blockIdx.x * 256 + threadIdx.x;   // < M*256 exact
  int k = t & 255;
  int row = t >> 8;
  int b = row / N;
  float v = (k < 128) ? Hb[(size_t)row * 128 + k] : DD[(size_t)b * 128 + (k - 128)];
  unsigned short hi = f2bf(v);
  fh[t] = hi;
  fl[t] = f2bf(v - bf2f(hi));
}

__global__ void k_gate_emb(const float* __restrict__ x1, const float* __restrict__ gW,
                           const float* __restrict__ gb, const float* __restrict__ emb,
                           float* __restrict__ A) {
  size_t t = (size_t)blockIdx.x * 256 + threadIdx.x;  // < M*512 exact
  int e = (int)(t & 511);
  size_t bn = t >> 9;
  int n = (int)(bn % N);
  float g = sigm(x1[bn] * gW[e] + gb[e]);
  A[t] = g * emb[(size_t)n * 512 + e];
}

__global__ void k_zero(float* __restrict__ p, int n) {
  int t = blockIdx.x * 256 + threadIdx.x;
  if (t < n) p[t] = 0.f;
}

__global__ void k_scatter(const int* __restrict__ ei, float* __restrict__ adj) {
  int t = blockIdx.x * 256 + threadIdx.x;
  if (t < NEDGE) {
    int r = ei[t], c = ei[NEDGE + t];
    adj[(size_t)r * N + c] = 1.f;
  }
}

// ---------------- generic fp32 GEMM (encoder / GCN XW) ----------------
template <int ACT, bool HASBIAS>
__global__ __launch_bounds__(256) void k_gemm(const float* __restrict__ A,
                                              const float* __restrict__ W, const float* __restrict__ bias,
                                              float* __restrict__ C,
                                              int Mm, int K, int Nc, int ldw) {
  __shared__ float As[16][132];
  __shared__ float Ws[16][132];
  const int tid = threadIdx.x;
  const int m0 = blockIdx.x * 128;
  const int n0 = blockIdx.y * 128;
  const int ty = tid >> 4, tx = tid & 15;
  float acc[8][8];
#pragma unroll
  for (int i = 0; i < 8; i++)
#pragma unroll
    for (int j = 0; j < 8; j++) acc[i][j] = 0.f;

  for (int k0 = 0; k0 < K; k0 += 16) {
#pragma unroll
    for (int l = 0; l < 2; l++) {
      int idx4 = tid + l * 256;
      int r = idx4 >> 2, c4 = idx4 & 3;
      int row = m0 + r;
      float4 v = make_float4(0.f, 0.f, 0.f, 0.f);
      if (row < Mm) v = *reinterpret_cast<const float4*>(&A[(size_t)row * K + k0 + c4 * 4]);
      As[c4 * 4 + 0][r] = v.x;
      As[c4 * 4 + 1][r] = v.y;
      As[c4 * 4 + 2][r] = v.z;
      As[c4 * 4 + 3][r] = v.w;
    }
#pragma unroll
    for (int l = 0; l < 2; l++) {
      int idx4 = tid + l * 256;
      int r = idx4 >> 5, c4 = idx4 & 31;
      float4 v = *reinterpret_cast<const float4*>(&W[(size_t)(k0 + r) * ldw + n0 + c4 * 4]);
      *reinterpret_cast<float4*>(&Ws[r][c4 * 4]) = v;
    }
    __syncthreads();
#pragma unroll
    for (int k = 0; k < 16; k++) {
      float a[8], bb[8];
      *reinterpret_cast<float4*>(&a[0]) = *reinterpret_cast<const float4*>(&As[k][ty * 8]);
      *reinterpret_cast<float4*>(&a[4]) = *reinterpret_cast<const float4*>(&As[k][ty * 8 + 4]);
      *reinterpret_cast<float4*>(&bb[0]) = *reinterpret_cast<const float4*>(&Ws[k][tx * 8]);
      *reinterpret_cast<float4*>(&bb[4]) = *reinterpret_cast<const float4*>(&Ws[k][tx * 8 + 4]);
#pragma unroll
      for (int i = 0; i < 8; i++)
#pragma unroll
        for (int j = 0; j < 8; j++) acc[i][j] = fmaf(a[i], bb[j], acc[i][j]);
    }
    __syncthreads();
  }
#pragma unroll
  for (int i = 0; i < 8; i++) {
    int row = m0 + ty * 8 + i;
    if (row >= Mm) continue;
#pragma unroll
    for (int j4 = 0; j4 < 2; j4++) {
      float4 v;
      float* vv = reinterpret_cast<float*>(&v);
#pragma unroll
      for (int j = 0; j < 4; j++) {
        float x = acc[i][j4 * 4 + j];
        if (HASBIAS) x += bias[n0 + tx * 8 + j4 * 4 + j];
        if (ACT == 1) x = geluf(x);
        if (ACT == 2) x = fmaxf(x, 0.f);
        vv[j] = x;
      }
      *reinterpret_cast<float4*>(&C[(size_t)row * Nc + n0 + tx * 8 + j4 * 4]) = v;
    }
  }
}

// ------- MFMA staging: 128x32 bf16 tile, XOR-swizzled ((r&7)<<4 on 64B rows) -------
__device__ __forceinline__ void stage_tile(const unsigned short* __restrict__ gbase, int grow0,
                                           int rowmax, int k0, int ldk, char* lds, int tid) {
#pragma unroll
  for (int it = 0; it < 2; it++) {
    int r = (tid >> 2) + it * 64;
    int c8 = tid & 3;
    int gr = grow0 + r;
    uint4 v = make_uint4(0u, 0u, 0u, 0u);
    if (gr < rowmax) v = *reinterpret_cast<const uint4*>(&gbase[(size_t)gr * ldk + k0 + c8 * 8]);
    int off = (r * 64 + c8 * 16) ^ ((r & 7) << 4);
    *reinterpret_cast<uint4*>(lds + off) = v;
  }
}

__device__ __forceinline__ bf16x8 frag(const char* lds, int r, int k8) {
  int off = (r * 64 + k8 * 16) ^ ((r & 7) << 4);
  return *reinterpret_cast<const bf16x8*>(lds + off);
}

// ------- hp chunk GEMM, split-bf16 (fp32-equivalent): CH = relu(FUS @ WT_chunk^T) -------
__global__ __launch_bounds__(256) void k_hp_mma(const unsigned short* __restrict__ FH,
                                                const unsigned short* __restrict__ FL,
                                                const unsigned short* __restrict__ WTHc,
                                                const unsigned short* __restrict__ WTLc,
                                                float* __restrict__ CH) {
  __shared__ __align__(16) char Ah[8192];
  __shared__ __align__(16) char Al[8192];
  __shared__ __align__(16) char Bh[8192];
  __shared__ __align__(16) char Bl[8192];
  const int m0 = blockIdx.x * 128;
  const int n0 = blockIdx.y * 128;   // within chunk (KCH)
  const int tid = threadIdx.x;
  const int wave = tid >> 6, lane = tid & 63;
  f32x4 acc[2][8];
#pragma unroll
  for (int i = 0; i < 2; i++)
#pragma unroll
    for (int j = 0; j < 8; j++) acc[i][j] = (f32x4){0.f, 0.f, 0.f, 0.f};

  for (int k0 = 0; k0 < 256; k0 += 32) {
    stage_tile(FH, m0, M, k0, 256, Ah, tid);
    stage_tile(FL, m0, M, k0, 256, Al, tid);
    stage_tile(WTHc, n0, KCH, k0, 256, Bh, tid);
    stage_tile(WTLc, n0, KCH, k0, 256, Bl, tid);
    __syncthreads();
    bf16x8 ah[2], al[2];
#pragma unroll
    for (int rf = 0; rf < 2; rf++) {
      int r = wave * 32 + rf * 16 + (lane & 15);
      ah[rf] = frag(Ah, r, lane >> 4);
      al[rf] = frag(Al, r, lane >> 4);
    }
#pragma unroll
    for (int cf = 0; cf < 8; cf++) {
      int rB = cf * 16 + (lane & 15);
      bf16x8 bh = frag(Bh, rB, lane >> 4);
      bf16x8 bl = frag(Bl, rB, lane >> 4);
#pragma unroll
      for (int rf = 0; rf < 2; rf++) {
        acc[rf][cf] = __builtin_amdgcn_mfma_f32_16x16x32_bf16(ah[rf], bh, acc[rf][cf], 0, 0, 0);
        acc[rf][cf] = __builtin_amdgcn_mfma_f32_16x16x32_bf16(ah[rf], bl, acc[rf][cf], 0, 0, 0);
        acc[rf][cf] = __builtin_amdgcn_mfma_f32_16x16x32_bf16(al[rf], bh, acc[rf][cf], 0, 0, 0);
      }
    }
    __syncthreads();
  }
#pragma unroll
  for (int rf = 0; rf < 2; rf++)
#pragma unroll
    for (int cf = 0; cf < 8; cf++)
#pragma unroll
      for (int r4 = 0; r4 < 4; r4++) {
        int row = m0 + wave * 32 + rf * 16 + ((lane >> 4) << 2) + r4;
        int col = n0 + cf * 16 + (lane & 15);
        if (row < M) CH[(size_t)row * KCH + col] = fmaxf(acc[rf][cf][r4], 0.f);
      }
}

// ---------------- per-chunk column means (parallel, deterministic) ----------------
// grid: dim3(KCH/32, 16); 256 thr = 32 j-lanes x 8 n-splits
__global__ __launch_bounds__(256) void k_mu(const float* __restrict__ CH, float* __restrict__ MU) {
  __shared__ double red[8][33];
  int b = blockIdx.y, jg = blockIdx.x;
  int jloc = threadIdx.x & 31, s = threadIdx.x >> 5;
  int j = jg * 32 + jloc;
  const float* p = CH + (size_t)b * N * KCH + j;
  double acc = 0.0;
  for (int n = s; n < N; n += 8) acc += (double)p[(size_t)n * KCH];
  red[s][jloc] = acc;
  __syncthreads();
  if (s == 0) {
    double t = 0.0;
#pragma unroll
    for (int k = 0; k < 8; k++) t += red[k][jloc];
    MU[b * KCH + j] = (float)(t * (1.0 / (double)N));
  }
}

// ------- fused center+q: CHB = bf16(CH - MU); qv[r] += <MU[b], CH[r]> (f64) -------
// one wave per row; lane covers 8 contiguous cols, 2 passes for KCH=1024
__global__ __launch_bounds__(256) void k_centerq(const float* __restrict__ CH,
                                                 const float* __restrict__ MU,
                                                 unsigned short* __restrict__ CHB,
                                                 double* __restrict__ qv) {
  int r = blockIdx.x * 4 + (threadIdx.x >> 6);   // grid = M/4 = 3912 exact
  int lane = threadIdx.x & 63;
  int b = r / N;
  const float* row = CH + (size_t)r * KCH;
  const float* mu = MU + (size_t)b * KCH;
  double q = 0.0;
#pragma unroll
  for (int jp = 0; jp < 2; jp++) {
    int j0 = lane * 8 + jp * 512;
    float4 v0 = *reinterpret_cast<const float4*>(&row[j0]);
    float4 v1 = *reinterpret_cast<const float4*>(&row[j0 + 4]);
    float4 m0 = *reinterpret_cast<const float4*>(&mu[j0]);
    float4 m1 = *reinterpret_cast<const float4*>(&mu[j0 + 4]);
    unsigned short cb[8];
    cb[0] = f2bf(v0.x - m0.x); cb[1] = f2bf(v0.y - m0.y);
    cb[2] = f2bf(v0.z - m0.z); cb[3] = f2bf(v0.w - m0.w);
    cb[4] = f2bf(v1.x - m1.x); cb[5] = f2bf(v1.y - m1.y);
    cb[6] = f2bf(v1.z - m1.z); cb[7] = f2bf(v1.w - m1.w);
    *reinterpret_cast<uint4*>(&CHB[(size_t)r * KCH + j0]) = *reinterpret_cast<uint4*>(cb);
    q += (double)m0.x * v0.x + (double)m0.y * v0.y + (double)m0.z * v0.z + (double)m0.w * v0.w
       + (double)m1.x * v1.x + (double)m1.y * v1.y + (double)m1.z * v1.z + (double)m1.w * v1.w;
  }
  for (int off = 32; off > 0; off >>= 1) q += __shfl_down(q, off);
  if (lane == 0) qv[r] += q;
}

// ------- centered Gram via bf16 MFMA: G[b] (+)= CHBc @ CHBc^T -------
template <bool ACC>
__global__ __launch_bounds__(256) void k_syrk_mma(const unsigned short* __restrict__ CHB,
                                                  float* __restrict__ ATT) {
  __shared__ __align__(16) char At[8192];
  __shared__ __align__(16) char Bt[8192];
  const int T = 8;
  int pr = blockIdx.x;
  int ti = 0, rem = pr;
  while (rem >= T - ti) { rem -= T - ti; ti++; }
  int tj = ti + rem;
  int b = blockIdx.y;
  const unsigned short* base = CHB + (size_t)b * N * KCH;
  const int tid = threadIdx.x;
  const int wave = tid >> 6, lane = tid & 63;
  f32x4 acc[2][8];
#pragma unroll
  for (int i = 0; i < 2; i++)
#pragma unroll
    for (int j = 0; j < 8; j++) acc[i][j] = (f32x4){0.f, 0.f, 0.f, 0.f};

  for (int k0 = 0; k0 < KCH; k0 += 32) {
    stage_tile(base, ti * 128, N, k0, KCH, At, tid);
    stage_tile(base, tj * 128, N, k0, KCH, Bt, tid);
    __syncthreads();
    bf16x8 af[2];
#pragma unroll
    for (int rf = 0; rf < 2; rf++)
      af[rf] = frag(At, wave * 32 + rf * 16 + (lane & 15), lane >> 4);
#pragma unroll
    for (int cf = 0; cf < 8; cf++) {
      bf16x8 bf_ = frag(Bt, cf * 16 + (lane & 15), lane >> 4);
#pragma unroll
      for (int rf = 0; rf < 2; rf++)
        acc[rf][cf] = __builtin_amdgcn_mfma_f32_16x16x32_bf16(af[rf], bf_, acc[rf][cf], 0, 0, 0);
    }
    __syncthreads();
  }
  float* att = ATT + (size_t)b * N * N;
#pragma unroll
  for (int rf = 0; rf < 2; rf++)
#pragma unroll
    for (int cf = 0; cf < 8; cf++)
#pragma unroll
      for (int r4 = 0; r4 < 4; r4++) {
        int row = ti * 128 + wave * 32 + rf * 16 + ((lane >> 4) << 2) + r4;
        int col = tj * 128 + cf * 16 + (lane & 15);
        if (row < N && col < N) {
          float v = acc[rf][cf][r4];
          if (ACC) {
            att[(size_t)row * N + col] += v;
            if (ti != tj) att[(size_t)col * N + row] += v;
          } else {
            att[(size_t)row * N + col] = v;
            if (ti != tj) att[(size_t)col * N + row] = v;
          }
        }
      }
}

// -------- top-50 on s = G + q_m - q_n, softmax(s/8), flagging --------
// Register-resident bitonic: 256 thr x 4 elements; j>=256 in-thread, j<=32 shfl_xor,
// j in {64,128} via LDS (14 barriers). Bit-identical to full-barrier network.
__global__ __launch_bounds__(256) void k_topk(float* __restrict__ ATT, const double* __restrict__ qv,
                                              const float* __restrict__ INITA,
                                              int* __restrict__ fcnt, int* __restrict__ frow,
                                              int* __restrict__ fcw, int* __restrict__ fidx,
                                              float* __restrict__ fv32) {
  int row = blockIdx.x;  // b*N + n
  int n = row % N;
  int b = row / N;
  float* arow = ATT + (size_t)row * N;
  __shared__ unsigned long long keys[1024];
  __shared__ float outr[N];
  __shared__ float sred;
  __shared__ int s_slot, s_cw;
  int tid = threadIdx.x;
  double qn = qv[row];
  unsigned long long kreg[4];
#pragma unroll
  for (int c = 0; c < 4; c++) {
    int i = tid + 256 * c;
    unsigned long long kk = 0xFFFFFFFFFFFFFFFFull;
    if (i < N) {
      float sv = (float)((double)arow[i] + qv[(size_t)b * N + i] - qn);
      unsigned u = __float_as_uint(sv);
      u ^= (u >> 31) ? 0xFFFFFFFFu : 0x80000000u;
      kk = ((unsigned long long)(~u) << 32) | (unsigned)i;
    }
    kreg[c] = kk;
  }
  for (int ksz = 2; ksz <= 1024; ksz <<= 1) {
    for (int j = ksz >> 1; j > 0; j >>= 1) {
      if (j <= 32) {
#pragma unroll
        for (int c = 0; c < 4; c++) {
          int e = tid + 256 * c;
          unsigned long long pk = __shfl_xor(kreg[c], j);
          bool takemin = (((e & j) == 0) == ((e & ksz) == 0));
          unsigned long long mn = kreg[c] < pk ? kreg[c] : pk;
          unsigned long long mx = kreg[c] < pk ? pk : kreg[c];
          kreg[c] = takemin ? mn : mx;
        }
      } else if (j >= 256) {
        int sw = j >> 8;
#pragma unroll
        for (int c = 0; c < 4; c++) {
          if ((c & sw) == 0) {
            int e = tid + 256 * c;
            bool up = (e & ksz) == 0;
            unsigned long long a = kreg[c], b2 = kreg[c | sw];
            if ((a > b2) == up) { kreg[c] = b2; kreg[c | sw] = a; }
          }
        }
      } else {
#pragma unroll
        for (int c = 0; c < 4; c++) keys[tid + 256 * c] = kreg[c];
        __syncthreads();
#pragma unroll
        for (int c = 0; c < 4; c++) {
          int e = tid + 256 * c;
          unsigned long long pk = keys[e ^ j];
          bool takemin = (((e & j) == 0) == ((e & ksz) == 0));
          unsigned long long mn = kreg[c] < pk ? kreg[c] : pk;
          unsigned long long mx = kreg[c] < pk ? pk : kreg[c];
          kreg[c] = takemin ? mn : mx;
        }
        __syncthreads();
      }
    }
  }
#pragma unroll
  for (int c = 0; c < 4; c++) keys[tid + 256 * c] = kreg[c];
  __syncthreads();
  auto dec = [](unsigned long long kk) {
    unsigned y = ~(unsigned)(kk >> 32);
    unsigned u = (y & 0x80000000u) ? (y ^ 0x80000000u) : ~y;
    return __uint_as_float(u);
  };

  float v49 = dec(keys[49]);
  float v50v = dec(keys[50]);
  float FLAGW = 8e-3f + 2e-5f * fabsf(v49);   // s-units
  bool flag = (v50v >= v49 - FLAGW);
  if (flag) {
    if (tid == 0) {
      int cin = 0;
      for (int r = 0; r < 50; r++)
        if (dec(keys[r]) > v49 + FLAGW) cin++;
      int rhi = 50;
      while (rhi < 113) {
        float vv = dec(keys[rhi + 1]);
        if (vv >= v49 - FLAGW) rhi++; else break;
      }
      int w = rhi - cin + 1;
      if (w > CANDMAX) w = CANDMAX;
      if (cin + w < 50) w = 50 - cin;
      int slot = atomicAdd(fcnt, 1);
      frow[slot] = row;
      fcw[slot] = cin | (w << 8);
      s_slot = slot;
      s_cw = cin | (w << 8);
    }
    __syncthreads();
    int slot = s_slot;
    int tot = (s_cw & 255) + (s_cw >> 8);
    for (int r = tid; r < tot; r += 256) {
      unsigned long long kk = keys[r];
      fidx[(size_t)slot * WST + r] = (int)(unsigned)(kk & 0xFFFFFFFFull);
      fv32[(size_t)slot * WST + r] = dec(kk);
    }
    __syncthreads();
  }

  float vmax = dec(keys[0]);
  float e = 0.f;
  int myidx = 0;
  if (tid < TOPKK) {
    unsigned long long kk = keys[tid];
    myidx = (int)(unsigned)(kk & 0xFFFFFFFFull);
    e = expf((dec(kk) - vmax) * 0.125f);
  }
  float s = e;
  for (int off = 32; off > 0; off >>= 1) s += __shfl_down(s, off);
  if (tid == 0) sred = s;
  for (int m2 = tid; m2 < N; m2 += 256) outr[m2] = 0.2f * INITA[(size_t)n * N + m2];
  __syncthreads();
  if (tid < TOPKK) outr[myidx] = 0.2f * INITA[(size_t)n * N + myidx] + 0.8f * (e / sred);
  __syncthreads();
  for (int m2 = tid; m2 < N; m2 += 256) arow[m2] = outr[m2];
}

// -------- fixup: fv32 ranking + minimax mass-split at near-tied boundaries --------
__global__ __launch_bounds__(256) void k_fixup(float* __restrict__ ATT, const float* __restrict__ INITA,
                                               const int* __restrict__ fcnt, const int* __restrict__ frow,
                                               const int* __restrict__ fcw, const int* __restrict__ fidx,
                                               const float* __restrict__ fv32) {
  __shared__ double wts[56];
  __shared__ int mm[56];
  __shared__ int s_tot;
  int tid = threadIdx.x;
  int cnt = *fcnt;
  for (int slot = blockIdx.x; slot < cnt; slot += gridDim.x) {
    int row = frow[slot];
    int cw = fcw[slot];
    int cin = cw & 255, w = cw >> 8;
    int n = row % N;
    __syncthreads();
    if (tid == 0) {
      int need = 50 - cin;
      if (need > w) need = w;
      double cv[CANDMAX]; int cm[CANDMAX]; float cs[CANDMAX];
      for (int c = 0; c < w; c++) {
        float sv = fv32[(size_t)slot * WST + cin + c];
        cv[c] = (double)sv * 0.125;
        cm[c] = fidx[(size_t)slot * WST + cin + c];
        cs[c] = sv;
      }
      int ord[CANDMAX];
      for (int c = 0; c < w; c++) ord[c] = c;
      for (int a2 = 0; a2 < w; a2++) {
        int best = a2;
        for (int c2 = a2 + 1; c2 < w; c2++) {
          int i1 = ord[c2], i0 = ord[best];
          if (cv[i1] > cv[i0] || (cv[i1] == cv[i0] && cm[i1] < cm[i0])) best = c2;
        }
        int tswap = ord[a2]; ord[a2] = ord[best]; ord[best] = tswap;
      }
      double b_in = cv[ord[need - 1]];
      double b_out = (need < w) ? cv[ord[need]] : -1e300;
      const double DATT = 1e-3;
      double fac[56];
      int tot = 0;
      for (int r = 0; r < cin; r++) {
        wts[tot] = (double)fv32[(size_t)slot * WST + r];
        mm[tot] = fidx[(size_t)slot * WST + r];
        fac[tot++] = 1.0;
      }
      if (need == w || b_in - b_out > DATT) {
        for (int t3 = 0; t3 < need; t3++) {
          wts[tot] = (double)cs[ord[t3]];
          mm[tot] = cm[ord[t3]];
          fac[tot++] = 1.0;
        }
      } else {
        int gs = 0;
        while (gs < w && cv[ord[gs]] > b_in + DATT) gs++;
        int ge = w - 1;
        while (ge >= 0 && cv[ord[ge]] < b_out - DATT) ge--;
        double mid = 0.5 * (b_in + b_out);
        while (ge - gs + 1 > 3) {
          if (cv[ord[gs]] - mid >= mid - cv[ord[ge]]) gs++;
          else ge--;
        }
        int fullc = gs;
        int gcount = ge - gs + 1;
        int gneed = need - fullc;
        if (gneed < 0) gneed = 0;
        if (gneed > gcount) gneed = gcount;
        double frac = (gcount > 0) ? (double)gneed / (double)gcount : 0.0;
        for (int t3 = 0; t3 < fullc; t3++) {
          wts[tot] = (double)cs[ord[t3]];
          mm[tot] = cm[ord[t3]];
          fac[tot++] = 1.0;
        }
        for (int t3 = gs; t3 <= ge; t3++) {
          wts[tot] = (double)cs[ord[t3]];
          mm[tot] = cm[ord[t3]];
          fac[tot++] = frac;
        }
      }
      double vmax = -1e300;
      for (int r = 0; r < tot; r++)
        if (fac[r] > 0.0 && wts[r] > vmax) vmax = wts[r];
      double S = 0.0;
      for (int r = 0; r < tot; r++) {
        double e = fac[r] * exp((wts[r] - vmax) * 0.125);
        wts[r] = e;
        S += e;
      }
      double inv = 1.0 / S;
      for (int r = 0; r < tot; r++) wts[r] *= inv;
      s_tot = tot;
    }
    __syncthreads();
    int tot = s_tot;
    float* arow = ATT + (size_t)row * N;
    for (int m2 = tid; m2 < N; m2 += 256) arow[m2] = 0.2f * INITA[(size_t)n * N + m2];
    __syncthreads();
    if (tid < tot && wts[tid] > 0.0)
      arow[mm[tid]] = 0.2f * INITA[(size_t)n * N + mm[tid]] + 0.8f * (float)wts[tid];
    __syncthreads();
  }
}

// ---------------- GCN degree: two-stage coalesced ----------------
// stage 1: grid (8 rowchunks, 16 b); partial column sums in registers
__global__ __launch_bounds__(256) void k_degp(const float* __restrict__ ADJ, float* __restrict__ DPART) {
  int ch = blockIdx.x, b = blockIdx.y;
  int tid = threadIdx.x;
  float reg[4] = {0.f, 0.f, 0.f, 0.f};
  int j0 = ch * 123, j1 = j0 + 123;
  if (j1 > N) j1 = N;
  const float* adj = ADJ + (size_t)b * N * N;
  for (int j = j0; j < j1; j++) {
    const float* rowp = adj + (size_t)j * N;
#pragma unroll
    for (int k = 0; k < 4; k++) {
      int i = tid + 256 * k;
      if (i < N) reg[k] += rowp[i];
    }
  }
  float* dp = DPART + ((size_t)b * 8 + ch) * N;
#pragma unroll
  for (int k = 0; k < 4; k++) {
    int i = tid + 256 * k;
    if (i < N) dp[i] = reg[k];
  }
}
// stage 2: deg = 1 + sum of 8 partials (fixed order, deterministic)
__global__ void k_degf(const float* __restrict__ DPART, float* __restrict__ DINV) {
  int t = blockIdx.x * 256 + threadIdx.x;
  if (t >= M) return;
  int b = t / N, i = t - b * N;
  float s = 1.f;
#pragma unroll
  for (int c = 0; c < 8; c++) s += DPART[((size_t)b * 8 + c) * N + i];
  DINV[t] = rsqrtf(s);
}

template <int ACT>
__global__ __launch_bounds__(256) void k_spmm(const float* __restrict__ ADJ, const float* __restrict__ DINV,
                                              const float* __restrict__ XW, const float* __restrict__ bias,
                                              float* __restrict__ OUT, int F) {
  __shared__ float As[16][132];
  __shared__ float Ws[16][132];
  const int tid = threadIdx.x;
  const int i0 = blockIdx.x * 128;
  const int f0 = blockIdx.y * 128;
  const int b = blockIdx.z;
  const float* adj = ADJ + (size_t)b * N * N;
  const float* dv = DINV + b * N;
  const float* xw = XW + (size_t)b * N * F;
  const int ty = tid >> 4, tx = tid & 15;
  float acc[8][8];
#pragma unroll
  for (int i = 0; i < 8; i++)
#pragma unroll
    for (int j = 0; j < 8; j++) acc[i][j] = 0.f;

  for (int j0 = 0; j0 < N; j0 += 16) {
#pragma unroll
    for (int l = 0; l < 8; l++) {
      int idx = tid + l * 256;
      int r = idx >> 7, c = idx & 127;
      int j = j0 + r, i = i0 + c;
      float v = 0.f;
      if (j < N && i < N) {
        float dj = dv[j];
        v = adj[(size_t)j * N + i] * dj;
        if (i == j) v += dj;
      }
      As[r][c] = v;
      float w = 0.f;
      if (j < N) w = xw[(size_t)j * F + f0 + c];
      Ws[r][c] = w;
    }
    __syncthreads();
#pragma unroll
    for (int k = 0; k < 16; k++) {
      float a[8], bb[8];
      *reinterpret_cast<float4*>(&a[0]) = *reinterpret_cast<const float4*>(&As[k][ty * 8]);
      *reinterpret_cast<float4*>(&a[4]) = *reinterpret_cast<const float4*>(&As[k][ty * 8 + 4]);
      *reinterpret_cast<float4*>(&bb[0]) = *reinterpret_cast<const float4*>(&Ws[k][tx * 8]);
      *reinterpret_cast<float4*>(&bb[4]) = *reinterpret_cast<const float4*>(&Ws[k][tx * 8 + 4]);
#pragma unroll
      for (int i = 0; i < 8; i++)
#pragma unroll
        for (int j = 0; j < 8; j++) acc[i][j] = fmaf(a[i], bb[j], acc[i][j]);
    }
    __syncthreads();
  }
#pragma unroll
  for (int i = 0; i < 8; i++) {
    int row = i0 + ty * 8 + i;
    if (row >= N) continue;
    float di = dv[row];
#pragma unroll
    for (int j4 = 0; j4 < 2; j4++) {
      float4 v;
      float* vv = reinterpret_cast<float*>(&v);
#pragma unroll
      for (int j = 0; j < 4; j++) {
        float x = acc[i][j4 * 4 + j] * di + bias[f0 + tx * 8 + j4 * 4 + j];
        if (ACT == 2) x = fmaxf(x, 0.f);
        vv[j] = x;
      }
      *reinterpret_cast<float4*>(&OUT[((size_t)b * N + row) * F + f0 + tx * 8 + j4 * 4]) = v;
    }
  }
}

// ---------------- drug embed (fp32) ----------------
__global__ __launch_bounds__(256) void k_drug_l1(const float* __restrict__ d1, const float* __restrict__ d2,
                                                 const float* __restrict__ W, const float* __restrict__ bias,
                                                 float* __restrict__ T1) {
  __shared__ float row[DF];
  int blk = blockIdx.x;
  const float* dr = ((blk & 16) ? d2 : d1) + (size_t)(blk & 15) * DF;
  for (int i = threadIdx.x; i < DF; i += 256) row[i] = dr[i];
  __syncthreads();
  for (int e = threadIdx.x; e < 512; e += 256) {
    float s = bias[e];
    for (int k = 0; k < DF; k++) s = fmaf(row[k], W[(size_t)k * 512 + e], s);
    T1[(size_t)blk * 512 + e] = fmaxf(s, 0.f);
  }
}

__global__ __launch_bounds__(128) void k_drug_l2(const float* __restrict__ T1, const float* __restrict__ W,
                                                 const float* __restrict__ bias, const float* __restrict__ lg,
                                                 const float* __restrict__ lb, float* __restrict__ D) {
  __shared__ float row[512];
  __shared__ float red[4];
  int blk = blockIdx.x;
  int e = threadIdx.x;
  for (int i = e; i < 512; i += 128) row[i] = T1[(size_t)blk * 512 + i];
  __syncthreads();
  float s = bias[e];
  for (int k = 0; k < 512; k++) s = fmaf(row[k], W[k * 128 + e], s);
  float t = s;
  for (int off = 32; off > 0; off >>= 1) t += __shfl_down(t, off);
  if ((e & 63) == 0) red[e >> 6] = t;
  __syncthreads();
  float mean = (red[0] + red[1]) * (1.f / 128.f);
  float dd = s - mean;
  float wv = dd * dd;
  for (int off = 32; off > 0; off >>= 1) wv += __shfl_down(wv, off);
  if ((e & 63) == 0) red[2 + (e >> 6)] = wv;
  __syncthreads();
  float var = (red[2] + red[3]) * (1.f / 128.f);
  D[(size_t)blk * 128 + e] = dd * rsqrtf(var + 1e-5f) * lg[e] + lb[e];
}

// ---------------- head + decoder ----------------
__global__ void k_gemb(const float* __restrict__ NODE, float* __restrict__ GEMB) {
  int t = blockIdx.x * 256 + threadIdx.x;
  int b = t >> 7, f = t & 127;
  const float* p = NODE + (size_t)b * N * IB2 + f;
  float s = 0.f;
  for (int n2 = 0; n2 < N; n2++) s += p[(size_t)n2 * IB2];
  GEMB[t] = s * (1.f / (float)N);
}

__global__ void k_heads(const float* __restrict__ GEMB, const float* __restrict__ EPS,
                        float* __restrict__ out_mu, float* __restrict__ out_std, float* __restrict__ Z) {
  int t = blockIdx.x * 256 + threadIdx.x;
  int b = t >> 6, q = t & 63;
  float mu = GEMB[b * 128 + q];
  float xs = GEMB[b * 128 + 64 + q] - 64.f;
  float sp = (xs > 20.f) ? xs : log1pf(expf(xs));
  out_mu[t] = mu;
  out_std[t] = sp;
  Z[t] = mu + EPS[t] * sp;
}

__global__ __launch_bounds__(512) void k_dec1(const float* __restrict__ Z, const float* __restrict__ W1,
                                              const float* __restrict__ b1, const float* __restrict__ bg,
                                              const float* __restrict__ bb, float* __restrict__ DEC) {
  int f = threadIdx.x;
  float d[16];
  for (int b = 0; b < 16; b++) {
    float s = b1[f];
    for (int k = 0; k < 64; k++) s = fmaf(Z[b * 64 + k], W1[k * 512 + f], s);
    d[b] = s;
  }
  float m = 0.f;
  for (int b = 0; b < 16; b++) m += d[b];
  m *= (1.f / 16.f);
  float v = 0.f;
  for (int b = 0; b < 16; b++) { float t = d[b] - m; v += t * t; }
  v *= (1.f / 16.f);
  float sc = rsqrtf(v + 1e-5f) * bg[f];
  float sh = bb[f];
  for (int b = 0; b < 16; b++) {
    float x = (d[b] - m) * sc + sh;
    DEC[b * 512 + f] = fmaxf(x, 0.f);
  }
}

__global__ void k_dec2(const float* __restrict__ DEC, const float* __restrict__ W2,
                       const float* __restrict__ b2, float* __restrict__ X2) {
  int t = blockIdx.x * 256 + threadIdx.x;
  if (t >= M) return;
  int b = t / N, n2 = t - b * N;
  float s = b2[n2];
  const float* db = DEC + b * 512;
  for (int f = 0; f < 512; f++) s = fmaf(db[f], W2[(size_t)f * N + n2], s);
  X2[t] = fmaxf(s, 0.f);
}

}  // namespace

extern "C" void kernel_launch(void* const* d_in, const int* in_sizes, int n_in,
                              void* d_out, int out_size, void* d_ws, size_t ws_size,
                              hipStream_t stream) {
  const float* x1 = (const float*)d_in[0];
  const float* drug1 = (const float*)d_in[1];
  const float* drug2 = (const float*)d_in[2];
  const float* eps = (const float*)d_in[3];
  const int* ei = (const int*)d_in[4];
  const float* gate_W = (const float*)d_in[5];
  const float* gate_b = (const float*)d_in[6];
  const float* emb = (const float*)d_in[7];
  const float* encW1 = (const float*)d_in[8];
  const float* encb1 = (const float*)d_in[9];
  const float* encW2 = (const float*)d_in[10];
  const float* encb2 = (const float*)d_in[11];
  const float* netW1 = (const float*)d_in[12];
  const float* netb1 = (const float*)d_in[13];
  const float* netW2 = (const float*)d_in[14];
  const float* netb2 = (const float*)d_in[15];
  const float* ln_g = (const float*)d_in[16];
  const float* ln_b = (const float*)d_in[17];
  const float* feat_mask = (const float*)d_in[18];
  const float* W_sims = (const float*)d_in[19];
  const float* gcnW1 = (const float*)d_in[20];
  const float* gcnb1 = (const float*)d_in[21];
  const float* gcnW2 = (const float*)d_in[22];
  const float* gcnb2 = (const float*)d_in[23];
  const float* decW1 = (const float*)d_in[24];
  const float* decb1 = (const float*)d_in[25];
  const float* bn_g = (const float*)d_in[26];
  const float* bn_b = (const float*)d_in[27];
  const float* decW2 = (const float*)d_in[28];
  const float* decb2 = (const float*)d_in[29];
  (void)in_sizes; (void)n_in; (void)out_size; (void)ws_size;

  // Workspace layout (~188 MB; known-good <=192 MB)
  size_t o = 0;
  auto A = [&](size_t bytes) { char* p = (char*)d_ws + o; o += (bytes + 255) & ~(size_t)255; return p; };
  unsigned short* WTH = (unsigned short*)A((size_t)KATT * 256 * 2);  // 2 MB
  unsigned short* WTL = (unsigned short*)A((size_t)KATT * 256 * 2);  // 2 MB
  char* RBIG = A((size_t)64 * 1024 * 1024);                          // 64 MB
  float* Hb = (float*)A((size_t)M * 128 * 4);                        // 8 MB
  float* ADJ1 = (float*)A((size_t)B * N * N * 4);                    // 61 MB
  float* INITA = (float*)A((size_t)N * N * 4);                       // 3.8 MB
  float* T1 = (float*)A(32 * 512 * 4);
  float* Dd32 = (float*)A(32 * 128 * 4);
  float* DINV = (float*)A(M * 4);
  float* DPART = (float*)A((size_t)16 * 8 * N * 4);                  // 0.5 MB
  float* GEMB = (float*)A(B * 128 * 4);
  float* Zb = (float*)A(B * 64 * 4);
  float* DEC = (float*)A(B * 512 * 4);
  int* fcnt = (int*)A(256);
  float* MU = (float*)A((size_t)B * KCH * 4);                        // 64 KB
  double* qv = (double*)A((size_t)M * 8);
  unsigned short* FUSH = (unsigned short*)A((size_t)M * 256 * 2);    // 8 MB
  unsigned short* FUSL = (unsigned short*)A((size_t)M * 256 * 2);    // 8 MB
  unsigned short* CHB = (unsigned short*)A((size_t)M * KCH * 2);     // 30.6 MB

  // RBIG unions (phases don't overlap):
  //  encoder: buf1 | buf2
  //  g-loop chunks: CH (61.1 MB) ; after chunks (CH dead): FLAGS
  //  GCN: XW | Tt
  float* buf1 = (float*)RBIG;
  float* buf2 = (float*)(RBIG + (size_t)32 * 1024 * 1024);
  float* CH = (float*)RBIG;
  char* FLAGS = RBIG;                          // alias CH: live only after chunk loop
  int* frow = (int*)FLAGS;
  int* fcw = (int*)(FLAGS + (size_t)M * 4);
  int* fidx = (int*)(FLAGS + (size_t)2 * M * 4);
  float* fv32 = (float*)(FLAGS + (size_t)2 * M * 4 + (size_t)M * WST * 4);
  float* XW = (float*)RBIG;
  float* Tt = (float*)(RBIG + (size_t)32 * 1024 * 1024);
  float* TW2 = (float*)FUSH;                   // GCN phase: FUS dead
  float* NODE = (float*)FUSL;

  float* out = (float*)d_out;
  float* out_x2 = out;
  float* out_adj2 = out + M;
  float* out_mu = out + M + (size_t)B * N * N;
  float* out_std = out_mu + B * 64;

  k_wt<<<4096, 256, 0, stream>>>(W_sims, feat_mask, WTH, WTL);
  k_gate_emb<<<31296, 256, 0, stream>>>(x1, gate_W, gate_b, emb, buf1);
  k_gemm<1, true><<<dim3(123, 4), 256, 0, stream>>>(buf1, encW1, encb1, buf2, M, 512, 512, 512);
  k_gemm<0, true><<<dim3(123, 1), 256, 0, stream>>>(buf2, encW2, encb2, Hb, M, 512, 128, 128);
  k_drug_l1<<<32, 256, 0, stream>>>(drug1, drug2, netW1, netb1, T1);
  k_drug_l2<<<32, 128, 0, stream>>>(T1, netW2, netb2, ln_g, ln_b, Dd32);
  k_zero<<<(N * N + 255) / 256, 256, 0, stream>>>(INITA, N * N);
  k_scatter<<<(NEDGE + 255) / 256, 256, 0, stream>>>(ei, INITA);

  for (int g = 0; g < 2; g++) {
    float* att = (g == 0) ? ADJ1 : out_adj2;
    const float* DDg = Dd32 + (size_t)g * 16 * 128;
    hipMemsetAsync(fcnt, 0, 4, stream);
    hipMemsetAsync(qv, 0, (size_t)M * 8, stream);
    k_fus<<<15648, 256, 0, stream>>>(Hb, DDg, FUSH, FUSL);
    for (int c = 0; c < NCH; c++) {
      k_hp_mma<<<dim3(123, KCH / 128), 256, 0, stream>>>(FUSH, FUSL, WTH + (size_t)c * KCH * 256,
                                                         WTL + (size_t)c * KCH * 256, CH);
      k_mu<<<dim3(KCH / 32, 16), 256, 0, stream>>>(CH, MU);
      k_centerq<<<M / 4, 256, 0, stream>>>(CH, MU, CHB, qv);
      if (c == 0)
        k_syrk_mma<false><<<dim3(36, 16), 256, 0, stream>>>(CHB, att);
      else
        k_syrk_mma<true><<<dim3(36, 16), 256, 0, stream>>>(CHB, att);
    }
    k_topk<<<M, 256, 0, stream>>>(att, qv, INITA, fcnt, frow, fcw, fidx, fv32);
    k_fixup<<<1024, 256, 0, stream>>>(att, INITA, fcnt, frow, fcw, fidx, fv32);
  }

  k_degp<<<dim3(8, 16), 256, 0, stream>>>(ADJ1, DPART);
  k_degf<<<(M + 255) / 256, 256, 0, stream>>>(DPART, DINV);
  k_gemm<0, false><<<dim3(123, 4), 256, 0, stream>>>(Hb, gcnW1, nullptr, XW, M, 128, 512, 512);
  k_spmm<2><<<dim3(8, 4, 16), 256, 0, stream>>>(ADJ1, DINV, XW, gcnb1, Tt, 512);
  k_gemm<0, false><<<dim3(123, 1), 256, 0, stream>>>(Tt, gcnW2, nullptr, TW2, M, 512, 128, 128);
  k_spmm<0><<<dim3(8, 1, 16), 256, 0, stream>>>(ADJ1, DINV, TW2, gcnb2, NODE, 128);
  k_gemb<<<8, 256, 0, stream>>>(NODE, GEMB);
  k_heads<<<4, 256, 0, stream>>>(GEMB, eps, out_mu, out_std, Zb);
  k_dec1<<<1, 512, 0, stream>>>(Zb, decW1, decb1, bn_g, bn_b, DEC);
  k_dec2<<<(M + 255) / 256, 256, 0, stream>>>(DEC, decW2, decb2, out_x2);
}

// Round 13
// 3909.384 us; speedup vs baseline: 1.7819x; 1.0940x over previous
//
#include <hip/hip_runtime.h>
#include <cmath>

namespace {

constexpr int B = 16;
constexpr int N = 978;
constexpr int M = B * N;          // 15648
constexpr int IB2 = 128;          // 2*IB
constexpr int KATT = 4096;        // P*HID
constexpr int KCH = 1024;         // hp column chunk
constexpr int NCH = KATT / KCH;   // 4
constexpr int DF = 2304;
constexpr int TOPKK = 50;
constexpr int NEDGE = 50000;
constexpr int CANDMAX = 64;
constexpr int WST = 120;
constexpr int JSPLIT = 489;       // spmm j-split point (978/2)

typedef __attribute__((ext_vector_type(8))) short bf16x8;
typedef __attribute__((ext_vector_type(4))) float f32x4;

__device__ __forceinline__ float geluf(float x) {
  return 0.5f * x * (1.f + erff(x * 0.7071067811865476f));
}
__device__ __forceinline__ float sigm(float x) { return 1.f / (1.f + expf(-x)); }
__device__ __forceinline__ double sigm64(double x) { return 1.0 / (1.0 + exp(-x)); }

__device__ __forceinline__ unsigned short f2bf(float f) {
  union { float f; unsigned u; } x; x.f = f;
  unsigned r = (x.u + 0x7FFFu + ((x.u >> 16) & 1u)) >> 16;
  return (unsigned short)r;
}
__device__ __forceinline__ float bf2f(unsigned short s) {
  union { float f; unsigned u; } x; x.u = ((unsigned)s) << 16; return x.f;
}

// ---------------- WT build: (4096 x 256) bf16 hi/lo of W_sims^T * sigm(fm) ----------------
__global__ void k_wt(const float* __restrict__ wsims, const float* __restrict__ fm,
                     unsigned short* __restrict__ wth, unsigned short* __restrict__ wtl) {
  int t = blockIdx.x * 256 + threadIdx.x;   // < 4096*256 = 1048576 exact
  int n = t >> 8, k = t & 255;
  int p = n >> 9, h = n & 511;
  double v = (double)wsims[(size_t)p * 131072 + (size_t)k * 512 + h] * sigm64((double)fm[k]);
  float vf = (float)v;
  unsigned short hi = f2bf(vf);
  wth[t] = hi;
  wtl[t] = f2bf(vf - bf2f(hi));
}

// ---------------- FUS build: (M x 256) bf16 hi/lo of [Hb | DDg] ----------------
__global__ void k_fus(const float* __restrict__ Hb, const float* __restrict__ DD,
                      unsigned short* __restrict__ fh, unsigned short* __restrict__ fl) {
  int t = blockIdx.x * 256 + threadIdx.x;   // < M*256 exact
  int k = t & 255;
  int row = t >> 8;
  int b = row / N;
  float v = (k < 128) ? Hb[(size_t)row * 128 + k] : DD[(size_t)b * 128 + (k - 128)];
  unsigned short hi = f2bf(v);
  fh[t] = hi;
  fl[t] = f2bf(v - bf2f(hi));
}

__global__ void k_gate_emb(const float* __restrict__ x1, const float* __restrict__ gW,
                           const float* __restrict__ gb, const float* __restrict__ emb,
                           float* __restrict__ A) {
  size_t t = (size_t)blockIdx.x * 256 + threadIdx.x;  // < M*512 exact
  int e = (int)(t & 511);
  size_t bn = t >> 9;
  int n = (int)(bn % N);
  float g = sigm(x1[bn] * gW[e] + gb[e]);
  A[t] = g * emb[(size_t)n * 512 + e];
}

__global__ void k_zero(float* __restrict__ p, int n) {
  int t = blockIdx.x * 256 + threadIdx.x;
  if (t < n) p[t] = 0.f;
}

__global__ void k_scatter(const int* __restrict__ ei, float* __restrict__ adj) {
  int t = blockIdx.x * 256 + threadIdx.x;
  if (t < NEDGE) {
    int r = ei[t], c = ei[NEDGE + t];
    adj[(size_t)r * N + c] = 1.f;
  }
}

// ---------------- generic fp32 GEMM (encoder / GCN) ----------------
template <int ACT, bool HASBIAS>
__global__ __launch_bounds__(256) void k_gemm(const float* __restrict__ A,
                                              const float* __restrict__ W, const float* __restrict__ bias,
                                              float* __restrict__ C,
                                              int Mm, int K, int Nc, int ldw) {
  __shared__ float As[16][132];
  __shared__ float Ws[16][132];
  const int tid = threadIdx.x;
  const int m0 = blockIdx.x * 128;
  const int n0 = blockIdx.y * 128;
  const int ty = tid >> 4, tx = tid & 15;
  float acc[8][8];
#pragma unroll
  for (int i = 0; i < 8; i++)
#pragma unroll
    for (int j = 0; j < 8; j++) acc[i][j] = 0.f;

  for (int k0 = 0; k0 < K; k0 += 16) {
#pragma unroll
    for (int l = 0; l < 2; l++) {
      int idx4 = tid + l * 256;
      int r = idx4 >> 2, c4 = idx4 & 3;
      int row = m0 + r;
      float4 v = make_float4(0.f, 0.f, 0.f, 0.f);
      if (row < Mm) v = *reinterpret_cast<const float4*>(&A[(size_t)row * K + k0 + c4 * 4]);
      As[c4 * 4 + 0][r] = v.x;
      As[c4 * 4 + 1][r] = v.y;
      As[c4 * 4 + 2][r] = v.z;
      As[c4 * 4 + 3][r] = v.w;
    }
#pragma unroll
    for (int l = 0; l < 2; l++) {
      int idx4 = tid + l * 256;
      int r = idx4 >> 5, c4 = idx4 & 31;
      float4 v = *reinterpret_cast<const float4*>(&W[(size_t)(k0 + r) * ldw + n0 + c4 * 4]);
      *reinterpret_cast<float4*>(&Ws[r][c4 * 4]) = v;
    }
    __syncthreads();
#pragma unroll
    for (int k = 0; k < 16; k++) {
      float a[8], bb[8];
      *reinterpret_cast<float4*>(&a[0]) = *reinterpret_cast<const float4*>(&As[k][ty * 8]);
      *reinterpret_cast<float4*>(&a[4]) = *reinterpret_cast<const float4*>(&As[k][ty * 8 + 4]);
      *reinterpret_cast<float4*>(&bb[0]) = *reinterpret_cast<const float4*>(&Ws[k][tx * 8]);
      *reinterpret_cast<float4*>(&bb[4]) = *reinterpret_cast<const float4*>(&Ws[k][tx * 8 + 4]);
#pragma unroll
      for (int i = 0; i < 8; i++)
#pragma unroll
        for (int j = 0; j < 8; j++) acc[i][j] = fmaf(a[i], bb[j], acc[i][j]);
    }
    __syncthreads();
  }
#pragma unroll
  for (int i = 0; i < 8; i++) {
    int row = m0 + ty * 8 + i;
    if (row >= Mm) continue;
#pragma unroll
    for (int j4 = 0; j4 < 2; j4++) {
      float4 v;
      float* vv = reinterpret_cast<float*>(&v);
#pragma unroll
      for (int j = 0; j < 4; j++) {
        float x = acc[i][j4 * 4 + j];
        if (HASBIAS) x += bias[n0 + tx * 8 + j4 * 4 + j];
        if (ACT == 1) x = geluf(x);
        if (ACT == 2) x = fmaxf(x, 0.f);
        vv[j] = x;
      }
      *reinterpret_cast<float4*>(&C[(size_t)row * Nc + n0 + tx * 8 + j4 * 4]) = v;
    }
  }
}

// ------- MFMA staging: 128x32 bf16 tile, XOR-swizzled ((r&7)<<4 on 64B rows) -------
__device__ __forceinline__ void stage_tile(const unsigned short* __restrict__ gbase, int grow0,
                                           int rowmax, int k0, int ldk, char* lds, int tid) {
#pragma unroll
  for (int it = 0; it < 2; it++) {
    int r = (tid >> 2) + it * 64;
    int c8 = tid & 3;
    int gr = grow0 + r;
    uint4 v = make_uint4(0u, 0u, 0u, 0u);
    if (gr < rowmax) v = *reinterpret_cast<const uint4*>(&gbase[(size_t)gr * ldk + k0 + c8 * 8]);
    int off = (r * 64 + c8 * 16) ^ ((r & 7) << 4);
    *reinterpret_cast<uint4*>(lds + off) = v;
  }
}

__device__ __forceinline__ bf16x8 frag(const char* lds, int r, int k8) {
  int off = (r * 64 + k8 * 16) ^ ((r & 7) << 4);
  return *reinterpret_cast<const bf16x8*>(lds + off);
}

// ------- hp chunk GEMM, split-bf16 (fp32-equivalent): CH = relu(FUS @ WT_chunk^T) -------
__global__ __launch_bounds__(256) void k_hp_mma(const unsigned short* __restrict__ FH,
                                                const unsigned short* __restrict__ FL,
                                                const unsigned short* __restrict__ WTHc,
                                                const unsigned short* __restrict__ WTLc,
                                                float* __restrict__ CH) {
  __shared__ __align__(16) char Ah[8192];
  __shared__ __align__(16) char Al[8192];
  __shared__ __align__(16) char Bh[8192];
  __shared__ __align__(16) char Bl[8192];
  const int m0 = blockIdx.x * 128;
  const int n0 = blockIdx.y * 128;   // within chunk (KCH)
  const int tid = threadIdx.x;
  const int wave = tid >> 6, lane = tid & 63;
  f32x4 acc[2][8];
#pragma unroll
  for (int i = 0; i < 2; i++)
#pragma unroll
    for (int j = 0; j < 8; j++) acc[i][j] = (f32x4){0.f, 0.f, 0.f, 0.f};

  for (int k0 = 0; k0 < 256; k0 += 32) {
    stage_tile(FH, m0, M, k0, 256, Ah, tid);
    stage_tile(FL, m0, M, k0, 256, Al, tid);
    stage_tile(WTHc, n0, KCH, k0, 256, Bh, tid);
    stage_tile(WTLc, n0, KCH, k0, 256, Bl, tid);
    __syncthreads();
    bf16x8 ah[2], al[2];
#pragma unroll
    for (int rf = 0; rf < 2; rf++) {
      int r = wave * 32 + rf * 16 + (lane & 15);
      ah[rf] = frag(Ah, r, lane >> 4);
      al[rf] = frag(Al, r, lane >> 4);
    }
#pragma unroll
    for (int cf = 0; cf < 8; cf++) {
      int rB = cf * 16 + (lane & 15);
      bf16x8 bh = frag(Bh, rB, lane >> 4);
      bf16x8 bl = frag(Bl, rB, lane >> 4);
#pragma unroll
      for (int rf = 0; rf < 2; rf++) {
        acc[rf][cf] = __builtin_amdgcn_mfma_f32_16x16x32_bf16(ah[rf], bh, acc[rf][cf], 0, 0, 0);
        acc[rf][cf] = __builtin_amdgcn_mfma_f32_16x16x32_bf16(ah[rf], bl, acc[rf][cf], 0, 0, 0);
        acc[rf][cf] = __builtin_amdgcn_mfma_f32_16x16x32_bf16(al[rf], bh, acc[rf][cf], 0, 0, 0);
      }
    }
    __syncthreads();
  }
#pragma unroll
  for (int rf = 0; rf < 2; rf++)
#pragma unroll
    for (int cf = 0; cf < 8; cf++)
#pragma unroll
      for (int r4 = 0; r4 < 4; r4++) {
        int row = m0 + wave * 32 + rf * 16 + ((lane >> 4) << 2) + r4;
        int col = n0 + cf * 16 + (lane & 15);
        if (row < M) CH[(size_t)row * KCH + col] = fmaxf(acc[rf][cf][r4], 0.f);
      }
}

// ---------------- per-chunk column means (parallel, deterministic) ----------------
__global__ __launch_bounds__(256) void k_mu(const float* __restrict__ CH, float* __restrict__ MU) {
  __shared__ double red[8][33];
  int b = blockIdx.y, jg = blockIdx.x;
  int jloc = threadIdx.x & 31, s = threadIdx.x >> 5;
  int j = jg * 32 + jloc;
  const float* p = CH + (size_t)b * N * KCH + j;
  double acc = 0.0;
  for (int n = s; n < N; n += 8) acc += (double)p[(size_t)n * KCH];
  red[s][jloc] = acc;
  __syncthreads();
  if (s == 0) {
    double t = 0.0;
#pragma unroll
    for (int k = 0; k < 8; k++) t += red[k][jloc];
    MU[b * KCH + j] = (float)(t * (1.0 / (double)N));
  }
}

// ------- fused center+q: CHB = bf16(CH - MU); qv[r] += <MU[b], CH[r]> (f64) -------
__global__ __launch_bounds__(256) void k_centerq(const float* __restrict__ CH,
                                                 const float* __restrict__ MU,
                                                 unsigned short* __restrict__ CHB,
                                                 double* __restrict__ qv) {
  int r = blockIdx.x * 4 + (threadIdx.x >> 6);   // grid = M/4 = 3912 exact
  int lane = threadIdx.x & 63;
  int b = r / N;
  const float* row = CH + (size_t)r * KCH;
  const float* mu = MU + (size_t)b * KCH;
  double q = 0.0;
#pragma unroll
  for (int jp = 0; jp < 2; jp++) {
    int j0 = lane * 8 + jp * 512;
    float4 v0 = *reinterpret_cast<const float4*>(&row[j0]);
    float4 v1 = *reinterpret_cast<const float4*>(&row[j0 + 4]);
    float4 m0 = *reinterpret_cast<const float4*>(&mu[j0]);
    float4 m1 = *reinterpret_cast<const float4*>(&mu[j0 + 4]);
    unsigned short cb[8];
    cb[0] = f2bf(v0.x - m0.x); cb[1] = f2bf(v0.y - m0.y);
    cb[2] = f2bf(v0.z - m0.z); cb[3] = f2bf(v0.w - m0.w);
    cb[4] = f2bf(v1.x - m1.x); cb[5] = f2bf(v1.y - m1.y);
    cb[6] = f2bf(v1.z - m1.z); cb[7] = f2bf(v1.w - m1.w);
    *reinterpret_cast<uint4*>(&CHB[(size_t)r * KCH + j0]) = *reinterpret_cast<uint4*>(cb);
    q += (double)m0.x * v0.x + (double)m0.y * v0.y + (double)m0.z * v0.z + (double)m0.w * v0.w
       + (double)m1.x * v1.x + (double)m1.y * v1.y + (double)m1.z * v1.z + (double)m1.w * v1.w;
  }
  for (int off = 32; off > 0; off >>= 1) q += __shfl_down(q, off);
  if (lane == 0) qv[r] += q;
}

// ------- centered Gram via bf16 MFMA: G[b] (+)= CHBc @ CHBc^T -------
template <bool ACC>
__global__ __launch_bounds__(256) void k_syrk_mma(const unsigned short* __restrict__ CHB,
                                                  float* __restrict__ ATT) {
  __shared__ __align__(16) char At[8192];
  __shared__ __align__(16) char Bt[8192];
  const int T = 8;
  int pr = blockIdx.x;
  int ti = 0, rem = pr;
  while (rem >= T - ti) { rem -= T - ti; ti++; }
  int tj = ti + rem;
  int b = blockIdx.y;
  const unsigned short* base = CHB + (size_t)b * N * KCH;
  const int tid = threadIdx.x;
  const int wave = tid >> 6, lane = tid & 63;
  f32x4 acc[2][8];
#pragma unroll
  for (int i = 0; i < 2; i++)
#pragma unroll
    for (int j = 0; j < 8; j++) acc[i][j] = (f32x4){0.f, 0.f, 0.f, 0.f};

  for (int k0 = 0; k0 < KCH; k0 += 32) {
    stage_tile(base, ti * 128, N, k0, KCH, At, tid);
    stage_tile(base, tj * 128, N, k0, KCH, Bt, tid);
    __syncthreads();
    bf16x8 af[2];
#pragma unroll
    for (int rf = 0; rf < 2; rf++)
      af[rf] = frag(At, wave * 32 + rf * 16 + (lane & 15), lane >> 4);
#pragma unroll
    for (int cf = 0; cf < 8; cf++) {
      bf16x8 bf_ = frag(Bt, cf * 16 + (lane & 15), lane >> 4);
#pragma unroll
      for (int rf = 0; rf < 2; rf++)
        acc[rf][cf] = __builtin_amdgcn_mfma_f32_16x16x32_bf16(af[rf], bf_, acc[rf][cf], 0, 0, 0);
    }
    __syncthreads();
  }
  float* att = ATT + (size_t)b * N * N;
#pragma unroll
  for (int rf = 0; rf < 2; rf++)
#pragma unroll
    for (int cf = 0; cf < 8; cf++)
#pragma unroll
      for (int r4 = 0; r4 < 4; r4++) {
        int row = ti * 128 + wave * 32 + rf * 16 + ((lane >> 4) << 2) + r4;
        int col = tj * 128 + cf * 16 + (lane & 15);
        if (row < N && col < N) {
          float v = acc[rf][cf][r4];
          if (ACC) {
            att[(size_t)row * N + col] += v;
            if (ti != tj) att[(size_t)col * N + row] += v;
          } else {
            att[(size_t)row * N + col] = v;
            if (ti != tj) att[(size_t)col * N + row] = v;
          }
        }
      }
}

// -------- top-50 on s = G + q_m - q_n, softmax(s/8), flagging --------
__global__ __launch_bounds__(256) void k_topk(float* __restrict__ ATT, const double* __restrict__ qv,
                                              const float* __restrict__ INITA,
                                              int* __restrict__ fcnt, int* __restrict__ frow,
                                              int* __restrict__ fcw, int* __restrict__ fidx,
                                              float* __restrict__ fv32) {
  int row = blockIdx.x;  // b*N + n
  int n = row % N;
  int b = row / N;
  float* arow = ATT + (size_t)row * N;
  __shared__ unsigned long long keys[1024];
  __shared__ float outr[N];
  __shared__ float sred;
  __shared__ int s_slot, s_cw;
  int tid = threadIdx.x;
  double qn = qv[row];
  unsigned long long kreg[4];
#pragma unroll
  for (int c = 0; c < 4; c++) {
    int i = tid + 256 * c;
    unsigned long long kk = 0xFFFFFFFFFFFFFFFFull;
    if (i < N) {
      float sv = (float)((double)arow[i] + qv[(size_t)b * N + i] - qn);
      unsigned u = __float_as_uint(sv);
      u ^= (u >> 31) ? 0xFFFFFFFFu : 0x80000000u;
      kk = ((unsigned long long)(~u) << 32) | (unsigned)i;
    }
    kreg[c] = kk;
  }
  for (int ksz = 2; ksz <= 1024; ksz <<= 1) {
    for (int j = ksz >> 1; j > 0; j >>= 1) {
      if (j <= 32) {
#pragma unroll
        for (int c = 0; c < 4; c++) {
          int e = tid + 256 * c;
          unsigned long long pk = __shfl_xor(kreg[c], j);
          bool takemin = (((e & j) == 0) == ((e & ksz) == 0));
          unsigned long long mn = kreg[c] < pk ? kreg[c] : pk;
          unsigned long long mx = kreg[c] < pk ? pk : kreg[c];
          kreg[c] = takemin ? mn : mx;
        }
      } else if (j >= 256) {
        int sw = j >> 8;
#pragma unroll
        for (int c = 0; c < 4; c++) {
          if ((c & sw) == 0) {
            int e = tid + 256 * c;
            bool up = (e & ksz) == 0;
            unsigned long long a = kreg[c], b2 = kreg[c | sw];
            if ((a > b2) == up) { kreg[c] = b2; kreg[c | sw] = a; }
          }
        }
      } else {
#pragma unroll
        for (int c = 0; c < 4; c++) keys[tid + 256 * c] = kreg[c];
        __syncthreads();
#pragma unroll
        for (int c = 0; c < 4; c++) {
          int e = tid + 256 * c;
          unsigned long long pk = keys[e ^ j];
          bool takemin = (((e & j) == 0) == ((e & ksz) == 0));
          unsigned long long mn = kreg[c] < pk ? kreg[c] : pk;
          unsigned long long mx = kreg[c] < pk ? pk : kreg[c];
          kreg[c] = takemin ? mn : mx;
        }
        __syncthreads();
      }
    }
  }
#pragma unroll
  for (int c = 0; c < 4; c++) keys[tid + 256 * c] = kreg[c];
  __syncthreads();
  auto dec = [](unsigned long long kk) {
    unsigned y = ~(unsigned)(kk >> 32);
    unsigned u = (y & 0x80000000u) ? (y ^ 0x80000000u) : ~y;
    return __uint_as_float(u);
  };

  float v49 = dec(keys[49]);
  float v50v = dec(keys[50]);
  float FLAGW = 8e-3f + 2e-5f * fabsf(v49);   // s-units
  bool flag = (v50v >= v49 - FLAGW);
  if (flag) {
    if (tid == 0) {
      int cin = 0;
      for (int r = 0; r < 50; r++)
        if (dec(keys[r]) > v49 + FLAGW) cin++;
      int rhi = 50;
      while (rhi < 113) {
        float vv = dec(keys[rhi + 1]);
        if (vv >= v49 - FLAGW) rhi++; else break;
      }
      int w = rhi - cin + 1;
      if (w > CANDMAX) w = CANDMAX;
      if (cin + w < 50) w = 50 - cin;
      int slot = atomicAdd(fcnt, 1);
      frow[slot] = row;
      fcw[slot] = cin | (w << 8);
      s_slot = slot;
      s_cw = cin | (w << 8);
    }
    __syncthreads();
    int slot = s_slot;
    int tot = (s_cw & 255) + (s_cw >> 8);
    for (int r = tid; r < tot; r += 256) {
      unsigned long long kk = keys[r];
      fidx[(size_t)slot * WST + r] = (int)(unsigned)(kk & 0xFFFFFFFFull);
      fv32[(size_t)slot * WST + r] = dec(kk);
    }
    __syncthreads();
  }

  float vmax = dec(keys[0]);
  float e = 0.f;
  int myidx = 0;
  if (tid < TOPKK) {
    unsigned long long kk = keys[tid];
    myidx = (int)(unsigned)(kk & 0xFFFFFFFFull);
    e = expf((dec(kk) - vmax) * 0.125f);
  }
  float s = e;
  for (int off = 32; off > 0; off >>= 1) s += __shfl_down(s, off);
  if (tid == 0) sred = s;
  for (int m2 = tid; m2 < N; m2 += 256) outr[m2] = 0.2f * INITA[(size_t)n * N + m2];
  __syncthreads();
  if (tid < TOPKK) outr[myidx] = 0.2f * INITA[(size_t)n * N + myidx] + 0.8f * (e / sred);
  __syncthreads();
  for (int m2 = tid; m2 < N; m2 += 256) arow[m2] = outr[m2];
}

// -------- fixup: fv32 ranking + minimax mass-split at near-tied boundaries --------
__global__ __launch_bounds__(256) void k_fixup(float* __restrict__ ATT, const float* __restrict__ INITA,
                                               const int* __restrict__ fcnt, const int* __restrict__ frow,
                                               const int* __restrict__ fcw, const int* __restrict__ fidx,
                                               const float* __restrict__ fv32) {
  __shared__ double wts[56];
  __shared__ int mm[56];
  __shared__ int s_tot;
  int tid = threadIdx.x;
  int cnt = *fcnt;
  for (int slot = blockIdx.x; slot < cnt; slot += gridDim.x) {
    int row = frow[slot];
    int cw = fcw[slot];
    int cin = cw & 255, w = cw >> 8;
    int n = row % N;
    __syncthreads();
    if (tid == 0) {
      int need = 50 - cin;
      if (need > w) need = w;
      double cv[CANDMAX]; int cm[CANDMAX]; float cs[CANDMAX];
      for (int c = 0; c < w; c++) {
        float sv = fv32[(size_t)slot * WST + cin + c];
        cv[c] = (double)sv * 0.125;
        cm[c] = fidx[(size_t)slot * WST + cin + c];
        cs[c] = sv;
      }
      int ord[CANDMAX];
      for (int c = 0; c < w; c++) ord[c] = c;
      for (int a2 = 0; a2 < w; a2++) {
        int best = a2;
        for (int c2 = a2 + 1; c2 < w; c2++) {
          int i1 = ord[c2], i0 = ord[best];
          if (cv[i1] > cv[i0] || (cv[i1] == cv[i0] && cm[i1] < cm[i0])) best = c2;
        }
        int tswap = ord[a2]; ord[a2] = ord[best]; ord[best] = tswap;
      }
      double b_in = cv[ord[need - 1]];
      double b_out = (need < w) ? cv[ord[need]] : -1e300;
      const double DATT = 1e-3;
      double fac[56];
      int tot = 0;
      for (int r = 0; r < cin; r++) {
        wts[tot] = (double)fv32[(size_t)slot * WST + r];
        mm[tot] = fidx[(size_t)slot * WST + r];
        fac[tot++] = 1.0;
      }
      if (need == w || b_in - b_out > DATT) {
        for (int t3 = 0; t3 < need; t3++) {
          wts[tot] = (double)cs[ord[t3]];
          mm[tot] = cm[ord[t3]];
          fac[tot++] = 1.0;
        }
      } else {
        int gs = 0;
        while (gs < w && cv[ord[gs]] > b_in + DATT) gs++;
        int ge = w - 1;
        while (ge >= 0 && cv[ord[ge]] < b_out - DATT) ge--;
        double mid = 0.5 * (b_in + b_out);
        while (ge - gs + 1 > 3) {
          if (cv[ord[gs]] - mid >= mid - cv[ord[ge]]) gs++;
          else ge--;
        }
        int fullc = gs;
        int gcount = ge - gs + 1;
        int gneed = need - fullc;
        if (gneed < 0) gneed = 0;
        if (gneed > gcount) gneed = gcount;
        double frac = (gcount > 0) ? (double)gneed / (double)gcount : 0.0;
        for (int t3 = 0; t3 < fullc; t3++) {
          wts[tot] = (double)cs[ord[t3]];
          mm[tot] = cm[ord[t3]];
          fac[tot++] = 1.0;
        }
        for (int t3 = gs; t3 <= ge; t3++) {
          wts[tot] = (double)cs[ord[t3]];
          mm[tot] = cm[ord[t3]];
          fac[tot++] = frac;
        }
      }
      double vmax = -1e300;
      for (int r = 0; r < tot; r++)
        if (fac[r] > 0.0 && wts[r] > vmax) vmax = wts[r];
      double S = 0.0;
      for (int r = 0; r < tot; r++) {
        double e = fac[r] * exp((wts[r] - vmax) * 0.125);
        wts[r] = e;
        S += e;
      }
      double inv = 1.0 / S;
      for (int r = 0; r < tot; r++) wts[r] *= inv;
      s_tot = tot;
    }
    __syncthreads();
    int tot = s_tot;
    float* arow = ATT + (size_t)row * N;
    for (int m2 = tid; m2 < N; m2 += 256) arow[m2] = 0.2f * INITA[(size_t)n * N + m2];
    __syncthreads();
    if (tid < tot && wts[tid] > 0.0)
      arow[mm[tid]] = 0.2f * INITA[(size_t)n * N + mm[tid]] + 0.8f * (float)wts[tid];
    __syncthreads();
  }
}

// ---------------- GCN degree: two-stage coalesced ----------------
__global__ __launch_bounds__(256) void k_degp(const float* __restrict__ ADJ, float* __restrict__ DPART) {
  int ch = blockIdx.x, b = blockIdx.y;
  int tid = threadIdx.x;
  float reg[4] = {0.f, 0.f, 0.f, 0.f};
  int j0 = ch * 123, j1 = j0 + 123;
  if (j1 > N) j1 = N;
  const float* adj = ADJ + (size_t)b * N * N;
  for (int j = j0; j < j1; j++) {
    const float* rowp = adj + (size_t)j * N;
#pragma unroll
    for (int k = 0; k < 4; k++) {
      int i = tid + 256 * k;
      if (i < N) reg[k] += rowp[i];
    }
  }
  float* dp = DPART + ((size_t)b * 8 + ch) * N;
#pragma unroll
  for (int k = 0; k < 4; k++) {
    int i = tid + 256 * k;
    if (i < N) dp[i] = reg[k];
  }
}
__global__ void k_degf(const float* __restrict__ DPART, float* __restrict__ DINV) {
  int t = blockIdx.x * 256 + threadIdx.x;
  if (t >= M) return;
  int b = t / N, i = t - b * N;
  float s = 1.f;
#pragma unroll
  for (int c = 0; c < 8; c++) s += DPART[((size_t)b * 8 + c) * N + i];
  DINV[t] = rsqrtf(s);
}

// ---------------- spmm partial (F=128, j-split): PP[half] = sum_j norm-col part ----------------
// OUT(i,f) partial = sum_{j in half} (adj[j,i]+eye)*dinv[j]*X[b,j,f]; di and bias at combine.
__global__ __launch_bounds__(256) void k_spmmp(const float* __restrict__ ADJ, const float* __restrict__ DINV,
                                               const float* __restrict__ X, float* __restrict__ PP) {
  __shared__ float As[16][132];
  __shared__ float Ws[16][132];
  const int tid = threadIdx.x;
  const int i0 = blockIdx.x * 128;
  const int b = blockIdx.z >> 1;
  const int half = blockIdx.z & 1;
  const int jstart = half ? JSPLIT : 0;
  const int jend = half ? N : JSPLIT;
  const float* adj = ADJ + (size_t)b * N * N;
  const float* dv = DINV + b * N;
  const float* xb = X + (size_t)b * N * 128;
  const int ty = tid >> 4, tx = tid & 15;
  float acc[8][8];
#pragma unroll
  for (int i = 0; i < 8; i++)
#pragma unroll
    for (int j = 0; j < 8; j++) acc[i][j] = 0.f;

  for (int j0 = jstart; j0 < jend; j0 += 16) {
#pragma unroll
    for (int l = 0; l < 8; l++) {
      int idx = tid + l * 256;
      int r = idx >> 7, c = idx & 127;
      int j = j0 + r, i = i0 + c;
      float v = 0.f;
      if (j < jend && i < N) {
        float dj = dv[j];
        v = adj[(size_t)j * N + i] * dj;
        if (i == j) v += dj;
      }
      As[r][c] = v;
      float w = 0.f;
      if (j < jend) w = xb[(size_t)j * 128 + c];
      Ws[r][c] = w;
    }
    __syncthreads();
#pragma unroll
    for (int k = 0; k < 16; k++) {
      float a[8], bb[8];
      *reinterpret_cast<float4*>(&a[0]) = *reinterpret_cast<const float4*>(&As[k][ty * 8]);
      *reinterpret_cast<float4*>(&a[4]) = *reinterpret_cast<const float4*>(&As[k][ty * 8 + 4]);
      *reinterpret_cast<float4*>(&bb[0]) = *reinterpret_cast<const float4*>(&Ws[k][tx * 8]);
      *reinterpret_cast<float4*>(&bb[4]) = *reinterpret_cast<const float4*>(&Ws[k][tx * 8 + 4]);
#pragma unroll
      for (int i = 0; i < 8; i++)
#pragma unroll
        for (int j = 0; j < 8; j++) acc[i][j] = fmaf(a[i], bb[j], acc[i][j]);
    }
    __syncthreads();
  }
#pragma unroll
  for (int i = 0; i < 8; i++) {
    int row = i0 + ty * 8 + i;
    if (row >= N) continue;
#pragma unroll
    for (int j4 = 0; j4 < 2; j4++) {
      float4 v;
      float* vv = reinterpret_cast<float*>(&v);
#pragma unroll
      for (int j = 0; j < 4; j++) vv[j] = acc[i][j4 * 4 + j];
      *reinterpret_cast<float4*>(&PP[(((size_t)half * M) + (size_t)b * N + row) * 128 +
                                     tx * 8 + j4 * 4]) = v;
    }
  }
}

// combine: OUT = (PP0+PP1)*di + bias (fixed order, deterministic)
template <bool HASBIAS>
__global__ void k_spmmc(const float* __restrict__ PP, const float* __restrict__ DINV,
                        const float* __restrict__ bias, float* __restrict__ OUT) {
  int t = blockIdx.x * 256 + threadIdx.x;   // < M*128 exact (grid 7824)
  int row = t >> 7, f = t & 127;
  float v = (PP[t] + PP[(size_t)M * 128 + t]) * DINV[row];
  if (HASBIAS) v += bias[f];
  OUT[t] = v;
}

// ---------------- drug embed (fp32) ----------------
__global__ __launch_bounds__(256) void k_drug_l1(const float* __restrict__ d1, const float* __restrict__ d2,
                                                 const float* __restrict__ W, const float* __restrict__ bias,
                                                 float* __restrict__ T1) {
  __shared__ float row[DF];
  int blk = blockIdx.x;
  const float* dr = ((blk & 16) ? d2 : d1) + (size_t)(blk & 15) * DF;
  for (int i = threadIdx.x; i < DF; i += 256) row[i] = dr[i];
  __syncthreads();
  for (int e = threadIdx.x; e < 512; e += 256) {
    float s = bias[e];
    for (int k = 0; k < DF; k++) s = fmaf(row[k], W[(size_t)k * 512 + e], s);
    T1[(size_t)blk * 512 + e] = fmaxf(s, 0.f);
  }
}

__global__ __launch_bounds__(128) void k_drug_l2(const float* __restrict__ T1, const float* __restrict__ W,
                                                 const float* __restrict__ bias, const float* __restrict__ lg,
                                                 const float* __restrict__ lb, float* __restrict__ D) {
  __shared__ float row[512];
  __shared__ float red[4];
  int blk = blockIdx.x;
  int e = threadIdx.x;
  for (int i = e; i < 512; i += 128) row[i] = T1[(size_t)blk * 512 + i];
  __syncthreads();
  float s = bias[e];
  for (int k = 0; k < 512; k++) s = fmaf(row[k], W[k * 128 + e], s);
  float t = s;
  for (int off = 32; off > 0; off >>= 1) t += __shfl_down(t, off);
  if ((e & 63) == 0) red[e >> 6] = t;
  __syncthreads();
  float mean = (red[0] + red[1]) * (1.f / 128.f);
  float dd = s - mean;
  float wv = dd * dd;
  for (int off = 32; off > 0; off >>= 1) wv += __shfl_down(wv, off);
  if ((e & 63) == 0) red[2 + (e >> 6)] = wv;
  __syncthreads();
  float var = (red[2] + red[3]) * (1.f / 128.f);
  D[(size_t)blk * 128 + e] = dd * rsqrtf(var + 1e-5f) * lg[e] + lb[e];
}

// ---------------- head + decoder ----------------
__global__ void k_gemb(const float* __restrict__ NODE, float* __restrict__ GEMB) {
  int t = blockIdx.x * 256 + threadIdx.x;
  int b = t >> 7, f = t & 127;
  const float* p = NODE + (size_t)b * N * IB2 + f;
  float s = 0.f;
  for (int n2 = 0; n2 < N; n2++) s += p[(size_t)n2 * IB2];
  GEMB[t] = s * (1.f / (float)N);
}

__global__ void k_heads(const float* __restrict__ GEMB, const float* __restrict__ EPS,
                        float* __restrict__ out_mu, float* __restrict__ out_std, float* __restrict__ Z) {
  int t = blockIdx.x * 256 + threadIdx.x;
  int b = t >> 6, q = t & 63;
  float mu = GEMB[b * 128 + q];
  float xs = GEMB[b * 128 + 64 + q] - 64.f;
  float sp = (xs > 20.f) ? xs : log1pf(expf(xs));
  out_mu[t] = mu;
  out_std[t] = sp;
  Z[t] = mu + EPS[t] * sp;
}

__global__ __launch_bounds__(512) void k_dec1(const float* __restrict__ Z, const float* __restrict__ W1,
                                              const float* __restrict__ b1, const float* __restrict__ bg,
                                              const float* __restrict__ bb, float* __restrict__ DEC) {
  int f = threadIdx.x;
  float d[16];
  for (int b = 0; b < 16; b++) {
    float s = b1[f];
    for (int k = 0; k < 64; k++) s = fmaf(Z[b * 64 + k], W1[k * 512 + f], s);
    d[b] = s;
  }
  float m = 0.f;
  for (int b = 0; b < 16; b++) m += d[b];
  m *= (1.f / 16.f);
  float v = 0.f;
  for (int b = 0; b < 16; b++) { float t = d[b] - m; v += t * t; }
  v *= (1.f / 16.f);
  float sc = rsqrtf(v + 1e-5f) * bg[f];
  float sh = bb[f];
  for (int b = 0; b < 16; b++) {
    float x = (d[b] - m) * sc + sh;
    DEC[b * 512 + f] = fmaxf(x, 0.f);
  }
}

__global__ void k_dec2(const float* __restrict__ DEC, const float* __restrict__ W2,
                       const float* __restrict__ b2, float* __restrict__ X2) {
  int t = blockIdx.x * 256 + threadIdx.x;
  if (t >= M) return;
  int b = t / N, n2 = t - b * N;
  float s = b2[n2];
  const float* db = DEC + b * 512;
  for (int f = 0; f < 512; f++) s = fmaf(db[f], W2[(size_t)f * N + n2], s);
  X2[t] = fmaxf(s, 0.f);
}

}  // namespace

extern "C" void kernel_launch(void* const* d_in, const int* in_sizes, int n_in,
                              void* d_out, int out_size, void* d_ws, size_t ws_size,
                              hipStream_t stream) {
  const float* x1 = (const float*)d_in[0];
  const float* drug1 = (const float*)d_in[1];
  const float* drug2 = (const float*)d_in[2];
  const float* eps = (const float*)d_in[3];
  const int* ei = (const int*)d_in[4];
  const float* gate_W = (const float*)d_in[5];
  const float* gate_b = (const float*)d_in[6];
  const float* emb = (const float*)d_in[7];
  const float* encW1 = (const float*)d_in[8];
  const float* encb1 = (const float*)d_in[9];
  const float* encW2 = (const float*)d_in[10];
  const float* encb2 = (const float*)d_in[11];
  const float* netW1 = (const float*)d_in[12];
  const float* netb1 = (const float*)d_in[13];
  const float* netW2 = (const float*)d_in[14];
  const float* netb2 = (const float*)d_in[15];
  const float* ln_g = (const float*)d_in[16];
  const float* ln_b = (const float*)d_in[17];
  const float* feat_mask = (const float*)d_in[18];
  const float* W_sims = (const float*)d_in[19];
  const float* gcnW1 = (const float*)d_in[20];
  const float* gcnb1 = (const float*)d_in[21];
  const float* gcnW2 = (const float*)d_in[22];
  const float* gcnb2 = (const float*)d_in[23];
  const float* decW1 = (const float*)d_in[24];
  const float* decb1 = (const float*)d_in[25];
  const float* bn_g = (const float*)d_in[26];
  const float* bn_b = (const float*)d_in[27];
  const float* decW2 = (const float*)d_in[28];
  const float* decb2 = (const float*)d_in[29];
  (void)in_sizes; (void)n_in; (void)out_size; (void)ws_size;

  // Workspace layout (~188 MB; known-good <=192 MB)
  size_t o = 0;
  auto A = [&](size_t bytes) { char* p = (char*)d_ws + o; o += (bytes + 255) & ~(size_t)255; return p; };
  unsigned short* WTH = (unsigned short*)A((size_t)KATT * 256 * 2);  // 2 MB
  unsigned short* WTL = (unsigned short*)A((size_t)KATT * 256 * 2);  // 2 MB
  char* RBIG = A((size_t)64 * 1024 * 1024);                          // 64 MB
  float* Hb = (float*)A((size_t)M * 128 * 4);                        // 8 MB
  float* ADJ1 = (float*)A((size_t)B * N * N * 4);                    // 61 MB
  float* INITA = (float*)A((size_t)N * N * 4);                       // 3.8 MB
  float* T1 = (float*)A(32 * 512 * 4);
  float* Dd32 = (float*)A(32 * 128 * 4);
  float* DINV = (float*)A(M * 4);
  float* DPART = (float*)A((size_t)16 * 8 * N * 4);                  // 0.5 MB
  float* GEMB = (float*)A(B * 128 * 4);
  float* Zb = (float*)A(B * 64 * 4);
  float* DEC = (float*)A(B * 512 * 4);
  int* fcnt = (int*)A(256);
  float* MU = (float*)A((size_t)B * KCH * 4);                        // 64 KB
  double* qv = (double*)A((size_t)M * 8);
  unsigned short* FUSH = (unsigned short*)A((size_t)M * 256 * 2);    // 8 MB
  unsigned short* FUSL = (unsigned short*)A((size_t)M * 256 * 2);    // 8 MB
  unsigned short* CHB = (unsigned short*)A((size_t)M * KCH * 2);     // 30.6 MB

  // RBIG unions (phases don't overlap):
  //  encoder: buf1 | buf2
  //  g-loop chunks: CH (61.1 MB) ; after chunks (CH dead): FLAGS
  //  GCN: AGG (8MB) | PP (16MB @ +8MB) | Tt (32MB @ +32MB)
  float* buf1 = (float*)RBIG;
  float* buf2 = (float*)(RBIG + (size_t)32 * 1024 * 1024);
  float* CH = (float*)RBIG;
  char* FLAGS = RBIG;                          // alias CH: live only after chunk loop
  int* frow = (int*)FLAGS;
  int* fcw = (int*)(FLAGS + (size_t)M * 4);
  int* fidx = (int*)(FLAGS + (size_t)2 * M * 4);
  float* fv32 = (float*)(FLAGS + (size_t)2 * M * 4 + (size_t)M * WST * 4);
  float* AGG = (float*)RBIG;
  float* PP = (float*)(RBIG + (size_t)8 * 1024 * 1024);
  float* Tt = (float*)(RBIG + (size_t)32 * 1024 * 1024);
  float* TW2 = (float*)FUSH;                   // GCN phase: FUS dead
  float* NODE = (float*)FUSL;

  float* out = (float*)d_out;
  float* out_x2 = out;
  float* out_adj2 = out + M;
  float* out_mu = out + M + (size_t)B * N * N;
  float* out_std = out_mu + B * 64;

  k_wt<<<4096, 256, 0, stream>>>(W_sims, feat_mask, WTH, WTL);
  k_gate_emb<<<31296, 256, 0, stream>>>(x1, gate_W, gate_b, emb, buf1);
  k_gemm<1, true><<<dim3(123, 4), 256, 0, stream>>>(buf1, encW1, encb1, buf2, M, 512, 512, 512);
  k_gemm<0, true><<<dim3(123, 1), 256, 0, stream>>>(buf2, encW2, encb2, Hb, M, 512, 128, 128);
  k_drug_l1<<<32, 256, 0, stream>>>(drug1, drug2, netW1, netb1, T1);
  k_drug_l2<<<32, 128, 0, stream>>>(T1, netW2, netb2, ln_g, ln_b, Dd32);
  k_zero<<<(N * N + 255) / 256, 256, 0, stream>>>(INITA, N * N);
  k_scatter<<<(NEDGE + 255) / 256, 256, 0, stream>>>(ei, INITA);

  for (int g = 0; g < 2; g++) {
    float* att = (g == 0) ? ADJ1 : out_adj2;
    const float* DDg = Dd32 + (size_t)g * 16 * 128;
    hipMemsetAsync(fcnt, 0, 4, stream);
    hipMemsetAsync(qv, 0, (size_t)M * 8, stream);
    k_fus<<<15648, 256, 0, stream>>>(Hb, DDg, FUSH, FUSL);
    for (int c = 0; c < NCH; c++) {
      k_hp_mma<<<dim3(123, KCH / 128), 256, 0, stream>>>(FUSH, FUSL, WTH + (size_t)c * KCH * 256,
                                                         WTL + (size_t)c * KCH * 256, CH);
      k_mu<<<dim3(KCH / 32, 16), 256, 0, stream>>>(CH, MU);
      k_centerq<<<M / 4, 256, 0, stream>>>(CH, MU, CHB, qv);
      if (c == 0)
        k_syrk_mma<false><<<dim3(36, 16), 256, 0, stream>>>(CHB, att);
      else
        k_syrk_mma<true><<<dim3(36, 16), 256, 0, stream>>>(CHB, att);
    }
    k_topk<<<M, 256, 0, stream>>>(att, qv, INITA, fcnt, frow, fcw, fidx, fv32);
    k_fixup<<<1024, 256, 0, stream>>>(att, INITA, fcnt, frow, fcw, fidx, fv32);
  }

  k_degp<<<dim3(8, 16), 256, 0, stream>>>(ADJ1, DPART);
  k_degf<<<(M + 255) / 256, 256, 0, stream>>>(DPART, DINV);
  // GCN layer 1 (associativity: aggregate Hb first, then @W1)
  k_spmmp<<<dim3(8, 1, 32), 256, 0, stream>>>(ADJ1, DINV, Hb, PP);
  k_spmmc<false><<<(M * 128) / 256, 256, 0, stream>>>(PP, DINV, nullptr, AGG);
  k_gemm<2, true><<<dim3(123, 4), 256, 0, stream>>>(AGG, gcnW1, gcnb1, Tt, M, 128, 512, 512);
  // GCN layer 2
  k_gemm<0, false><<<dim3(123, 1), 256, 0, stream>>>(Tt, gcnW2, nullptr, TW2, M, 512, 128, 128);
  k_spmmp<<<dim3(8, 1, 32), 256, 0, stream>>>(ADJ1, DINV, TW2, PP);
  k_spmmc<true><<<(M * 128) / 256, 256, 0, stream>>>(PP, DINV, gcnb2, NODE);
  k_gemb<<<8, 256, 0, stream>>>(NODE, GEMB);
  k_heads<<<4, 256, 0, stream>>>(GEMB, eps, out_mu, out_std, Zb);
  k_dec1<<<1, 512, 0, stream>>>(Zb, decW1, decb1, bn_g, bn_b, DEC);
  k_dec2<<<(M + 255) / 256, 256, 0, stream>>>(DEC, decW2, decb2, out_x2);
}

// Round 14
// 3838.030 us; speedup vs baseline: 1.8150x; 1.0186x over previous
//
#include <hip/hip_runtime.h>
#include <cmath>

namespace {

constexpr int B = 16;
constexpr int N = 978;
constexpr int M = B * N;          // 15648
constexpr int IB2 = 128;          // 2*IB
constexpr int KATT = 4096;        // P*HID
constexpr int KCH = 1024;         // hp column chunk
constexpr int NCH = KATT / KCH;   // 4
constexpr int DF = 2304;
constexpr int TOPKK = 50;
constexpr int NEDGE = 50000;
constexpr int CANDMAX = 64;
constexpr int WST = 120;
constexpr int JSPLIT = 489;       // spmm j-split point

typedef __attribute__((ext_vector_type(8))) short bf16x8;
typedef __attribute__((ext_vector_type(4))) float f32x4;

__device__ __forceinline__ float geluf(float x) {
  return 0.5f * x * (1.f + erff(x * 0.7071067811865476f));
}
__device__ __forceinline__ float sigm(float x) { return 1.f / (1.f + expf(-x)); }
__device__ __forceinline__ double sigm64(double x) { return 1.0 / (1.0 + exp(-x)); }

__device__ __forceinline__ unsigned short f2bf(float f) {
  union { float f; unsigned u; } x; x.f = f;
  unsigned r = (x.u + 0x7FFFu + ((x.u >> 16) & 1u)) >> 16;
  return (unsigned short)r;
}
__device__ __forceinline__ float bf2f(unsigned short s) {
  union { float f; unsigned u; } x; x.u = ((unsigned)s) << 16; return x.f;
}

// ---------------- WT build: (4096 x 256) bf16 hi/lo of W_sims^T * sigm(fm) ----------------
__global__ void k_wt(const float* __restrict__ wsims, const float* __restrict__ fm,
                     unsigned short* __restrict__ wth, unsigned short* __restrict__ wtl) {
  int t = blockIdx.x * 256 + threadIdx.x;   // < 1048576 exact
  int n = t >> 8, k = t & 255;
  int p = n >> 9, h = n & 511;
  double v = (double)wsims[(size_t)p * 131072 + (size_t)k * 512 + h] * sigm64((double)fm[k]);
  float vf = (float)v;
  unsigned short hi = f2bf(vf);
  wth[t] = hi;
  wtl[t] = f2bf(vf - bf2f(hi));
}

// ---------------- generic W transpose-convert: out (Nc x K) bf16 hi/lo of W (K x Nc) ----------------
__global__ void k_wtrans(const float* __restrict__ W, unsigned short* __restrict__ TH,
                         unsigned short* __restrict__ TL, int K, int Nc) {
  int t = blockIdx.x * 256 + threadIdx.x;
  if (t >= K * Nc) return;
  int n = t / K, k = t - n * K;
  float v = W[(size_t)k * Nc + n];
  unsigned short hi = f2bf(v);
  TH[t] = hi;
  TL[t] = f2bf(v - bf2f(hi));
}

// ---------------- FUS build: (M x 256) bf16 hi/lo of [Hb | DDg] ----------------
__global__ void k_fus(const float* __restrict__ Hb, const float* __restrict__ DD,
                      unsigned short* __restrict__ fh, unsigned short* __restrict__ fl) {
  int t = blockIdx.x * 256 + threadIdx.x;   // < M*256 exact
  int k = t & 255;
  int row = t >> 8;
  int b = row / N;
  float v = (k < 128) ? Hb[(size_t)row * 128 + k] : DD[(size_t)b * 128 + (k - 128)];
  unsigned short hi = f2bf(v);
  fh[t] = hi;
  fl[t] = f2bf(v - bf2f(hi));
}

// ---------------- gate*emb -> bf16 hi/lo directly ----------------
__global__ void k_gate_emb_bf(const float* __restrict__ x1, const float* __restrict__ gW,
                              const float* __restrict__ gb, const float* __restrict__ emb,
                              unsigned short* __restrict__ GH, unsigned short* __restrict__ GL) {
  size_t t = (size_t)blockIdx.x * 256 + threadIdx.x;  // < M*512 exact
  int e = (int)(t & 511);
  size_t bn = t >> 9;
  int n = (int)(bn % N);
  float g = sigm(x1[bn] * gW[e] + gb[e]);
  float v = g * emb[(size_t)n * 512 + e];
  unsigned short hi = f2bf(v);
  GH[t] = hi;
  GL[t] = f2bf(v - bf2f(hi));
}

__global__ void k_zero(float* __restrict__ p, int n) {
  int t = blockIdx.x * 256 + threadIdx.x;
  if (t < n) p[t] = 0.f;
}

__global__ void k_scatter(const int* __restrict__ ei, float* __restrict__ adj) {
  int t = blockIdx.x * 256 + threadIdx.x;
  if (t < NEDGE) {
    int r = ei[t], c = ei[NEDGE + t];
    adj[(size_t)r * N + c] = 1.f;
  }
}

// ------- MFMA staging: 128x32 bf16 tile, XOR-swizzled ((r&7)<<4 on 64B rows) -------
__device__ __forceinline__ void stage_tile(const unsigned short* __restrict__ gbase, int grow0,
                                           int rowmax, int k0, int ldk, char* lds, int tid) {
#pragma unroll
  for (int it = 0; it < 2; it++) {
    int r = (tid >> 2) + it * 64;
    int c8 = tid & 3;
    int gr = grow0 + r;
    uint4 v = make_uint4(0u, 0u, 0u, 0u);
    if (gr < rowmax) v = *reinterpret_cast<const uint4*>(&gbase[(size_t)gr * ldk + k0 + c8 * 8]);
    int off = (r * 64 + c8 * 16) ^ ((r & 7) << 4);
    *reinterpret_cast<uint4*>(lds + off) = v;
  }
}

__device__ __forceinline__ bf16x8 frag(const char* lds, int r, int k8) {
  int off = (r * 64 + k8 * 16) ^ ((r & 7) << 4);
  return *reinterpret_cast<const bf16x8*>(lds + off);
}

// ------- generic split-bf16 MFMA GEMM: C = act(A@B + bias), A (Mm,K) hi/lo, BT (Nc,K) hi/lo
template <int ACT, bool HASBIAS, bool OUTF32, bool OUTBF>
__global__ __launch_bounds__(256) void k_mgemm(const unsigned short* __restrict__ AH,
                                               const unsigned short* __restrict__ AL,
                                               const unsigned short* __restrict__ BTH,
                                               const unsigned short* __restrict__ BTL,
                                               const float* __restrict__ bias,
                                               float* __restrict__ Cf,
                                               unsigned short* __restrict__ CbH,
                                               unsigned short* __restrict__ CbL,
                                               int Mm, int K, int Nc) {
  __shared__ __align__(16) char Ah[8192];
  __shared__ __align__(16) char Al[8192];
  __shared__ __align__(16) char Bh[8192];
  __shared__ __align__(16) char Bl[8192];
  const int m0 = blockIdx.x * 128;
  const int n0 = blockIdx.y * 128;
  const int tid = threadIdx.x;
  const int wave = tid >> 6, lane = tid & 63;
  f32x4 acc[2][8];
#pragma unroll
  for (int i = 0; i < 2; i++)
#pragma unroll
    for (int j = 0; j < 8; j++) acc[i][j] = (f32x4){0.f, 0.f, 0.f, 0.f};

  for (int k0 = 0; k0 < K; k0 += 32) {
    stage_tile(AH, m0, Mm, k0, K, Ah, tid);
    stage_tile(AL, m0, Mm, k0, K, Al, tid);
    stage_tile(BTH, n0, Nc, k0, K, Bh, tid);
    stage_tile(BTL, n0, Nc, k0, K, Bl, tid);
    __syncthreads();
    bf16x8 ah[2], al[2];
#pragma unroll
    for (int rf = 0; rf < 2; rf++) {
      int r = wave * 32 + rf * 16 + (lane & 15);
      ah[rf] = frag(Ah, r, lane >> 4);
      al[rf] = frag(Al, r, lane >> 4);
    }
#pragma unroll
    for (int cf = 0; cf < 8; cf++) {
      int rB = cf * 16 + (lane & 15);
      bf16x8 bh = frag(Bh, rB, lane >> 4);
      bf16x8 bl = frag(Bl, rB, lane >> 4);
#pragma unroll
      for (int rf = 0; rf < 2; rf++) {
        acc[rf][cf] = __builtin_amdgcn_mfma_f32_16x16x32_bf16(ah[rf], bh, acc[rf][cf], 0, 0, 0);
        acc[rf][cf] = __builtin_amdgcn_mfma_f32_16x16x32_bf16(ah[rf], bl, acc[rf][cf], 0, 0, 0);
        acc[rf][cf] = __builtin_amdgcn_mfma_f32_16x16x32_bf16(al[rf], bh, acc[rf][cf], 0, 0, 0);
      }
    }
    __syncthreads();
  }
#pragma unroll
  for (int rf = 0; rf < 2; rf++)
#pragma unroll
    for (int cf = 0; cf < 8; cf++)
#pragma unroll
      for (int r4 = 0; r4 < 4; r4++) {
        int row = m0 + wave * 32 + rf * 16 + ((lane >> 4) << 2) + r4;
        int col = n0 + cf * 16 + (lane & 15);
        if (row < Mm) {
          float v = acc[rf][cf][r4];
          if (HASBIAS) v += bias[col];
          if (ACT == 1) v = geluf(v);
          if (ACT == 2) v = fmaxf(v, 0.f);
          size_t idx = (size_t)row * Nc + col;
          if (OUTF32) Cf[idx] = v;
          if (OUTBF) {
            unsigned short hi = f2bf(v);
            CbH[idx] = hi;
            CbL[idx] = f2bf(v - bf2f(hi));
          }
        }
      }
}

// ------- hp chunk GEMM, split-bf16 (fp32-equivalent): CH = relu(FUS @ WT_chunk^T) -------
__global__ __launch_bounds__(256) void k_hp_mma(const unsigned short* __restrict__ FH,
                                                const unsigned short* __restrict__ FL,
                                                const unsigned short* __restrict__ WTHc,
                                                const unsigned short* __restrict__ WTLc,
                                                float* __restrict__ CH) {
  __shared__ __align__(16) char Ah[8192];
  __shared__ __align__(16) char Al[8192];
  __shared__ __align__(16) char Bh[8192];
  __shared__ __align__(16) char Bl[8192];
  const int m0 = blockIdx.x * 128;
  const int n0 = blockIdx.y * 128;   // within chunk (KCH)
  const int tid = threadIdx.x;
  const int wave = tid >> 6, lane = tid & 63;
  f32x4 acc[2][8];
#pragma unroll
  for (int i = 0; i < 2; i++)
#pragma unroll
    for (int j = 0; j < 8; j++) acc[i][j] = (f32x4){0.f, 0.f, 0.f, 0.f};

  for (int k0 = 0; k0 < 256; k0 += 32) {
    stage_tile(FH, m0, M, k0, 256, Ah, tid);
    stage_tile(FL, m0, M, k0, 256, Al, tid);
    stage_tile(WTHc, n0, KCH, k0, 256, Bh, tid);
    stage_tile(WTLc, n0, KCH, k0, 256, Bl, tid);
    __syncthreads();
    bf16x8 ah[2], al[2];
#pragma unroll
    for (int rf = 0; rf < 2; rf++) {
      int r = wave * 32 + rf * 16 + (lane & 15);
      ah[rf] = frag(Ah, r, lane >> 4);
      al[rf] = frag(Al, r, lane >> 4);
    }
#pragma unroll
    for (int cf = 0; cf < 8; cf++) {
      int rB = cf * 16 + (lane & 15);
      bf16x8 bh = frag(Bh, rB, lane >> 4);
      bf16x8 bl = frag(Bl, rB, lane >> 4);
#pragma unroll
      for (int rf = 0; rf < 2; rf++) {
        acc[rf][cf] = __builtin_amdgcn_mfma_f32_16x16x32_bf16(ah[rf], bh, acc[rf][cf], 0, 0, 0);
        acc[rf][cf] = __builtin_amdgcn_mfma_f32_16x16x32_bf16(ah[rf], bl, acc[rf][cf], 0, 0, 0);
        acc[rf][cf] = __builtin_amdgcn_mfma_f32_16x16x32_bf16(al[rf], bh, acc[rf][cf], 0, 0, 0);
      }
    }
    __syncthreads();
  }
#pragma unroll
  for (int rf = 0; rf < 2; rf++)
#pragma unroll
    for (int cf = 0; cf < 8; cf++)
#pragma unroll
      for (int r4 = 0; r4 < 4; r4++) {
        int row = m0 + wave * 32 + rf * 16 + ((lane >> 4) << 2) + r4;
        int col = n0 + cf * 16 + (lane & 15);
        if (row < M) CH[(size_t)row * KCH + col] = fmaxf(acc[rf][cf][r4], 0.f);
      }
}

// ---------------- per-chunk column means (parallel, deterministic) ----------------
__global__ __launch_bounds__(256) void k_mu(const float* __restrict__ CH, float* __restrict__ MU) {
  __shared__ double red[8][33];
  int b = blockIdx.y, jg = blockIdx.x;
  int jloc = threadIdx.x & 31, s = threadIdx.x >> 5;
  int j = jg * 32 + jloc;
  const float* p = CH + (size_t)b * N * KCH + j;
  double acc = 0.0;
  for (int n = s; n < N; n += 8) acc += (double)p[(size_t)n * KCH];
  red[s][jloc] = acc;
  __syncthreads();
  if (s == 0) {
    double t = 0.0;
#pragma unroll
    for (int k = 0; k < 8; k++) t += red[k][jloc];
    MU[b * KCH + j] = (float)(t * (1.0 / (double)N));
  }
}

// ------- fused center+q: CHB = bf16(CH - MU); qv[r] += <MU[b], CH[r]> (f64) -------
__global__ __launch_bounds__(256) void k_centerq(const float* __restrict__ CH,
                                                 const float* __restrict__ MU,
                                                 unsigned short* __restrict__ CHB,
                                                 double* __restrict__ qv) {
  int r = blockIdx.x * 4 + (threadIdx.x >> 6);   // grid = M/4 = 3912 exact
  int lane = threadIdx.x & 63;
  int b = r / N;
  const float* row = CH + (size_t)r * KCH;
  const float* mu = MU + (size_t)b * KCH;
  double q = 0.0;
#pragma unroll
  for (int jp = 0; jp < 2; jp++) {
    int j0 = lane * 8 + jp * 512;
    float4 v0 = *reinterpret_cast<const float4*>(&row[j0]);
    float4 v1 = *reinterpret_cast<const float4*>(&row[j0 + 4]);
    float4 m0 = *reinterpret_cast<const float4*>(&mu[j0]);
    float4 m1 = *reinterpret_cast<const float4*>(&mu[j0 + 4]);
    unsigned short cb[8];
    cb[0] = f2bf(v0.x - m0.x); cb[1] = f2bf(v0.y - m0.y);
    cb[2] = f2bf(v0.z - m0.z); cb[3] = f2bf(v0.w - m0.w);
    cb[4] = f2bf(v1.x - m1.x); cb[5] = f2bf(v1.y - m1.y);
    cb[6] = f2bf(v1.z - m1.z); cb[7] = f2bf(v1.w - m1.w);
    *reinterpret_cast<uint4*>(&CHB[(size_t)r * KCH + j0]) = *reinterpret_cast<uint4*>(cb);
    q += (double)m0.x * v0.x + (double)m0.y * v0.y + (double)m0.z * v0.z + (double)m0.w * v0.w
       + (double)m1.x * v1.x + (double)m1.y * v1.y + (double)m1.z * v1.z + (double)m1.w * v1.w;
  }
  for (int off = 32; off > 0; off >>= 1) q += __shfl_down(q, off);
  if (lane == 0) qv[r] += q;
}

// ------- centered Gram via bf16 MFMA: G[b] (+)= CHBc @ CHBc^T -------
template <bool ACC>
__global__ __launch_bounds__(256) void k_syrk_mma(const unsigned short* __restrict__ CHB,
                                                  float* __restrict__ ATT) {
  __shared__ __align__(16) char At[8192];
  __shared__ __align__(16) char Bt[8192];
  const int T = 8;
  int pr = blockIdx.x;
  int ti = 0, rem = pr;
  while (rem >= T - ti) { rem -= T - ti; ti++; }
  int tj = ti + rem;
  int b = blockIdx.y;
  const unsigned short* base = CHB + (size_t)b * N * KCH;
  const int tid = threadIdx.x;
  const int wave = tid >> 6, lane = tid & 63;
  f32x4 acc[2][8];
#pragma unroll
  for (int i = 0; i < 2; i++)
#pragma unroll
    for (int j = 0; j < 8; j++) acc[i][j] = (f32x4){0.f, 0.f, 0.f, 0.f};

  for (int k0 = 0; k0 < KCH; k0 += 32) {
    stage_tile(base, ti * 128, N, k0, KCH, At, tid);
    stage_tile(base, tj * 128, N, k0, KCH, Bt, tid);
    __syncthreads();
    bf16x8 af[2];
#pragma unroll
    for (int rf = 0; rf < 2; rf++)
      af[rf] = frag(At, wave * 32 + rf * 16 + (lane & 15), lane >> 4);
#pragma unroll
    for (int cf = 0; cf < 8; cf++) {
      bf16x8 bf_ = frag(Bt, cf * 16 + (lane & 15), lane >> 4);
#pragma unroll
      for (int rf = 0; rf < 2; rf++)
        acc[rf][cf] = __builtin_amdgcn_mfma_f32_16x16x32_bf16(af[rf], bf_, acc[rf][cf], 0, 0, 0);
    }
    __syncthreads();
  }
  float* att = ATT + (size_t)b * N * N;
#pragma unroll
  for (int rf = 0; rf < 2; rf++)
#pragma unroll
    for (int cf = 0; cf < 8; cf++)
#pragma unroll
      for (int r4 = 0; r4 < 4; r4++) {
        int row = ti * 128 + wave * 32 + rf * 16 + ((lane >> 4) << 2) + r4;
        int col = tj * 128 + cf * 16 + (lane & 15);
        if (row < N && col < N) {
          float v = acc[rf][cf][r4];
          if (ACC) {
            att[(size_t)row * N + col] += v;
            if (ti != tj) att[(size_t)col * N + row] += v;
          } else {
            att[(size_t)row * N + col] = v;
            if (ti != tj) att[(size_t)col * N + row] = v;
          }
        }
      }
}

// -------- top-50 on s = G + q_m - q_n, softmax(s/8), flagging --------
// Register-resident bitonic: 256 thr x 4 elements; j>=256 in-thread, j<=32 shfl_xor,
// j in {64,128} via LDS (14 barriers). Bit-identical to full-barrier network.
__global__ __launch_bounds__(256) void k_topk(float* __restrict__ ATT, const double* __restrict__ qv,
                                              const float* __restrict__ INITA,
                                              int* __restrict__ fcnt, int* __restrict__ frow,
                                              int* __restrict__ fcw, int* __restrict__ fidx,
                                              float* __restrict__ fv32) {
  int row = blockIdx.x;  // b*N + n
  int n = row % N;
  int b = row / N;
  float* arow = ATT + (size_t)row * N;
  __shared__ unsigned long long keys[1024];
  __shared__ float outr[N];
  __shared__ float sred;
  __shared__ int s_slot, s_cw;
  int tid = threadIdx.x;
  double qn = qv[row];
  unsigned long long kreg[4];
#pragma unroll
  for (int c = 0; c < 4; c++) {
    int i = tid + 256 * c;
    unsigned long long kk = 0xFFFFFFFFFFFFFFFFull;
    if (i < N) {
      float sv = (float)((double)arow[i] + qv[(size_t)b * N + i] - qn);
      unsigned u = __float_as_uint(sv);
      u ^= (u >> 31) ? 0xFFFFFFFFu : 0x80000000u;
      kk = ((unsigned long long)(~u) << 32) | (unsigned)i;
    }
    kreg[c] = kk;
  }
  for (int ksz = 2; ksz <= 1024; ksz <<= 1) {
    for (int j = ksz >> 1; j > 0; j >>= 1) {
      if (j <= 32) {
#pragma unroll
        for (int c = 0; c < 4; c++) {
          int e = tid + 256 * c;
          unsigned long long pk = __shfl_xor(kreg[c], j);
          bool takemin = (((e & j) == 0) == ((e & ksz) == 0));
          unsigned long long mn = kreg[c] < pk ? kreg[c] : pk;
          unsigned long long mx = kreg[c] < pk ? pk : kreg[c];
          kreg[c] = takemin ? mn : mx;
        }
      } else if (j >= 256) {
        int sw = j >> 8;
#pragma unroll
        for (int c = 0; c < 4; c++) {
          if ((c & sw) == 0) {
            int e = tid + 256 * c;
            bool up = (e & ksz) == 0;
            unsigned long long a = kreg[c], b2 = kreg[c | sw];
            if ((a > b2) == up) { kreg[c] = b2; kreg[c | sw] = a; }
          }
        }
      } else {
#pragma unroll
        for (int c = 0; c < 4; c++) keys[tid + 256 * c] = kreg[c];
        __syncthreads();
#pragma unroll
        for (int c = 0; c < 4; c++) {
          int e = tid + 256 * c;
          unsigned long long pk = keys[e ^ j];
          bool takemin = (((e & j) == 0) == ((e & ksz) == 0));
          unsigned long long mn = kreg[c] < pk ? kreg[c] : pk;
          unsigned long long mx = kreg[c] < pk ? pk : kreg[c];
          kreg[c] = takemin ? mn : mx;
        }
        __syncthreads();
      }
    }
  }
#pragma unroll
  for (int c = 0; c < 4; c++) keys[tid + 256 * c] = kreg[c];
  __syncthreads();
  auto dec = [](unsigned long long kk) {
    unsigned y = ~(unsigned)(kk >> 32);
    unsigned u = (y & 0x80000000u) ? (y ^ 0x80000000u) : ~y;
    return __uint_as_float(u);
  };

  float v49 = dec(keys[49]);
  float v50v = dec(keys[50]);
  float FLAGW = 8e-3f + 2e-5f * fabsf(v49);   // s-units
  bool flag = (v50v >= v49 - FLAGW);
  if (flag) {
    if (tid == 0) {
      int cin = 0;
      for (int r = 0; r < 50; r++)
        if (dec(keys[r]) > v49 + FLAGW) cin++;
      int rhi = 50;
      while (rhi < 113) {
        float vv = dec(keys[rhi + 1]);
        if (vv >= v49 - FLAGW) rhi++; else break;
      }
      int w = rhi - cin + 1;
      if (w > CANDMAX) w = CANDMAX;
      if (cin + w < 50) w = 50 - cin;
      int slot = atomicAdd(fcnt, 1);
      frow[slot] = row;
      fcw[slot] = cin | (w << 8);
      s_slot = slot;
      s_cw = cin | (w << 8);
    }
    __syncthreads();
    int slot = s_slot;
    int tot = (s_cw & 255) + (s_cw >> 8);
    for (int r = tid; r < tot; r += 256) {
      unsigned long long kk = keys[r];
      fidx[(size_t)slot * WST + r] = (int)(unsigned)(kk & 0xFFFFFFFFull);
      fv32[(size_t)slot * WST + r] = dec(kk);
    }
    __syncthreads();
  }

  float vmax = dec(keys[0]);
  float e = 0.f;
  int myidx = 0;
  if (tid < TOPKK) {
    unsigned long long kk = keys[tid];
    myidx = (int)(unsigned)(kk & 0xFFFFFFFFull);
    e = expf((dec(kk) - vmax) * 0.125f);
  }
  float s = e;
  for (int off = 32; off > 0; off >>= 1) s += __shfl_down(s, off);
  if (tid == 0) sred = s;
  for (int m2 = tid; m2 < N; m2 += 256) outr[m2] = 0.2f * INITA[(size_t)n * N + m2];
  __syncthreads();
  if (tid < TOPKK) outr[myidx] = 0.2f * INITA[(size_t)n * N + myidx] + 0.8f * (e / sred);
  __syncthreads();
  for (int m2 = tid; m2 < N; m2 += 256) arow[m2] = outr[m2];
}

// -------- fixup: fv32 ranking + minimax mass-split at near-tied boundaries --------
__global__ __launch_bounds__(256) void k_fixup(float* __restrict__ ATT, const float* __restrict__ INITA,
                                               const int* __restrict__ fcnt, const int* __restrict__ frow,
                                               const int* __restrict__ fcw, const int* __restrict__ fidx,
                                               const float* __restrict__ fv32) {
  __shared__ double wts[56];
  __shared__ int mm[56];
  __shared__ int s_tot;
  int tid = threadIdx.x;
  int cnt = *fcnt;
  for (int slot = blockIdx.x; slot < cnt; slot += gridDim.x) {
    int row = frow[slot];
    int cw = fcw[slot];
    int cin = cw & 255, w = cw >> 8;
    int n = row % N;
    __syncthreads();
    if (tid == 0) {
      int need = 50 - cin;
      if (need > w) need = w;
      double cv[CANDMAX]; int cm[CANDMAX]; float cs[CANDMAX];
      for (int c = 0; c < w; c++) {
        float sv = fv32[(size_t)slot * WST + cin + c];
        cv[c] = (double)sv * 0.125;
        cm[c] = fidx[(size_t)slot * WST + cin + c];
        cs[c] = sv;
      }
      int ord[CANDMAX];
      for (int c = 0; c < w; c++) ord[c] = c;
      for (int a2 = 0; a2 < w; a2++) {
        int best = a2;
        for (int c2 = a2 + 1; c2 < w; c2++) {
          int i1 = ord[c2], i0 = ord[best];
          if (cv[i1] > cv[i0] || (cv[i1] == cv[i0] && cm[i1] < cm[i0])) best = c2;
        }
        int tswap = ord[a2]; ord[a2] = ord[best]; ord[best] = tswap;
      }
      double b_in = cv[ord[need - 1]];
      double b_out = (need < w) ? cv[ord[need]] : -1e300;
      const double DATT = 1e-3;
      double fac[56];
      int tot = 0;
      for (int r = 0; r < cin; r++) {
        wts[tot] = (double)fv32[(size_t)slot * WST + r];
        mm[tot] = fidx[(size_t)slot * WST + r];
        fac[tot++] = 1.0;
      }
      if (need == w || b_in - b_out > DATT) {
        for (int t3 = 0; t3 < need; t3++) {
          wts[tot] = (double)cs[ord[t3]];
          mm[tot] = cm[ord[t3]];
          fac[tot++] = 1.0;
        }
      } else {
        int gs = 0;
        while (gs < w && cv[ord[gs]] > b_in + DATT) gs++;
        int ge = w - 1;
        while (ge >= 0 && cv[ord[ge]] < b_out - DATT) ge--;
        double mid = 0.5 * (b_in + b_out);
        while (ge - gs + 1 > 3) {
          if (cv[ord[gs]] - mid >= mid - cv[ord[ge]]) gs++;
          else ge--;
        }
        int fullc = gs;
        int gcount = ge - gs + 1;
        int gneed = need - fullc;
        if (gneed < 0) gneed = 0;
        if (gneed > gcount) gneed = gcount;
        double frac = (gcount > 0) ? (double)gneed / (double)gcount : 0.0;
        for (int t3 = 0; t3 < fullc; t3++) {
          wts[tot] = (double)cs[ord[t3]];
          mm[tot] = cm[ord[t3]];
          fac[tot++] = 1.0;
        }
        for (int t3 = gs; t3 <= ge; t3++) {
          wts[tot] = (double)cs[ord[t3]];
          mm[tot] = cm[ord[t3]];
          fac[tot++] = frac;
        }
      }
      double vmax = -1e300;
      for (int r = 0; r < tot; r++)
        if (fac[r] > 0.0 && wts[r] > vmax) vmax = wts[r];
      double S = 0.0;
      for (int r = 0; r < tot; r++) {
        double e = fac[r] * exp((wts[r] - vmax) * 0.125);
        wts[r] = e;
        S += e;
      }
      double inv = 1.0 / S;
      for (int r = 0; r < tot; r++) wts[r] *= inv;
      s_tot = tot;
    }
    __syncthreads();
    int tot = s_tot;
    float* arow = ATT + (size_t)row * N;
    for (int m2 = tid; m2 < N; m2 += 256) arow[m2] = 0.2f * INITA[(size_t)n * N + m2];
    __syncthreads();
    if (tid < tot && wts[tid] > 0.0)
      arow[mm[tid]] = 0.2f * INITA[(size_t)n * N + mm[tid]] + 0.8f * (float)wts[tid];
    __syncthreads();
  }
}

// ---------------- GCN degree: two-stage coalesced ----------------
__global__ __launch_bounds__(256) void k_degp(const float* __restrict__ ADJ, float* __restrict__ DPART) {
  int ch = blockIdx.x, b = blockIdx.y;
  int tid = threadIdx.x;
  float reg[4] = {0.f, 0.f, 0.f, 0.f};
  int j0 = ch * 123, j1 = j0 + 123;
  if (j1 > N) j1 = N;
  const float* adj = ADJ + (size_t)b * N * N;
  for (int j = j0; j < j1; j++) {
    const float* rowp = adj + (size_t)j * N;
#pragma unroll
    for (int k = 0; k < 4; k++) {
      int i = tid + 256 * k;
      if (i < N) reg[k] += rowp[i];
    }
  }
  float* dp = DPART + ((size_t)b * 8 + ch) * N;
#pragma unroll
  for (int k = 0; k < 4; k++) {
    int i = tid + 256 * k;
    if (i < N) dp[i] = reg[k];
  }
}
__global__ void k_degf(const float* __restrict__ DPART, float* __restrict__ DINV) {
  int t = blockIdx.x * 256 + threadIdx.x;
  if (t >= M) return;
  int b = t / N, i = t - b * N;
  float s = 1.f;
#pragma unroll
  for (int c = 0; c < 8; c++) s += DPART[((size_t)b * 8 + c) * N + i];
  DINV[t] = rsqrtf(s);
}

// ---------------- spmm partial (F=128, j-split) ----------------
__global__ __launch_bounds__(256) void k_spmmp(const float* __restrict__ ADJ, const float* __restrict__ DINV,
                                               const float* __restrict__ X, float* __restrict__ PP) {
  __shared__ float As[16][132];
  __shared__ float Ws[16][132];
  const int tid = threadIdx.x;
  const int i0 = blockIdx.x * 128;
  const int b = blockIdx.z >> 1;
  const int half = blockIdx.z & 1;
  const int jstart = half ? JSPLIT : 0;
  const int jend = half ? N : JSPLIT;
  const float* adj = ADJ + (size_t)b * N * N;
  const float* dv = DINV + b * N;
  const float* xb = X + (size_t)b * N * 128;
  const int ty = tid >> 4, tx = tid & 15;
  float acc[8][8];
#pragma unroll
  for (int i = 0; i < 8; i++)
#pragma unroll
    for (int j = 0; j < 8; j++) acc[i][j] = 0.f;

  for (int j0 = jstart; j0 < jend; j0 += 16) {
#pragma unroll
    for (int l = 0; l < 8; l++) {
      int idx = tid + l * 256;
      int r = idx >> 7, c = idx & 127;
      int j = j0 + r, i = i0 + c;
      float v = 0.f;
      if (j < jend && i < N) {
        float dj = dv[j];
        v = adj[(size_t)j * N + i] * dj;
        if (i == j) v += dj;
      }
      As[r][c] = v;
      float w = 0.f;
      if (j < jend) w = xb[(size_t)j * 128 + c];
      Ws[r][c] = w;
    }
    __syncthreads();
#pragma unroll
    for (int k = 0; k < 16; k++) {
      float a[8], bb[8];
      *reinterpret_cast<float4*>(&a[0]) = *reinterpret_cast<const float4*>(&As[k][ty * 8]);
      *reinterpret_cast<float4*>(&a[4]) = *reinterpret_cast<const float4*>(&As[k][ty * 8 + 4]);
      *reinterpret_cast<float4*>(&bb[0]) = *reinterpret_cast<const float4*>(&Ws[k][tx * 8]);
      *reinterpret_cast<float4*>(&bb[4]) = *reinterpret_cast<const float4*>(&Ws[k][tx * 8 + 4]);
#pragma unroll
      for (int i = 0; i < 8; i++)
#pragma unroll
        for (int j = 0; j < 8; j++) acc[i][j] = fmaf(a[i], bb[j], acc[i][j]);
    }
    __syncthreads();
  }
#pragma unroll
  for (int i = 0; i < 8; i++) {
    int row = i0 + ty * 8 + i;
    if (row >= N) continue;
#pragma unroll
    for (int j4 = 0; j4 < 2; j4++) {
      float4 v;
      float* vv = reinterpret_cast<float*>(&v);
#pragma unroll
      for (int j = 0; j < 4; j++) vv[j] = acc[i][j4 * 4 + j];
      *reinterpret_cast<float4*>(&PP[(((size_t)half * M) + (size_t)b * N + row) * 128 +
                                     tx * 8 + j4 * 4]) = v;
    }
  }
}

// combine: v = (PP0+PP1)*di (+bias); OUTBF -> bf16 hi/lo, else fp32
template <bool HASBIAS, bool OUTBF>
__global__ void k_spmmc(const float* __restrict__ PP, const float* __restrict__ DINV,
                        const float* __restrict__ bias, float* __restrict__ OUT,
                        unsigned short* __restrict__ OH, unsigned short* __restrict__ OL) {
  int t = blockIdx.x * 256 + threadIdx.x;   // < M*128 exact
  int row = t >> 7, f = t & 127;
  float v = (PP[t] + PP[(size_t)M * 128 + t]) * DINV[row];
  if (HASBIAS) v += bias[f];
  if (OUTBF) {
    unsigned short hi = f2bf(v);
    OH[t] = hi;
    OL[t] = f2bf(v - bf2f(hi));
  } else {
    OUT[t] = v;
  }
}

// ---------------- drug embed (fp32) ----------------
__global__ __launch_bounds__(256) void k_drug_l1(const float* __restrict__ d1, const float* __restrict__ d2,
                                                 const float* __restrict__ W, const float* __restrict__ bias,
                                                 float* __restrict__ T1) {
  __shared__ float row[DF];
  int blk = blockIdx.x;
  const float* dr = ((blk & 16) ? d2 : d1) + (size_t)(blk & 15) * DF;
  for (int i = threadIdx.x; i < DF; i += 256) row[i] = dr[i];
  __syncthreads();
  for (int e = threadIdx.x; e < 512; e += 256) {
    float s = bias[e];
    for (int k = 0; k < DF; k++) s = fmaf(row[k], W[(size_t)k * 512 + e], s);
    T1[(size_t)blk * 512 + e] = fmaxf(s, 0.f);
  }
}

__global__ __launch_bounds__(128) void k_drug_l2(const float* __restrict__ T1, const float* __restrict__ W,
                                                 const float* __restrict__ bias, const float* __restrict__ lg,
                                                 const float* __restrict__ lb, float* __restrict__ D) {
  __shared__ float row[512];
  __shared__ float red[4];
  int blk = blockIdx.x;
  int e = threadIdx.x;
  for (int i = e; i < 512; i += 128) row[i] = T1[(size_t)blk * 512 + i];
  __syncthreads();
  float s = bias[e];
  for (int k = 0; k < 512; k++) s = fmaf(row[k], W[k * 128 + e], s);
  float t = s;
  for (int off = 32; off > 0; off >>= 1) t += __shfl_down(t, off);
  if ((e & 63) == 0) red[e >> 6] = t;
  __syncthreads();
  float mean = (red[0] + red[1]) * (1.f / 128.f);
  float dd = s - mean;
  float wv = dd * dd;
  for (int off = 32; off > 0; off >>= 1) wv += __shfl_down(wv, off);
  if ((e & 63) == 0) red[2 + (e >> 6)] = wv;
  __syncthreads();
  float var = (red[2] + red[3]) * (1.f / 128.f);
  D[(size_t)blk * 128 + e] = dd * rsqrtf(var + 1e-5f) * lg[e] + lb[e];
}

// ---------------- head + decoder ----------------
__global__ void k_gemb(const float* __restrict__ NODE, float* __restrict__ GEMB) {
  int t = blockIdx.x * 256 + threadIdx.x;
  int b = t >> 7, f = t & 127;
  const float* p = NODE + (size_t)b * N * IB2 + f;
  float s = 0.f;
  for (int n2 = 0; n2 < N; n2++) s += p[(size_t)n2 * IB2];
  GEMB[t] = s * (1.f / (float)N);
}

__global__ void k_heads(const float* __restrict__ GEMB, const float* __restrict__ EPS,
                        float* __restrict__ out_mu, float* __restrict__ out_std, float* __restrict__ Z) {
  int t = blockIdx.x * 256 + threadIdx.x;
  int b = t >> 6, q = t & 63;
  float mu = GEMB[b * 128 + q];
  float xs = GEMB[b * 128 + 64 + q] - 64.f;
  float sp = (xs > 20.f) ? xs : log1pf(expf(xs));
  out_mu[t] = mu;
  out_std[t] = sp;
  Z[t] = mu + EPS[t] * sp;
}

__global__ __launch_bounds__(512) void k_dec1(const float* __restrict__ Z, const float* __restrict__ W1,
                                              const float* __restrict__ b1, const float* __restrict__ bg,
                                              const float* __restrict__ bb, float* __restrict__ DEC) {
  int f = threadIdx.x;
  float d[16];
  for (int b = 0; b < 16; b++) {
    float s = b1[f];
    for (int k = 0; k < 64; k++) s = fmaf(Z[b * 64 + k], W1[k * 512 + f], s);
    d[b] = s;
  }
  float m = 0.f;
  for (int b = 0; b < 16; b++) m += d[b];
  m *= (1.f / 16.f);
  float v = 0.f;
  for (int b = 0; b < 16; b++) { float t = d[b] - m; v += t * t; }
  v *= (1.f / 16.f);
  float sc = rsqrtf(v + 1e-5f) * bg[f];
  float sh = bb[f];
  for (int b = 0; b < 16; b++) {
    float x = (d[b] - m) * sc + sh;
    DEC[b * 512 + f] = fmaxf(x, 0.f);
  }
}

__global__ void k_dec2(const float* __restrict__ DEC, const float* __restrict__ W2,
                       const float* __restrict__ b2, float* __restrict__ X2) {
  int t = blockIdx.x * 256 + threadIdx.x;
  if (t >= M) return;
  int b = t / N, n2 = t - b * N;
  float s = b2[n2];
  const float* db = DEC + b * 512;
  for (int f = 0; f < 512; f++) s = fmaf(db[f], W2[(size_t)f * N + n2], s);
  X2[t] = fmaxf(s, 0.f);
}

}  // namespace

extern "C" void kernel_launch(void* const* d_in, const int* in_sizes, int n_in,
                              void* d_out, int out_size, void* d_ws, size_t ws_size,
                              hipStream_t stream) {
  const float* x1 = (const float*)d_in[0];
  const float* drug1 = (const float*)d_in[1];
  const float* drug2 = (const float*)d_in[2];
  const float* eps = (const float*)d_in[3];
  const int* ei = (const int*)d_in[4];
  const float* gate_W = (const float*)d_in[5];
  const float* gate_b = (const float*)d_in[6];
  const float* emb = (const float*)d_in[7];
  const float* encW1 = (const float*)d_in[8];
  const float* encb1 = (const float*)d_in[9];
  const float* encW2 = (const float*)d_in[10];
  const float* encb2 = (const float*)d_in[11];
  const float* netW1 = (const float*)d_in[12];
  const float* netb1 = (const float*)d_in[13];
  const float* netW2 = (const float*)d_in[14];
  const float* netb2 = (const float*)d_in[15];
  const float* ln_g = (const float*)d_in[16];
  const float* ln_b = (const float*)d_in[17];
  const float* feat_mask = (const float*)d_in[18];
  const float* W_sims = (const float*)d_in[19];
  const float* gcnW1 = (const float*)d_in[20];
  const float* gcnb1 = (const float*)d_in[21];
  const float* gcnW2 = (const float*)d_in[22];
  const float* gcnb2 = (const float*)d_in[23];
  const float* decW1 = (const float*)d_in[24];
  const float* decb1 = (const float*)d_in[25];
  const float* bn_g = (const float*)d_in[26];
  const float* bn_b = (const float*)d_in[27];
  const float* decW2 = (const float*)d_in[28];
  const float* decb2 = (const float*)d_in[29];
  (void)in_sizes; (void)n_in; (void)out_size; (void)ws_size;

  // Workspace layout (~190 MB; known-good <=192 MB)
  size_t o = 0;
  auto A = [&](size_t bytes) { char* p = (char*)d_ws + o; o += (bytes + 255) & ~(size_t)255; return p; };
  unsigned short* WTH = (unsigned short*)A((size_t)KATT * 256 * 2);  // 2 MB
  unsigned short* WTL = (unsigned short*)A((size_t)KATT * 256 * 2);  // 2 MB
  char* RBIG = A((size_t)64 * 1024 * 1024);                          // 64 MB
  float* Hb = (float*)A((size_t)M * 128 * 4);                        // 8 MB
  float* ADJ1 = (float*)A((size_t)B * N * N * 4);                    // 61 MB
  float* INITA = (float*)A((size_t)N * N * 4);                       // 3.8 MB
  float* T1 = (float*)A(32 * 512 * 4);
  float* Dd32 = (float*)A(32 * 128 * 4);
  float* DINV = (float*)A(M * 4);
  float* DPART = (float*)A((size_t)16 * 8 * N * 4);                  // 0.5 MB
  float* GEMB = (float*)A(B * 128 * 4);
  float* Zb = (float*)A(B * 64 * 4);
  float* DEC = (float*)A(B * 512 * 4);
  int* fcnt = (int*)A(256);
  float* MU = (float*)A((size_t)B * KCH * 4);                        // 64 KB
  double* qv = (double*)A((size_t)M * 8);
  unsigned short* FUSH = (unsigned short*)A((size_t)M * 256 * 2);    // 8 MB
  unsigned short* FUSL = (unsigned short*)A((size_t)M * 256 * 2);    // 8 MB
  unsigned short* CHB = (unsigned short*)A((size_t)M * KCH * 2);     // 30.6 MB
  unsigned short* WE1H = (unsigned short*)A(512 * 512 * 2);          // encW1^T hi
  unsigned short* WE1L = (unsigned short*)A(512 * 512 * 2);
  unsigned short* WE2H = (unsigned short*)A(128 * 512 * 2);          // encW2^T hi
  unsigned short* WE2L = (unsigned short*)A(128 * 512 * 2);
  unsigned short* WG1H = (unsigned short*)A(512 * 128 * 2);          // gcnW1^T hi
  unsigned short* WG1L = (unsigned short*)A(512 * 128 * 2);
  unsigned short* WG2H = (unsigned short*)A(128 * 512 * 2);          // gcnW2^T hi
  unsigned short* WG2L = (unsigned short*)A(128 * 512 * 2);

  // RBIG unions (phases don't overlap):
  //  encoder: GEH@0 GEL@16M H1H@32M H1L@48M
  //  g-loop chunks: CH (61.1 MB); after chunks (CH dead): FLAGS
  //  GCN: AGGH@0 AGGL@4M PP@8M TtH@32M TtL@48M
  unsigned short* GEH = (unsigned short*)RBIG;
  unsigned short* GEL = (unsigned short*)(RBIG + (size_t)16 * 1024 * 1024);
  unsigned short* H1H = (unsigned short*)(RBIG + (size_t)32 * 1024 * 1024);
  unsigned short* H1L = (unsigned short*)(RBIG + (size_t)48 * 1024 * 1024);
  float* CH = (float*)RBIG;
  char* FLAGS = RBIG;                          // alias CH: live only after chunk loop
  int* frow = (int*)FLAGS;
  int* fcw = (int*)(FLAGS + (size_t)M * 4);
  int* fidx = (int*)(FLAGS + (size_t)2 * M * 4);
  float* fv32 = (float*)(FLAGS + (size_t)2 * M * 4 + (size_t)M * WST * 4);
  unsigned short* AGGH = (unsigned short*)RBIG;
  unsigned short* AGGL = (unsigned short*)(RBIG + (size_t)4 * 1024 * 1024);
  float* PP = (float*)(RBIG + (size_t)8 * 1024 * 1024);
  unsigned short* TTH = (unsigned short*)(RBIG + (size_t)32 * 1024 * 1024);
  unsigned short* TTL = (unsigned short*)(RBIG + (size_t)48 * 1024 * 1024);
  float* TW2 = (float*)FUSH;                   // GCN phase: FUS dead (M*128*4 = 8MB fits)
  float* NODE = (float*)FUSL;

  float* out = (float*)d_out;
  float* out_x2 = out;
  float* out_adj2 = out + M;
  float* out_mu = out + M + (size_t)B * N * N;
  float* out_std = out_mu + B * 64;

  k_wt<<<4096, 256, 0, stream>>>(W_sims, feat_mask, WTH, WTL);
  k_wtrans<<<1024, 256, 0, stream>>>(encW1, WE1H, WE1L, 512, 512);
  k_wtrans<<<256, 256, 0, stream>>>(encW2, WE2H, WE2L, 512, 128);
  k_wtrans<<<256, 256, 0, stream>>>(gcnW1, WG1H, WG1L, 128, 512);
  k_wtrans<<<256, 256, 0, stream>>>(gcnW2, WG2H, WG2L, 512, 128);
  // encoder in split-bf16 MFMA
  k_gate_emb_bf<<<31296, 256, 0, stream>>>(x1, gate_W, gate_b, emb, GEH, GEL);
  k_mgemm<1, true, false, true><<<dim3(123, 4), 256, 0, stream>>>(
      GEH, GEL, WE1H, WE1L, encb1, nullptr, H1H, H1L, M, 512, 512);
  k_mgemm<0, true, true, false><<<dim3(123, 1), 256, 0, stream>>>(
      H1H, H1L, WE2H, WE2L, encb2, Hb, nullptr, nullptr, M, 512, 128);
  k_drug_l1<<<32, 256, 0, stream>>>(drug1, drug2, netW1, netb1, T1);
  k_drug_l2<<<32, 128, 0, stream>>>(T1, netW2, netb2, ln_g, ln_b, Dd32);
  k_zero<<<(N * N + 255) / 256, 256, 0, stream>>>(INITA, N * N);
  k_scatter<<<(NEDGE + 255) / 256, 256, 0, stream>>>(ei, INITA);

  for (int g = 0; g < 2; g++) {
    float* att = (g == 0) ? ADJ1 : out_adj2;
    const float* DDg = Dd32 + (size_t)g * 16 * 128;
    hipMemsetAsync(fcnt, 0, 4, stream);
    hipMemsetAsync(qv, 0, (size_t)M * 8, stream);
    k_fus<<<15648, 256, 0, stream>>>(Hb, DDg, FUSH, FUSL);
    for (int c = 0; c < NCH; c++) {
      k_hp_mma<<<dim3(123, KCH / 128), 256, 0, stream>>>(FUSH, FUSL, WTH + (size_t)c * KCH * 256,
                                                         WTL + (size_t)c * KCH * 256, CH);
      k_mu<<<dim3(KCH / 32, 16), 256, 0, stream>>>(CH, MU);
      k_centerq<<<M / 4, 256, 0, stream>>>(CH, MU, CHB, qv);
      if (c == 0)
        k_syrk_mma<false><<<dim3(36, 16), 256, 0, stream>>>(CHB, att);
      else
        k_syrk_mma<true><<<dim3(36, 16), 256, 0, stream>>>(CHB, att);
    }
    k_topk<<<M, 256, 0, stream>>>(att, qv, INITA, fcnt, frow, fcw, fidx, fv32);
    k_fixup<<<1024, 256, 0, stream>>>(att, INITA, fcnt, frow, fcw, fidx, fv32);
  }

  k_degp<<<dim3(8, 16), 256, 0, stream>>>(ADJ1, DPART);
  k_degf<<<(M + 255) / 256, 256, 0, stream>>>(DPART, DINV);
  // GCN layer 1: aggregate Hb first (associativity), then @W1 via MFMA
  k_spmmp<<<dim3(8, 1, 32), 256, 0, stream>>>(ADJ1, DINV, Hb, PP);
  k_spmmc<false, true><<<(M * 128) / 256, 256, 0, stream>>>(PP, DINV, nullptr, nullptr, AGGH, AGGL);
  k_mgemm<2, true, false, true><<<dim3(123, 4), 256, 0, stream>>>(
      AGGH, AGGL, WG1H, WG1L, gcnb1, nullptr, TTH, TTL, M, 128, 512);
  // GCN layer 2
  k_mgemm<0, false, true, false><<<dim3(123, 1), 256, 0, stream>>>(
      TTH, TTL, WG2H, WG2L, nullptr, TW2, nullptr, nullptr, M, 512, 128);
  k_spmmp<<<dim3(8, 1, 32), 256, 0, stream>>>(ADJ1, DINV, TW2, PP);
  k_spmmc<true, false><<<(M * 128) / 256, 256, 0, stream>>>(PP, DINV, gcnb2, NODE, nullptr, nullptr);
  k_gemb<<<8, 256, 0, stream>>>(NODE, GEMB);
  k_heads<<<4, 256, 0, stream>>>(GEMB, eps, out_mu, out_std, Zb);
  k_dec1<<<1, 512, 0, stream>>>(Zb, decW1, decb1, bn_g, bn_b, DEC);
  k_dec2<<<(M + 255) / 256, 256, 0, stream>>>(DEC, decW2, decb2, out_x2);
}

// Round 15
// 3400.387 us; speedup vs baseline: 2.0486x; 1.1287x over previous
//
#include <hip/hip_runtime.h>
#include <cmath>

namespace {

constexpr int B = 16;
constexpr int N = 978;
constexpr int M = B * N;          // 15648
constexpr int IB2 = 128;          // 2*IB
constexpr int KATT = 4096;        // P*HID
constexpr int KCH = 1024;         // hp column chunk
constexpr int NCH = KATT / KCH;   // 4
constexpr int DF = 2304;
constexpr int TOPKK = 50;
constexpr int NEDGE = 50000;
constexpr int CANDMAX = 64;
constexpr int WST = 120;
constexpr int JSPLIT = 489;       // spmm j-split point

typedef __attribute__((ext_vector_type(8))) short bf16x8;
typedef __attribute__((ext_vector_type(4))) float f32x4;

__device__ __forceinline__ float geluf(float x) {
  return 0.5f * x * (1.f + erff(x * 0.7071067811865476f));
}
__device__ __forceinline__ float sigm(float x) { return 1.f / (1.f + expf(-x)); }
__device__ __forceinline__ double sigm64(double x) { return 1.0 / (1.0 + exp(-x)); }

__device__ __forceinline__ unsigned short f2bf(float f) {
  union { float f; unsigned u; } x; x.f = f;
  unsigned r = (x.u + 0x7FFFu + ((x.u >> 16) & 1u)) >> 16;
  return (unsigned short)r;
}
__device__ __forceinline__ float bf2f(unsigned short s) {
  union { float f; unsigned u; } x; x.u = ((unsigned)s) << 16; return x.f;
}

// ---------------- WT build: (4096 x 256) bf16 hi/lo of W_sims^T * sigm(fm) ----------------
__global__ void k_wt(const float* __restrict__ wsims, const float* __restrict__ fm,
                     unsigned short* __restrict__ wth, unsigned short* __restrict__ wtl) {
  int t = blockIdx.x * 256 + threadIdx.x;   // < 1048576 exact
  int n = t >> 8, k = t & 255;
  int p = n >> 9, h = n & 511;
  double v = (double)wsims[(size_t)p * 131072 + (size_t)k * 512 + h] * sigm64((double)fm[k]);
  float vf = (float)v;
  unsigned short hi = f2bf(vf);
  wth[t] = hi;
  wtl[t] = f2bf(vf - bf2f(hi));
}

// ---------------- generic W transpose-convert ----------------
__global__ void k_wtrans(const float* __restrict__ W, unsigned short* __restrict__ TH,
                         unsigned short* __restrict__ TL, int K, int Nc) {
  int t = blockIdx.x * 256 + threadIdx.x;
  if (t >= K * Nc) return;
  int n = t / K, k = t - n * K;
  float v = W[(size_t)k * Nc + n];
  unsigned short hi = f2bf(v);
  TH[t] = hi;
  TL[t] = f2bf(v - bf2f(hi));
}

// ---------------- FUS build: (M x 256) bf16 hi/lo of [Hb | DDg] ----------------
__global__ void k_fus(const float* __restrict__ Hb, const float* __restrict__ DD,
                      unsigned short* __restrict__ fh, unsigned short* __restrict__ fl) {
  int t = blockIdx.x * 256 + threadIdx.x;   // < M*256 exact
  int k = t & 255;
  int row = t >> 8;
  int b = row / N;
  float v = (k < 128) ? Hb[(size_t)row * 128 + k] : DD[(size_t)b * 128 + (k - 128)];
  unsigned short hi = f2bf(v);
  fh[t] = hi;
  fl[t] = f2bf(v - bf2f(hi));
}

// ---------------- gate*emb -> bf16 hi/lo directly ----------------
__global__ void k_gate_emb_bf(const float* __restrict__ x1, const float* __restrict__ gW,
                              const float* __restrict__ gb, const float* __restrict__ emb,
                              unsigned short* __restrict__ GH, unsigned short* __restrict__ GL) {
  size_t t = (size_t)blockIdx.x * 256 + threadIdx.x;  // < M*512 exact
  int e = (int)(t & 511);
  size_t bn = t >> 9;
  int n = (int)(bn % N);
  float g = sigm(x1[bn] * gW[e] + gb[e]);
  float v = g * emb[(size_t)n * 512 + e];
  unsigned short hi = f2bf(v);
  GH[t] = hi;
  GL[t] = f2bf(v - bf2f(hi));
}

__global__ void k_zero(float* __restrict__ p, int n) {
  int t = blockIdx.x * 256 + threadIdx.x;
  if (t < n) p[t] = 0.f;
}

__global__ void k_scatter(const int* __restrict__ ei, float* __restrict__ adj) {
  int t = blockIdx.x * 256 + threadIdx.x;
  if (t < NEDGE) {
    int r = ei[t], c = ei[NEDGE + t];
    adj[(size_t)r * N + c] = 1.f;
  }
}

// ------- MFMA staging: 128x32 bf16 tile, XOR-swizzled ((r&7)<<4 on 64B rows) -------
__device__ __forceinline__ void stage_tile(const unsigned short* __restrict__ gbase, int grow0,
                                           int rowmax, int k0, int ldk, char* lds, int tid) {
#pragma unroll
  for (int it = 0; it < 2; it++) {
    int r = (tid >> 2) + it * 64;
    int c8 = tid & 3;
    int gr = grow0 + r;
    uint4 v = make_uint4(0u, 0u, 0u, 0u);
    if (gr < rowmax) v = *reinterpret_cast<const uint4*>(&gbase[(size_t)gr * ldk + k0 + c8 * 8]);
    int off = (r * 64 + c8 * 16) ^ ((r & 7) << 4);
    *reinterpret_cast<uint4*>(lds + off) = v;
  }
}

__device__ __forceinline__ bf16x8 frag(const char* lds, int r, int k8) {
  int off = (r * 64 + k8 * 16) ^ ((r & 7) << 4);
  return *reinterpret_cast<const bf16x8*>(lds + off);
}

// ------- generic split-bf16 MFMA GEMM: C = act(A@B + bias) -------
template <int ACT, bool HASBIAS, bool OUTF32, bool OUTBF>
__global__ __launch_bounds__(256) void k_mgemm(const unsigned short* __restrict__ AH,
                                               const unsigned short* __restrict__ AL,
                                               const unsigned short* __restrict__ BTH,
                                               const unsigned short* __restrict__ BTL,
                                               const float* __restrict__ bias,
                                               float* __restrict__ Cf,
                                               unsigned short* __restrict__ CbH,
                                               unsigned short* __restrict__ CbL,
                                               int Mm, int K, int Nc) {
  __shared__ __align__(16) char Ah[8192];
  __shared__ __align__(16) char Al[8192];
  __shared__ __align__(16) char Bh[8192];
  __shared__ __align__(16) char Bl[8192];
  const int m0 = blockIdx.x * 128;
  const int n0 = blockIdx.y * 128;
  const int tid = threadIdx.x;
  const int wave = tid >> 6, lane = tid & 63;
  f32x4 acc[2][8];
#pragma unroll
  for (int i = 0; i < 2; i++)
#pragma unroll
    for (int j = 0; j < 8; j++) acc[i][j] = (f32x4){0.f, 0.f, 0.f, 0.f};

  for (int k0 = 0; k0 < K; k0 += 32) {
    stage_tile(AH, m0, Mm, k0, K, Ah, tid);
    stage_tile(AL, m0, Mm, k0, K, Al, tid);
    stage_tile(BTH, n0, Nc, k0, K, Bh, tid);
    stage_tile(BTL, n0, Nc, k0, K, Bl, tid);
    __syncthreads();
    bf16x8 ah[2], al[2];
#pragma unroll
    for (int rf = 0; rf < 2; rf++) {
      int r = wave * 32 + rf * 16 + (lane & 15);
      ah[rf] = frag(Ah, r, lane >> 4);
      al[rf] = frag(Al, r, lane >> 4);
    }
#pragma unroll
    for (int cf = 0; cf < 8; cf++) {
      int rB = cf * 16 + (lane & 15);
      bf16x8 bh = frag(Bh, rB, lane >> 4);
      bf16x8 bl = frag(Bl, rB, lane >> 4);
#pragma unroll
      for (int rf = 0; rf < 2; rf++) {
        acc[rf][cf] = __builtin_amdgcn_mfma_f32_16x16x32_bf16(ah[rf], bh, acc[rf][cf], 0, 0, 0);
        acc[rf][cf] = __builtin_amdgcn_mfma_f32_16x16x32_bf16(ah[rf], bl, acc[rf][cf], 0, 0, 0);
        acc[rf][cf] = __builtin_amdgcn_mfma_f32_16x16x32_bf16(al[rf], bh, acc[rf][cf], 0, 0, 0);
      }
    }
    __syncthreads();
  }
#pragma unroll
  for (int rf = 0; rf < 2; rf++)
#pragma unroll
    for (int cf = 0; cf < 8; cf++)
#pragma unroll
      for (int r4 = 0; r4 < 4; r4++) {
        int row = m0 + wave * 32 + rf * 16 + ((lane >> 4) << 2) + r4;
        int col = n0 + cf * 16 + (lane & 15);
        if (row < Mm) {
          float v = acc[rf][cf][r4];
          if (HASBIAS) v += bias[col];
          if (ACT == 1) v = geluf(v);
          if (ACT == 2) v = fmaxf(v, 0.f);
          size_t idx = (size_t)row * Nc + col;
          if (OUTF32) Cf[idx] = v;
          if (OUTBF) {
            unsigned short hi = f2bf(v);
            CbH[idx] = hi;
            CbL[idx] = f2bf(v - bf2f(hi));
          }
        }
      }
}

// ------- hp chunk GEMM, split-bf16 (fp32-equivalent): CH = relu(FUS @ WT_chunk^T) -------
__global__ __launch_bounds__(256) void k_hp_mma(const unsigned short* __restrict__ FH,
                                                const unsigned short* __restrict__ FL,
                                                const unsigned short* __restrict__ WTHc,
                                                const unsigned short* __restrict__ WTLc,
                                                float* __restrict__ CH) {
  __shared__ __align__(16) char Ah[8192];
  __shared__ __align__(16) char Al[8192];
  __shared__ __align__(16) char Bh[8192];
  __shared__ __align__(16) char Bl[8192];
  const int m0 = blockIdx.x * 128;
  const int n0 = blockIdx.y * 128;   // within chunk (KCH)
  const int tid = threadIdx.x;
  const int wave = tid >> 6, lane = tid & 63;
  f32x4 acc[2][8];
#pragma unroll
  for (int i = 0; i < 2; i++)
#pragma unroll
    for (int j = 0; j < 8; j++) acc[i][j] = (f32x4){0.f, 0.f, 0.f, 0.f};

  for (int k0 = 0; k0 < 256; k0 += 32) {
    stage_tile(FH, m0, M, k0, 256, Ah, tid);
    stage_tile(FL, m0, M, k0, 256, Al, tid);
    stage_tile(WTHc, n0, KCH, k0, 256, Bh, tid);
    stage_tile(WTLc, n0, KCH, k0, 256, Bl, tid);
    __syncthreads();
    bf16x8 ah[2], al[2];
#pragma unroll
    for (int rf = 0; rf < 2; rf++) {
      int r = wave * 32 + rf * 16 + (lane & 15);
      ah[rf] = frag(Ah, r, lane >> 4);
      al[rf] = frag(Al, r, lane >> 4);
    }
#pragma unroll
    for (int cf = 0; cf < 8; cf++) {
      int rB = cf * 16 + (lane & 15);
      bf16x8 bh = frag(Bh, rB, lane >> 4);
      bf16x8 bl = frag(Bl, rB, lane >> 4);
#pragma unroll
      for (int rf = 0; rf < 2; rf++) {
        acc[rf][cf] = __builtin_amdgcn_mfma_f32_16x16x32_bf16(ah[rf], bh, acc[rf][cf], 0, 0, 0);
        acc[rf][cf] = __builtin_amdgcn_mfma_f32_16x16x32_bf16(ah[rf], bl, acc[rf][cf], 0, 0, 0);
        acc[rf][cf] = __builtin_amdgcn_mfma_f32_16x16x32_bf16(al[rf], bh, acc[rf][cf], 0, 0, 0);
      }
    }
    __syncthreads();
  }
#pragma unroll
  for (int rf = 0; rf < 2; rf++)
#pragma unroll
    for (int cf = 0; cf < 8; cf++)
#pragma unroll
      for (int r4 = 0; r4 < 4; r4++) {
        int row = m0 + wave * 32 + rf * 16 + ((lane >> 4) << 2) + r4;
        int col = n0 + cf * 16 + (lane & 15);
        if (row < M) CH[(size_t)row * KCH + col] = fmaxf(acc[rf][cf][r4], 0.f);
      }
}

// ---------------- per-chunk column means (parallel, deterministic) ----------------
__global__ __launch_bounds__(256) void k_mu(const float* __restrict__ CH, float* __restrict__ MU) {
  __shared__ double red[8][33];
  int b = blockIdx.y, jg = blockIdx.x;
  int jloc = threadIdx.x & 31, s = threadIdx.x >> 5;
  int j = jg * 32 + jloc;
  const float* p = CH + (size_t)b * N * KCH + j;
  double acc = 0.0;
  for (int n = s; n < N; n += 8) acc += (double)p[(size_t)n * KCH];
  red[s][jloc] = acc;
  __syncthreads();
  if (s == 0) {
    double t = 0.0;
#pragma unroll
    for (int k = 0; k < 8; k++) t += red[k][jloc];
    MU[b * KCH + j] = (float)(t * (1.0 / (double)N));
  }
}

// ------- fused center+q: CHB = bf16(CH - MU); qv[r] += <MU[b], CH[r]> (f64) -------
__global__ __launch_bounds__(256) void k_centerq(const float* __restrict__ CH,
                                                 const float* __restrict__ MU,
                                                 unsigned short* __restrict__ CHB,
                                                 double* __restrict__ qv) {
  int r = blockIdx.x * 4 + (threadIdx.x >> 6);   // grid = M/4 = 3912 exact
  int lane = threadIdx.x & 63;
  int b = r / N;
  const float* row = CH + (size_t)r * KCH;
  const float* mu = MU + (size_t)b * KCH;
  double q = 0.0;
#pragma unroll
  for (int jp = 0; jp < 2; jp++) {
    int j0 = lane * 8 + jp * 512;
    float4 v0 = *reinterpret_cast<const float4*>(&row[j0]);
    float4 v1 = *reinterpret_cast<const float4*>(&row[j0 + 4]);
    float4 m0 = *reinterpret_cast<const float4*>(&mu[j0]);
    float4 m1 = *reinterpret_cast<const float4*>(&mu[j0 + 4]);
    unsigned short cb[8];
    cb[0] = f2bf(v0.x - m0.x); cb[1] = f2bf(v0.y - m0.y);
    cb[2] = f2bf(v0.z - m0.z); cb[3] = f2bf(v0.w - m0.w);
    cb[4] = f2bf(v1.x - m1.x); cb[5] = f2bf(v1.y - m1.y);
    cb[6] = f2bf(v1.z - m1.z); cb[7] = f2bf(v1.w - m1.w);
    *reinterpret_cast<uint4*>(&CHB[(size_t)r * KCH + j0]) = *reinterpret_cast<uint4*>(cb);
    q += (double)m0.x * v0.x + (double)m0.y * v0.y + (double)m0.z * v0.z + (double)m0.w * v0.w
       + (double)m1.x * v1.x + (double)m1.y * v1.y + (double)m1.z * v1.z + (double)m1.w * v1.w;
  }
  for (int off = 32; off > 0; off >>= 1) q += __shfl_down(q, off);
  if (lane == 0) qv[r] += q;
}

// ------- centered Gram via bf16 MFMA: G[b] (+)= CHBc @ CHBc^T -------
template <bool ACC>
__global__ __launch_bounds__(256) void k_syrk_mma(const unsigned short* __restrict__ CHB,
                                                  float* __restrict__ ATT) {
  __shared__ __align__(16) char At[8192];
  __shared__ __align__(16) char Bt[8192];
  const int T = 8;
  int pr = blockIdx.x;
  int ti = 0, rem = pr;
  while (rem >= T - ti) { rem -= T - ti; ti++; }
  int tj = ti + rem;
  int b = blockIdx.y;
  const unsigned short* base = CHB + (size_t)b * N * KCH;
  const int tid = threadIdx.x;
  const int wave = tid >> 6, lane = tid & 63;
  f32x4 acc[2][8];
#pragma unroll
  for (int i = 0; i < 2; i++)
#pragma unroll
    for (int j = 0; j < 8; j++) acc[i][j] = (f32x4){0.f, 0.f, 0.f, 0.f};

  for (int k0 = 0; k0 < KCH; k0 += 32) {
    stage_tile(base, ti * 128, N, k0, KCH, At, tid);
    stage_tile(base, tj * 128, N, k0, KCH, Bt, tid);
    __syncthreads();
    bf16x8 af[2];
#pragma unroll
    for (int rf = 0; rf < 2; rf++)
      af[rf] = frag(At, wave * 32 + rf * 16 + (lane & 15), lane >> 4);
#pragma unroll
    for (int cf = 0; cf < 8; cf++) {
      bf16x8 bf_ = frag(Bt, cf * 16 + (lane & 15), lane >> 4);
#pragma unroll
      for (int rf = 0; rf < 2; rf++)
        acc[rf][cf] = __builtin_amdgcn_mfma_f32_16x16x32_bf16(af[rf], bf_, acc[rf][cf], 0, 0, 0);
    }
    __syncthreads();
  }
  float* att = ATT + (size_t)b * N * N;
#pragma unroll
  for (int rf = 0; rf < 2; rf++)
#pragma unroll
    for (int cf = 0; cf < 8; cf++)
#pragma unroll
      for (int r4 = 0; r4 < 4; r4++) {
        int row = ti * 128 + wave * 32 + rf * 16 + ((lane >> 4) << 2) + r4;
        int col = tj * 128 + cf * 16 + (lane & 15);
        if (row < N && col < N) {
          float v = acc[rf][cf][r4];
          if (ACC) {
            att[(size_t)row * N + col] += v;
            if (ti != tj) att[(size_t)col * N + row] += v;
          } else {
            att[(size_t)row * N + col] = v;
            if (ti != tj) att[(size_t)col * N + row] = v;
          }
        }
      }
}

// -------- top-50 on s = G + q_m - q_n, softmax(s/8), flagging --------
// Register bitonic on 32-bit keys: (~monotone(sv) & 0xFFFFFC00) | idx.
// 22 value bits + 10 idx bits; exact fp32 values in LDS side-table svs[].
// 22-bit truncation only permutes pairs with |ds| < ~5e-7 s-units; such pairs at the
// rank-50 boundary are always flagged (FLAGW=8e-3) and fixup rewrites with exact values,
// so outputs are unchanged. j>=256 in-thread, j<=32 shfl_xor, j in {64,128} via LDS.
__global__ __launch_bounds__(256) void k_topk(float* __restrict__ ATT, const double* __restrict__ qv,
                                              const float* __restrict__ INITA,
                                              int* __restrict__ fcnt, int* __restrict__ frow,
                                              int* __restrict__ fcw, int* __restrict__ fidx,
                                              float* __restrict__ fv32) {
  int row = blockIdx.x;  // b*N + n
  int n = row % N;
  int b = row / N;
  float* arow = ATT + (size_t)row * N;
  __shared__ unsigned keys[1024];
  __shared__ float svs[1024];
  __shared__ float outr[N];
  __shared__ float sred;
  __shared__ int s_slot, s_cw;
  int tid = threadIdx.x;
  double qn = qv[row];
  unsigned kreg[4];
#pragma unroll
  for (int c = 0; c < 4; c++) {
    int i = tid + 256 * c;
    unsigned kk = 0xFFFFFFFFu;
    float sv = -1e30f;
    if (i < N) {
      sv = (float)((double)arow[i] + qv[(size_t)b * N + i] - qn);
      unsigned u = __float_as_uint(sv);
      u ^= (u >> 31) ? 0xFFFFFFFFu : 0x80000000u;
      kk = ((~u) & 0xFFFFFC00u) | (unsigned)i;
    }
    svs[i] = sv;
    kreg[c] = kk;
  }
  __syncthreads();
  for (int ksz = 2; ksz <= 1024; ksz <<= 1) {
    for (int j = ksz >> 1; j > 0; j >>= 1) {
      if (j <= 32) {
#pragma unroll
        for (int c = 0; c < 4; c++) {
          int e = tid + 256 * c;
          unsigned pk = __shfl_xor(kreg[c], j);
          bool takemin = (((e & j) == 0) == ((e & ksz) == 0));
          unsigned mn = kreg[c] < pk ? kreg[c] : pk;
          unsigned mx = kreg[c] < pk ? pk : kreg[c];
          kreg[c] = takemin ? mn : mx;
        }
      } else if (j >= 256) {
        int sw = j >> 8;
#pragma unroll
        for (int c = 0; c < 4; c++) {
          if ((c & sw) == 0) {
            int e = tid + 256 * c;
            bool up = (e & ksz) == 0;
            unsigned a = kreg[c], b2 = kreg[c | sw];
            if ((a > b2) == up) { kreg[c] = b2; kreg[c | sw] = a; }
          }
        }
      } else {
#pragma unroll
        for (int c = 0; c < 4; c++) keys[tid + 256 * c] = kreg[c];
        __syncthreads();
#pragma unroll
        for (int c = 0; c < 4; c++) {
          int e = tid + 256 * c;
          unsigned pk = keys[e ^ j];
          bool takemin = (((e & j) == 0) == ((e & ksz) == 0));
          unsigned mn = kreg[c] < pk ? kreg[c] : pk;
          unsigned mx = kreg[c] < pk ? pk : kreg[c];
          kreg[c] = takemin ? mn : mx;
        }
        __syncthreads();
      }
    }
  }
#pragma unroll
  for (int c = 0; c < 4; c++) keys[tid + 256 * c] = kreg[c];
  __syncthreads();

  float v49 = svs[keys[49] & 1023u];
  float v50v = svs[keys[50] & 1023u];
  float FLAGW = 8e-3f + 2e-5f * fabsf(v49);   // s-units
  bool flag = (v50v >= v49 - FLAGW);
  if (flag) {
    if (tid == 0) {
      int cin = 0;
      for (int r = 0; r < 50; r++)
        if (svs[keys[r] & 1023u] > v49 + FLAGW) cin++;
      int rhi = 50;
      while (rhi < 113) {
        float vv = svs[keys[rhi + 1] & 1023u];
        if (vv >= v49 - FLAGW) rhi++; else break;
      }
      int w = rhi - cin + 1;
      if (w > CANDMAX) w = CANDMAX;
      if (cin + w < 50) w = 50 - cin;
      int slot = atomicAdd(fcnt, 1);
      frow[slot] = row;
      fcw[slot] = cin | (w << 8);
      s_slot = slot;
      s_cw = cin | (w << 8);
    }
    __syncthreads();
    int slot = s_slot;
    int tot = (s_cw & 255) + (s_cw >> 8);
    for (int r = tid; r < tot; r += 256) {
      unsigned kk = keys[r];
      fidx[(size_t)slot * WST + r] = (int)(kk & 1023u);
      fv32[(size_t)slot * WST + r] = svs[kk & 1023u];
    }
    __syncthreads();
  }

  float vmax = svs[keys[0] & 1023u];
  float e = 0.f;
  int myidx = 0;
  if (tid < TOPKK) {
    unsigned kk = keys[tid];
    myidx = (int)(kk & 1023u);
    e = expf((svs[myidx] - vmax) * 0.125f);
  }
  float s = e;
  for (int off = 32; off > 0; off >>= 1) s += __shfl_down(s, off);
  if (tid == 0) sred = s;
  for (int m2 = tid; m2 < N; m2 += 256) outr[m2] = 0.2f * INITA[(size_t)n * N + m2];
  __syncthreads();
  if (tid < TOPKK) outr[myidx] = 0.2f * INITA[(size_t)n * N + myidx] + 0.8f * (e / sred);
  __syncthreads();
  for (int m2 = tid; m2 < N; m2 += 256) arow[m2] = outr[m2];
}

// -------- fixup: fv32 ranking + minimax mass-split at near-tied boundaries --------
__global__ __launch_bounds__(256) void k_fixup(float* __restrict__ ATT, const float* __restrict__ INITA,
                                               const int* __restrict__ fcnt, const int* __restrict__ frow,
                                               const int* __restrict__ fcw, const int* __restrict__ fidx,
                                               const float* __restrict__ fv32) {
  __shared__ double wts[56];
  __shared__ int mm[56];
  __shared__ int s_tot;
  int tid = threadIdx.x;
  int cnt = *fcnt;
  for (int slot = blockIdx.x; slot < cnt; slot += gridDim.x) {
    int row = frow[slot];
    int cw = fcw[slot];
    int cin = cw & 255, w = cw >> 8;
    int n = row % N;
    __syncthreads();
    if (tid == 0) {
      int need = 50 - cin;
      if (need > w) need = w;
      double cv[CANDMAX]; int cm[CANDMAX]; float cs[CANDMAX];
      for (int c = 0; c < w; c++) {
        float sv = fv32[(size_t)slot * WST + cin + c];
        cv[c] = (double)sv * 0.125;
        cm[c] = fidx[(size_t)slot * WST + cin + c];
        cs[c] = sv;
      }
      int ord[CANDMAX];
      for (int c = 0; c < w; c++) ord[c] = c;
      for (int a2 = 0; a2 < w; a2++) {
        int best = a2;
        for (int c2 = a2 + 1; c2 < w; c2++) {
          int i1 = ord[c2], i0 = ord[best];
          if (cv[i1] > cv[i0] || (cv[i1] == cv[i0] && cm[i1] < cm[i0])) best = c2;
        }
        int tswap = ord[a2]; ord[a2] = ord[best]; ord[best] = tswap;
      }
      double b_in = cv[ord[need - 1]];
      double b_out = (need < w) ? cv[ord[need]] : -1e300;
      const double DATT = 1e-3;
      double fac[56];
      int tot = 0;
      for (int r = 0; r < cin; r++) {
        wts[tot] = (double)fv32[(size_t)slot * WST + r];
        mm[tot] = fidx[(size_t)slot * WST + r];
        fac[tot++] = 1.0;
      }
      if (need == w || b_in - b_out > DATT) {
        for (int t3 = 0; t3 < need; t3++) {
          wts[tot] = (double)cs[ord[t3]];
          mm[tot] = cm[ord[t3]];
          fac[tot++] = 1.0;
        }
      } else {
        int gs = 0;
        while (gs < w && cv[ord[gs]] > b_in + DATT) gs++;
        int ge = w - 1;
        while (ge >= 0 && cv[ord[ge]] < b_out - DATT) ge--;
        double mid = 0.5 * (b_in + b_out);
        while (ge - gs + 1 > 3) {
          if (cv[ord[gs]] - mid >= mid - cv[ord[ge]]) gs++;
          else ge--;
        }
        int fullc = gs;
        int gcount = ge - gs + 1;
        int gneed = need - fullc;
        if (gneed < 0) gneed = 0;
        if (gneed > gcount) gneed = gcount;
        double frac = (gcount > 0) ? (double)gneed / (double)gcount : 0.0;
        for (int t3 = 0; t3 < fullc; t3++) {
          wts[tot] = (double)cs[ord[t3]];
          mm[tot] = cm[ord[t3]];
          fac[tot++] = 1.0;
        }
        for (int t3 = gs; t3 <= ge; t3++) {
          wts[tot] = (double)cs[ord[t3]];
          mm[tot] = cm[ord[t3]];
          fac[tot++] = frac;
        }
      }
      double vmax = -1e300;
      for (int r = 0; r < tot; r++)
        if (fac[r] > 0.0 && wts[r] > vmax) vmax = wts[r];
      double S = 0.0;
      for (int r = 0; r < tot; r++) {
        double e = fac[r] * exp((wts[r] - vmax) * 0.125);
        wts[r] = e;
        S += e;
      }
      double inv = 1.0 / S;
      for (int r = 0; r < tot; r++) wts[r] *= inv;
      s_tot = tot;
    }
    __syncthreads();
    int tot = s_tot;
    float* arow = ATT + (size_t)row * N;
    for (int m2 = tid; m2 < N; m2 += 256) arow[m2] = 0.2f * INITA[(size_t)n * N + m2];
    __syncthreads();
    if (tid < tot && wts[tid] > 0.0)
      arow[mm[tid]] = 0.2f * INITA[(size_t)n * N + mm[tid]] + 0.8f * (float)wts[tid];
    __syncthreads();
  }
}

// ---------------- GCN degree: two-stage coalesced ----------------
__global__ __launch_bounds__(256) void k_degp(const float* __restrict__ ADJ, float* __restrict__ DPART) {
  int ch = blockIdx.x, b = blockIdx.y;
  int tid = threadIdx.x;
  float reg[4] = {0.f, 0.f, 0.f, 0.f};
  int j0 = ch * 123, j1 = j0 + 123;
  if (j1 > N) j1 = N;
  const float* adj = ADJ + (size_t)b * N * N;
  for (int j = j0; j < j1; j++) {
    const float* rowp = adj + (size_t)j * N;
#pragma unroll
    for (int k = 0; k < 4; k++) {
      int i = tid + 256 * k;
      if (i < N) reg[k] += rowp[i];
    }
  }
  float* dp = DPART + ((size_t)b * 8 + ch) * N;
#pragma unroll
  for (int k = 0; k < 4; k++) {
    int i = tid + 256 * k;
    if (i < N) dp[i] = reg[k];
  }
}
__global__ void k_degf(const float* __restrict__ DPART, float* __restrict__ DINV) {
  int t = blockIdx.x * 256 + threadIdx.x;
  if (t >= M) return;
  int b = t / N, i = t - b * N;
  float s = 1.f;
#pragma unroll
  for (int c = 0; c < 8; c++) s += DPART[((size_t)b * 8 + c) * N + i];
  DINV[t] = rsqrtf(s);
}

// ---------------- spmm partial (F=128, j-split) ----------------
__global__ __launch_bounds__(256) void k_spmmp(const float* __restrict__ ADJ, const float* __restrict__ DINV,
                                               const float* __restrict__ X, float* __restrict__ PP) {
  __shared__ float As[16][132];
  __shared__ float Ws[16][132];
  const int tid = threadIdx.x;
  const int i0 = blockIdx.x * 128;
  const int b = blockIdx.z >> 1;
  const int half = blockIdx.z & 1;
  const int jstart = half ? JSPLIT : 0;
  const int jend = half ? N : JSPLIT;
  const float* adj = ADJ + (size_t)b * N * N;
  const float* dv = DINV + b * N;
  const float* xb = X + (size_t)b * N * 128;
  const int ty = tid >> 4, tx = tid & 15;
  float acc[8][8];
#pragma unroll
  for (int i = 0; i < 8; i++)
#pragma unroll
    for (int j = 0; j < 8; j++) acc[i][j] = 0.f;

  for (int j0 = jstart; j0 < jend; j0 += 16) {
#pragma unroll
    for (int l = 0; l < 8; l++) {
      int idx = tid + l * 256;
      int r = idx >> 7, c = idx & 127;
      int j = j0 + r, i = i0 + c;
      float v = 0.f;
      if (j < jend && i < N) {
        float dj = dv[j];
        v = adj[(size_t)j * N + i] * dj;
        if (i == j) v += dj;
      }
      As[r][c] = v;
      float w = 0.f;
      if (j < jend) w = xb[(size_t)j * 128 + c];
      Ws[r][c] = w;
    }
    __syncthreads();
#pragma unroll
    for (int k = 0; k < 16; k++) {
      float a[8], bb[8];
      *reinterpret_cast<float4*>(&a[0]) = *reinterpret_cast<const float4*>(&As[k][ty * 8]);
      *reinterpret_cast<float4*>(&a[4]) = *reinterpret_cast<const float4*>(&As[k][ty * 8 + 4]);
      *reinterpret_cast<float4*>(&bb[0]) = *reinterpret_cast<const float4*>(&Ws[k][tx * 8]);
      *reinterpret_cast<float4*>(&bb[4]) = *reinterpret_cast<const float4*>(&Ws[k][tx * 8 + 4]);
#pragma unroll
      for (int i = 0; i < 8; i++)
#pragma unroll
        for (int j = 0; j < 8; j++) acc[i][j] = fmaf(a[i], bb[j], acc[i][j]);
    }
    __syncthreads();
  }
#pragma unroll
  for (int i = 0; i < 8; i++) {
    int row = i0 + ty * 8 + i;
    if (row >= N) continue;
#pragma unroll
    for (int j4 = 0; j4 < 2; j4++) {
      float4 v;
      float* vv = reinterpret_cast<float*>(&v);
#pragma unroll
      for (int j = 0; j < 4; j++) vv[j] = acc[i][j4 * 4 + j];
      *reinterpret_cast<float4*>(&PP[(((size_t)half * M) + (size_t)b * N + row) * 128 +
                                     tx * 8 + j4 * 4]) = v;
    }
  }
}

// combine: v = (PP0+PP1)*di (+bias); OUTBF -> bf16 hi/lo, else fp32
template <bool HASBIAS, bool OUTBF>
__global__ void k_spmmc(const float* __restrict__ PP, const float* __restrict__ DINV,
                        const float* __restrict__ bias, float* __restrict__ OUT,
                        unsigned short* __restrict__ OH, unsigned short* __restrict__ OL) {
  int t = blockIdx.x * 256 + threadIdx.x;   // < M*128 exact
  int row = t >> 7, f = t & 127;
  float v = (PP[t] + PP[(size_t)M * 128 + t]) * DINV[row];
  if (HASBIAS) v += bias[f];
  if (OUTBF) {
    unsigned short hi = f2bf(v);
    OH[t] = hi;
    OL[t] = f2bf(v - bf2f(hi));
  } else {
    OUT[t] = v;
  }
}

// ---------------- drug embed (fp32) ----------------
__global__ __launch_bounds__(256) void k_drug_l1(const float* __restrict__ d1, const float* __restrict__ d2,
                                                 const float* __restrict__ W, const float* __restrict__ bias,
                                                 float* __restrict__ T1) {
  __shared__ float row[DF];
  int blk = blockIdx.x;
  const float* dr = ((blk & 16) ? d2 : d1) + (size_t)(blk & 15) * DF;
  for (int i = threadIdx.x; i < DF; i += 256) row[i] = dr[i];
  __syncthreads();
  for (int e = threadIdx.x; e < 512; e += 256) {
    float s = bias[e];
    for (int k = 0; k < DF; k++) s = fmaf(row[k], W[(size_t)k * 512 + e], s);
    T1[(size_t)blk * 512 + e] = fmaxf(s, 0.f);
  }
}

__global__ __launch_bounds__(128) void k_drug_l2(const float* __restrict__ T1, const float* __restrict__ W,
                                                 const float* __restrict__ bias, const float* __restrict__ lg,
                                                 const float* __restrict__ lb, float* __restrict__ D) {
  __shared__ float row[512];
  __shared__ float red[4];
  int blk = blockIdx.x;
  int e = threadIdx.x;
  for (int i = e; i < 512; i += 128) row[i] = T1[(size_t)blk * 512 + i];
  __syncthreads();
  float s = bias[e];
  for (int k = 0; k < 512; k++) s = fmaf(row[k], W[k * 128 + e], s);
  float t = s;
  for (int off = 32; off > 0; off >>= 1) t += __shfl_down(t, off);
  if ((e & 63) == 0) red[e >> 6] = t;
  __syncthreads();
  float mean = (red[0] + red[1]) * (1.f / 128.f);
  float dd = s - mean;
  float wv = dd * dd;
  for (int off = 32; off > 0; off >>= 1) wv += __shfl_down(wv, off);
  if ((e & 63) == 0) red[2 + (e >> 6)] = wv;
  __syncthreads();
  float var = (red[2] + red[3]) * (1.f / 128.f);
  D[(size_t)blk * 128 + e] = dd * rsqrtf(var + 1e-5f) * lg[e] + lb[e];
}

// ---------------- head + decoder ----------------
__global__ void k_gemb(const float* __restrict__ NODE, float* __restrict__ GEMB) {
  int t = blockIdx.x * 256 + threadIdx.x;
  int b = t >> 7, f = t & 127;
  const float* p = NODE + (size_t)b * N * IB2 + f;
  float s = 0.f;
  for (int n2 = 0; n2 < N; n2++) s += p[(size_t)n2 * IB2];
  GEMB[t] = s * (1.f / (float)N);
}

__global__ void k_heads(const float* __restrict__ GEMB, const float* __restrict__ EPS,
                        float* __restrict__ out_mu, float* __restrict__ out_std, float* __restrict__ Z) {
  int t = blockIdx.x * 256 + threadIdx.x;
  int b = t >> 6, q = t & 63;
  float mu = GEMB[b * 128 + q];
  float xs = GEMB[b * 128 + 64 + q] - 64.f;
  float sp = (xs > 20.f) ? xs : log1pf(expf(xs));
  out_mu[t] = mu;
  out_std[t] = sp;
  Z[t] = mu + EPS[t] * sp;
}

__global__ __launch_bounds__(512) void k_dec1(const float* __restrict__ Z, const float* __restrict__ W1,
                                              const float* __restrict__ b1, const float* __restrict__ bg,
                                              const float* __restrict__ bb, float* __restrict__ DEC) {
  int f = threadIdx.x;
  float d[16];
  for (int b = 0; b < 16; b++) {
    float s = b1[f];
    for (int k = 0; k < 64; k++) s = fmaf(Z[b * 64 + k], W1[k * 512 + f], s);
    d[b] = s;
  }
  float m = 0.f;
  for (int b = 0; b < 16; b++) m += d[b];
  m *= (1.f / 16.f);
  float v = 0.f;
  for (int b = 0; b < 16; b++) { float t = d[b] - m; v += t * t; }
  v *= (1.f / 16.f);
  float sc = rsqrtf(v + 1e-5f) * bg[f];
  float sh = bb[f];
  for (int b = 0; b < 16; b++) {
    float x = (d[b] - m) * sc + sh;
    DEC[b * 512 + f] = fmaxf(x, 0.f);
  }
}

__global__ void k_dec2(const float* __restrict__ DEC, const float* __restrict__ W2,
                       const float* __restrict__ b2, float* __restrict__ X2) {
  int t = blockIdx.x * 256 + threadIdx.x;
  if (t >= M) return;
  int b = t / N, n2 = t - b * N;
  float s = b2[n2];
  const float* db = DEC + b * 512;
  for (int f = 0; f < 512; f++) s = fmaf(db[f], W2[(size_t)f * N + n2], s);
  X2[t] = fmaxf(s, 0.f);
}

}  // namespace

extern "C" void kernel_launch(void* const* d_in, const int* in_sizes, int n_in,
                              void* d_out, int out_size, void* d_ws, size_t ws_size,
                              hipStream_t stream) {
  const float* x1 = (const float*)d_in[0];
  const float* drug1 = (const float*)d_in[1];
  const float* drug2 = (const float*)d_in[2];
  const float* eps = (const float*)d_in[3];
  const int* ei = (const int*)d_in[4];
  const float* gate_W = (const float*)d_in[5];
  const float* gate_b = (const float*)d_in[6];
  const float* emb = (const float*)d_in[7];
  const float* encW1 = (const float*)d_in[8];
  const float* encb1 = (const float*)d_in[9];
  const float* encW2 = (const float*)d_in[10];
  const float* encb2 = (const float*)d_in[11];
  const float* netW1 = (const float*)d_in[12];
  const float* netb1 = (const float*)d_in[13];
  const float* netW2 = (const float*)d_in[14];
  const float* netb2 = (const float*)d_in[15];
  const float* ln_g = (const float*)d_in[16];
  const float* ln_b = (const float*)d_in[17];
  const float* feat_mask = (const float*)d_in[18];
  const float* W_sims = (const float*)d_in[19];
  const float* gcnW1 = (const float*)d_in[20];
  const float* gcnb1 = (const float*)d_in[21];
  const float* gcnW2 = (const float*)d_in[22];
  const float* gcnb2 = (const float*)d_in[23];
  const float* decW1 = (const float*)d_in[24];
  const float* decb1 = (const float*)d_in[25];
  const float* bn_g = (const float*)d_in[26];
  const float* bn_b = (const float*)d_in[27];
  const float* decW2 = (const float*)d_in[28];
  const float* decb2 = (const float*)d_in[29];
  (void)in_sizes; (void)n_in; (void)out_size; (void)ws_size;

  // Workspace layout (~190 MB; known-good <=192 MB)
  size_t o = 0;
  auto A = [&](size_t bytes) { char* p = (char*)d_ws + o; o += (bytes + 255) & ~(size_t)255; return p; };
  unsigned short* WTH = (unsigned short*)A((size_t)KATT * 256 * 2);  // 2 MB
  unsigned short* WTL = (unsigned short*)A((size_t)KATT * 256 * 2);  // 2 MB
  char* RBIG = A((size_t)64 * 1024 * 1024);                          // 64 MB
  float* Hb = (float*)A((size_t)M * 128 * 4);                        // 8 MB
  float* ADJ1 = (float*)A((size_t)B * N * N * 4);                    // 61 MB
  float* INITA = (float*)A((size_t)N * N * 4);                       // 3.8 MB
  float* T1 = (float*)A(32 * 512 * 4);
  float* Dd32 = (float*)A(32 * 128 * 4);
  float* DINV = (float*)A(M * 4);
  float* DPART = (float*)A((size_t)16 * 8 * N * 4);                  // 0.5 MB
  float* GEMB = (float*)A(B * 128 * 4);
  float* Zb = (float*)A(B * 64 * 4);
  float* DEC = (float*)A(B * 512 * 4);
  int* fcnt = (int*)A(256);
  float* MU = (float*)A((size_t)B * KCH * 4);                        // 64 KB
  double* qv = (double*)A((size_t)M * 8);
  unsigned short* FUSH = (unsigned short*)A((size_t)M * 256 * 2);    // 8 MB
  unsigned short* FUSL = (unsigned short*)A((size_t)M * 256 * 2);    // 8 MB
  unsigned short* CHB = (unsigned short*)A((size_t)M * KCH * 2);     // 30.6 MB
  unsigned short* WE1H = (unsigned short*)A(512 * 512 * 2);
  unsigned short* WE1L = (unsigned short*)A(512 * 512 * 2);
  unsigned short* WE2H = (unsigned short*)A(128 * 512 * 2);
  unsigned short* WE2L = (unsigned short*)A(128 * 512 * 2);
  unsigned short* WG1H = (unsigned short*)A(512 * 128 * 2);
  unsigned short* WG1L = (unsigned short*)A(512 * 128 * 2);
  unsigned short* WG2H = (unsigned short*)A(128 * 512 * 2);
  unsigned short* WG2L = (unsigned short*)A(128 * 512 * 2);

  // RBIG unions (phases don't overlap)
  unsigned short* GEH = (unsigned short*)RBIG;
  unsigned short* GEL = (unsigned short*)(RBIG + (size_t)16 * 1024 * 1024);
  unsigned short* H1H = (unsigned short*)(RBIG + (size_t)32 * 1024 * 1024);
  unsigned short* H1L = (unsigned short*)(RBIG + (size_t)48 * 1024 * 1024);
  float* CH = (float*)RBIG;
  char* FLAGS = RBIG;                          // alias CH: live only after chunk loop
  int* frow = (int*)FLAGS;
  int* fcw = (int*)(FLAGS + (size_t)M * 4);
  int* fidx = (int*)(FLAGS + (size_t)2 * M * 4);
  float* fv32 = (float*)(FLAGS + (size_t)2 * M * 4 + (size_t)M * WST * 4);
  unsigned short* AGGH = (unsigned short*)RBIG;
  unsigned short* AGGL = (unsigned short*)(RBIG + (size_t)4 * 1024 * 1024);
  float* PP = (float*)(RBIG + (size_t)8 * 1024 * 1024);
  unsigned short* TTH = (unsigned short*)(RBIG + (size_t)32 * 1024 * 1024);
  unsigned short* TTL = (unsigned short*)(RBIG + (size_t)48 * 1024 * 1024);
  float* TW2 = (float*)FUSH;                   // GCN phase: FUS dead
  float* NODE = (float*)FUSL;

  float* out = (float*)d_out;
  float* out_x2 = out;
  float* out_adj2 = out + M;
  float* out_mu = out + M + (size_t)B * N * N;
  float* out_std = out_mu + B * 64;

  k_wt<<<4096, 256, 0, stream>>>(W_sims, feat_mask, WTH, WTL);
  k_wtrans<<<1024, 256, 0, stream>>>(encW1, WE1H, WE1L, 512, 512);
  k_wtrans<<<256, 256, 0, stream>>>(encW2, WE2H, WE2L, 512, 128);
  k_wtrans<<<256, 256, 0, stream>>>(gcnW1, WG1H, WG1L, 128, 512);
  k_wtrans<<<256, 256, 0, stream>>>(gcnW2, WG2H, WG2L, 512, 128);
  // encoder in split-bf16 MFMA
  k_gate_emb_bf<<<31296, 256, 0, stream>>>(x1, gate_W, gate_b, emb, GEH, GEL);
  k_mgemm<1, true, false, true><<<dim3(123, 4), 256, 0, stream>>>(
      GEH, GEL, WE1H, WE1L, encb1, nullptr, H1H, H1L, M, 512, 512);
  k_mgemm<0, true, true, false><<<dim3(123, 1), 256, 0, stream>>>(
      H1H, H1L, WE2H, WE2L, encb2, Hb, nullptr, nullptr, M, 512, 128);
  k_drug_l1<<<32, 256, 0, stream>>>(drug1, drug2, netW1, netb1, T1);
  k_drug_l2<<<32, 128, 0, stream>>>(T1, netW2, netb2, ln_g, ln_b, Dd32);
  k_zero<<<(N * N + 255) / 256, 256, 0, stream>>>(INITA, N * N);
  k_scatter<<<(NEDGE + 255) / 256, 256, 0, stream>>>(ei, INITA);

  for (int g = 0; g < 2; g++) {
    float* att = (g == 0) ? ADJ1 : out_adj2;
    const float* DDg = Dd32 + (size_t)g * 16 * 128;
    hipMemsetAsync(fcnt, 0, 4, stream);
    hipMemsetAsync(qv, 0, (size_t)M * 8, stream);
    k_fus<<<15648, 256, 0, stream>>>(Hb, DDg, FUSH, FUSL);
    for (int c = 0; c < NCH; c++) {
      k_hp_mma<<<dim3(123, KCH / 128), 256, 0, stream>>>(FUSH, FUSL, WTH + (size_t)c * KCH * 256,
                                                         WTL + (size_t)c * KCH * 256, CH);
      k_mu<<<dim3(KCH / 32, 16), 256, 0, stream>>>(CH, MU);
      k_centerq<<<M / 4, 256, 0, stream>>>(CH, MU, CHB, qv);
      if (c == 0)
        k_syrk_mma<false><<<dim3(36, 16), 256, 0, stream>>>(CHB, att);
      else
        k_syrk_mma<true><<<dim3(36, 16), 256, 0, stream>>>(CHB, att);
    }
    k_topk<<<M, 256, 0, stream>>>(att, qv, INITA, fcnt, frow, fcw, fidx, fv32);
    k_fixup<<<1024, 256, 0, stream>>>(att, INITA, fcnt, frow, fcw, fidx, fv32);
  }

  k_degp<<<dim3(8, 16), 256, 0, stream>>>(ADJ1, DPART);
  k_degf<<<(M + 255) / 256, 256, 0, stream>>>(DPART, DINV);
  // GCN layer 1: aggregate Hb first (associativity), then @W1 via MFMA
  k_spmmp<<<dim3(8, 1, 32), 256, 0, stream>>>(ADJ1, DINV, Hb, PP);
  k_spmmc<false, true><<<(M * 128) / 256, 256, 0, stream>>>(PP, DINV, nullptr, nullptr, AGGH, AGGL);
  k_mgemm<2, true, false, true><<<dim3(123, 4), 256, 0, stream>>>(
      AGGH, AGGL, WG1H, WG1L, gcnb1, nullptr, TTH, TTL, M, 128, 512);
  // GCN layer 2
  k_mgemm<0, false, true, false><<<dim3(123, 1), 256, 0, stream>>>(
      TTH, TTL, WG2H, WG2L, nullptr, TW2, nullptr, nullptr, M, 512, 128);
  k_spmmp<<<dim3(8, 1, 32), 256, 0, stream>>>(ADJ1, DINV, TW2, PP);
  k_spmmc<true, false><<<(M * 128) / 256, 256, 0, stream>>>(PP, DINV, gcnb2, NODE, nullptr, nullptr);
  k_gemb<<<8, 256, 0, stream>>>(NODE, GEMB);
  k_heads<<<4, 256, 0, stream>>>(GEMB, eps, out_mu, out_std, Zb);
  k_dec1<<<1, 512, 0, stream>>>(Zb, decW1, decb1, bn_g, bn_b, DEC);
  k_dec2<<<(M + 255) / 256, 256, 0, stream>>>(DEC, decW2, decb2, out_x2);
}

// Round 16
// 3235.866 us; speedup vs baseline: 2.1527x; 1.0508x over previous
//
#include <hip/hip_runtime.h>
#include <cmath>

namespace {

constexpr int B = 16;
constexpr int N = 978;
constexpr int M = B * N;          // 15648
constexpr int IB2 = 128;          // 2*IB
constexpr int KATT = 4096;        // P*HID
constexpr int KCH = 1024;         // hp column chunk
constexpr int NCH = KATT / KCH;   // 4
constexpr int DF = 2304;
constexpr int TOPKK = 50;
constexpr int NEDGE = 50000;
constexpr int CANDMAX = 64;
constexpr int WST = 120;
constexpr int JQ = 245;           // spmm j-quarter size (boundaries 0,245,490,735,978)

typedef __attribute__((ext_vector_type(8))) short bf16x8;
typedef __attribute__((ext_vector_type(4))) float f32x4;

__device__ __forceinline__ float geluf(float x) {
  return 0.5f * x * (1.f + erff(x * 0.7071067811865476f));
}
__device__ __forceinline__ float sigm(float x) { return 1.f / (1.f + expf(-x)); }
__device__ __forceinline__ double sigm64(double x) { return 1.0 / (1.0 + exp(-x)); }

__device__ __forceinline__ unsigned short f2bf(float f) {
  union { float f; unsigned u; } x; x.f = f;
  unsigned r = (x.u + 0x7FFFu + ((x.u >> 16) & 1u)) >> 16;
  return (unsigned short)r;
}
__device__ __forceinline__ float bf2f(unsigned short s) {
  union { float f; unsigned u; } x; x.u = ((unsigned)s) << 16; return x.f;
}

// ---------------- WT build: (4096 x 256) bf16 hi/lo of W_sims^T * sigm(fm) ----------------
__global__ void k_wt(const float* __restrict__ wsims, const float* __restrict__ fm,
                     unsigned short* __restrict__ wth, unsigned short* __restrict__ wtl) {
  int t = blockIdx.x * 256 + threadIdx.x;   // < 1048576 exact
  int n = t >> 8, k = t & 255;
  int p = n >> 9, h = n & 511;
  double v = (double)wsims[(size_t)p * 131072 + (size_t)k * 512 + h] * sigm64((double)fm[k]);
  float vf = (float)v;
  unsigned short hi = f2bf(vf);
  wth[t] = hi;
  wtl[t] = f2bf(vf - bf2f(hi));
}

// ---------------- generic W transpose-convert ----------------
__global__ void k_wtrans(const float* __restrict__ W, unsigned short* __restrict__ TH,
                         unsigned short* __restrict__ TL, int K, int Nc) {
  int t = blockIdx.x * 256 + threadIdx.x;
  if (t >= K * Nc) return;
  int n = t / K, k = t - n * K;
  float v = W[(size_t)k * Nc + n];
  unsigned short hi = f2bf(v);
  TH[t] = hi;
  TL[t] = f2bf(v - bf2f(hi));
}

// ---------------- FUS build: (M x 256) bf16 hi/lo of [Hb | DDg] ----------------
__global__ void k_fus(const float* __restrict__ Hb, const float* __restrict__ DD,
                      unsigned short* __restrict__ fh, unsigned short* __restrict__ fl) {
  int t = blockIdx.x * 256 + threadIdx.x;   // < M*256 exact
  int k = t & 255;
  int row = t >> 8;
  int b = row / N;
  float v = (k < 128) ? Hb[(size_t)row * 128 + k] : DD[(size_t)b * 128 + (k - 128)];
  unsigned short hi = f2bf(v);
  fh[t] = hi;
  fl[t] = f2bf(v - bf2f(hi));
}

// ---------------- gate*emb -> bf16 hi/lo directly ----------------
__global__ void k_gate_emb_bf(const float* __restrict__ x1, const float* __restrict__ gW,
                              const float* __restrict__ gb, const float* __restrict__ emb,
                              unsigned short* __restrict__ GH, unsigned short* __restrict__ GL) {
  size_t t = (size_t)blockIdx.x * 256 + threadIdx.x;  // < M*512 exact
  int e = (int)(t & 511);
  size_t bn = t >> 9;
  int n = (int)(bn % N);
  float g = sigm(x1[bn] * gW[e] + gb[e]);
  float v = g * emb[(size_t)n * 512 + e];
  unsigned short hi = f2bf(v);
  GH[t] = hi;
  GL[t] = f2bf(v - bf2f(hi));
}

__global__ void k_zero(float* __restrict__ p, int n) {
  int t = blockIdx.x * 256 + threadIdx.x;
  if (t < n) p[t] = 0.f;
}

__global__ void k_scatter(const int* __restrict__ ei, float* __restrict__ adj) {
  int t = blockIdx.x * 256 + threadIdx.x;
  if (t < NEDGE) {
    int r = ei[t], c = ei[NEDGE + t];
    adj[(size_t)r * N + c] = 1.f;
  }
}

// ------- MFMA staging: 128x32 bf16 tile, XOR-swizzled ((r&7)<<4 on 64B rows) -------
__device__ __forceinline__ void stage_tile(const unsigned short* __restrict__ gbase, int grow0,
                                           int rowmax, int k0, int ldk, char* lds, int tid) {
#pragma unroll
  for (int it = 0; it < 2; it++) {
    int r = (tid >> 2) + it * 64;
    int c8 = tid & 3;
    int gr = grow0 + r;
    uint4 v = make_uint4(0u, 0u, 0u, 0u);
    if (gr < rowmax) v = *reinterpret_cast<const uint4*>(&gbase[(size_t)gr * ldk + k0 + c8 * 8]);
    int off = (r * 64 + c8 * 16) ^ ((r & 7) << 4);
    *reinterpret_cast<uint4*>(lds + off) = v;
  }
}

__device__ __forceinline__ bf16x8 frag(const char* lds, int r, int k8) {
  int off = (r * 64 + k8 * 16) ^ ((r & 7) << 4);
  return *reinterpret_cast<const bf16x8*>(lds + off);
}

// ------- generic split-bf16 MFMA GEMM: C = act(A@B + bias) -------
template <int ACT, bool HASBIAS, bool OUTF32, bool OUTBF>
__global__ __launch_bounds__(256) void k_mgemm(const unsigned short* __restrict__ AH,
                                               const unsigned short* __restrict__ AL,
                                               const unsigned short* __restrict__ BTH,
                                               const unsigned short* __restrict__ BTL,
                                               const float* __restrict__ bias,
                                               float* __restrict__ Cf,
                                               unsigned short* __restrict__ CbH,
                                               unsigned short* __restrict__ CbL,
                                               int Mm, int K, int Nc) {
  __shared__ __align__(16) char Ah[8192];
  __shared__ __align__(16) char Al[8192];
  __shared__ __align__(16) char Bh[8192];
  __shared__ __align__(16) char Bl[8192];
  const int m0 = blockIdx.x * 128;
  const int n0 = blockIdx.y * 128;
  const int tid = threadIdx.x;
  const int wave = tid >> 6, lane = tid & 63;
  f32x4 acc[2][8];
#pragma unroll
  for (int i = 0; i < 2; i++)
#pragma unroll
    for (int j = 0; j < 8; j++) acc[i][j] = (f32x4){0.f, 0.f, 0.f, 0.f};

  for (int k0 = 0; k0 < K; k0 += 32) {
    stage_tile(AH, m0, Mm, k0, K, Ah, tid);
    stage_tile(AL, m0, Mm, k0, K, Al, tid);
    stage_tile(BTH, n0, Nc, k0, K, Bh, tid);
    stage_tile(BTL, n0, Nc, k0, K, Bl, tid);
    __syncthreads();
    bf16x8 ah[2], al[2];
#pragma unroll
    for (int rf = 0; rf < 2; rf++) {
      int r = wave * 32 + rf * 16 + (lane & 15);
      ah[rf] = frag(Ah, r, lane >> 4);
      al[rf] = frag(Al, r, lane >> 4);
    }
#pragma unroll
    for (int cf = 0; cf < 8; cf++) {
      int rB = cf * 16 + (lane & 15);
      bf16x8 bh = frag(Bh, rB, lane >> 4);
      bf16x8 bl = frag(Bl, rB, lane >> 4);
#pragma unroll
      for (int rf = 0; rf < 2; rf++) {
        acc[rf][cf] = __builtin_amdgcn_mfma_f32_16x16x32_bf16(ah[rf], bh, acc[rf][cf], 0, 0, 0);
        acc[rf][cf] = __builtin_amdgcn_mfma_f32_16x16x32_bf16(ah[rf], bl, acc[rf][cf], 0, 0, 0);
        acc[rf][cf] = __builtin_amdgcn_mfma_f32_16x16x32_bf16(al[rf], bh, acc[rf][cf], 0, 0, 0);
      }
    }
    __syncthreads();
  }
#pragma unroll
  for (int rf = 0; rf < 2; rf++)
#pragma unroll
    for (int cf = 0; cf < 8; cf++)
#pragma unroll
      for (int r4 = 0; r4 < 4; r4++) {
        int row = m0 + wave * 32 + rf * 16 + ((lane >> 4) << 2) + r4;
        int col = n0 + cf * 16 + (lane & 15);
        if (row < Mm) {
          float v = acc[rf][cf][r4];
          if (HASBIAS) v += bias[col];
          if (ACT == 1) v = geluf(v);
          if (ACT == 2) v = fmaxf(v, 0.f);
          size_t idx = (size_t)row * Nc + col;
          if (OUTF32) Cf[idx] = v;
          if (OUTBF) {
            unsigned short hi = f2bf(v);
            CbH[idx] = hi;
            CbL[idx] = f2bf(v - bf2f(hi));
          }
        }
      }
}

// ------- hp chunk GEMM, split-bf16 (fp32-equivalent): CH = relu(FUS @ WT_chunk^T) -------
__global__ __launch_bounds__(256) void k_hp_mma(const unsigned short* __restrict__ FH,
                                                const unsigned short* __restrict__ FL,
                                                const unsigned short* __restrict__ WTHc,
                                                const unsigned short* __restrict__ WTLc,
                                                float* __restrict__ CH) {
  __shared__ __align__(16) char Ah[8192];
  __shared__ __align__(16) char Al[8192];
  __shared__ __align__(16) char Bh[8192];
  __shared__ __align__(16) char Bl[8192];
  const int m0 = blockIdx.x * 128;
  const int n0 = blockIdx.y * 128;   // within chunk (KCH)
  const int tid = threadIdx.x;
  const int wave = tid >> 6, lane = tid & 63;
  f32x4 acc[2][8];
#pragma unroll
  for (int i = 0; i < 2; i++)
#pragma unroll
    for (int j = 0; j < 8; j++) acc[i][j] = (f32x4){0.f, 0.f, 0.f, 0.f};

  for (int k0 = 0; k0 < 256; k0 += 32) {
    stage_tile(FH, m0, M, k0, 256, Ah, tid);
    stage_tile(FL, m0, M, k0, 256, Al, tid);
    stage_tile(WTHc, n0, KCH, k0, 256, Bh, tid);
    stage_tile(WTLc, n0, KCH, k0, 256, Bl, tid);
    __syncthreads();
    bf16x8 ah[2], al[2];
#pragma unroll
    for (int rf = 0; rf < 2; rf++) {
      int r = wave * 32 + rf * 16 + (lane & 15);
      ah[rf] = frag(Ah, r, lane >> 4);
      al[rf] = frag(Al, r, lane >> 4);
    }
#pragma unroll
    for (int cf = 0; cf < 8; cf++) {
      int rB = cf * 16 + (lane & 15);
      bf16x8 bh = frag(Bh, rB, lane >> 4);
      bf16x8 bl = frag(Bl, rB, lane >> 4);
#pragma unroll
      for (int rf = 0; rf < 2; rf++) {
        acc[rf][cf] = __builtin_amdgcn_mfma_f32_16x16x32_bf16(ah[rf], bh, acc[rf][cf], 0, 0, 0);
        acc[rf][cf] = __builtin_amdgcn_mfma_f32_16x16x32_bf16(ah[rf], bl, acc[rf][cf], 0, 0, 0);
        acc[rf][cf] = __builtin_amdgcn_mfma_f32_16x16x32_bf16(al[rf], bh, acc[rf][cf], 0, 0, 0);
      }
    }
    __syncthreads();
  }
#pragma unroll
  for (int rf = 0; rf < 2; rf++)
#pragma unroll
    for (int cf = 0; cf < 8; cf++)
#pragma unroll
      for (int r4 = 0; r4 < 4; r4++) {
        int row = m0 + wave * 32 + rf * 16 + ((lane >> 4) << 2) + r4;
        int col = n0 + cf * 16 + (lane & 15);
        if (row < M) CH[(size_t)row * KCH + col] = fmaxf(acc[rf][cf][r4], 0.f);
      }
}

// ---------------- per-chunk column means (parallel, deterministic) ----------------
__global__ __launch_bounds__(256) void k_mu(const float* __restrict__ CH, float* __restrict__ MU) {
  __shared__ double red[8][33];
  int b = blockIdx.y, jg = blockIdx.x;
  int jloc = threadIdx.x & 31, s = threadIdx.x >> 5;
  int j = jg * 32 + jloc;
  const float* p = CH + (size_t)b * N * KCH + j;
  double acc = 0.0;
  for (int n = s; n < N; n += 8) acc += (double)p[(size_t)n * KCH];
  red[s][jloc] = acc;
  __syncthreads();
  if (s == 0) {
    double t = 0.0;
#pragma unroll
    for (int k = 0; k < 8; k++) t += red[k][jloc];
    MU[b * KCH + j] = (float)(t * (1.0 / (double)N));
  }
}

// ------- fused center+q: CHB = bf16(CH - MU); qv[r] += <MU[b], CH[r]> (f64) -------
__global__ __launch_bounds__(256) void k_centerq(const float* __restrict__ CH,
                                                 const float* __restrict__ MU,
                                                 unsigned short* __restrict__ CHB,
                                                 double* __restrict__ qv) {
  int r = blockIdx.x * 4 + (threadIdx.x >> 6);   // grid = M/4 = 3912 exact
  int lane = threadIdx.x & 63;
  int b = r / N;
  const float* row = CH + (size_t)r * KCH;
  const float* mu = MU + (size_t)b * KCH;
  double q = 0.0;
#pragma unroll
  for (int jp = 0; jp < 2; jp++) {
    int j0 = lane * 8 + jp * 512;
    float4 v0 = *reinterpret_cast<const float4*>(&row[j0]);
    float4 v1 = *reinterpret_cast<const float4*>(&row[j0 + 4]);
    float4 m0 = *reinterpret_cast<const float4*>(&mu[j0]);
    float4 m1 = *reinterpret_cast<const float4*>(&mu[j0 + 4]);
    unsigned short cb[8];
    cb[0] = f2bf(v0.x - m0.x); cb[1] = f2bf(v0.y - m0.y);
    cb[2] = f2bf(v0.z - m0.z); cb[3] = f2bf(v0.w - m0.w);
    cb[4] = f2bf(v1.x - m1.x); cb[5] = f2bf(v1.y - m1.y);
    cb[6] = f2bf(v1.z - m1.z); cb[7] = f2bf(v1.w - m1.w);
    *reinterpret_cast<uint4*>(&CHB[(size_t)r * KCH + j0]) = *reinterpret_cast<uint4*>(cb);
    q += (double)m0.x * v0.x + (double)m0.y * v0.y + (double)m0.z * v0.z + (double)m0.w * v0.w
       + (double)m1.x * v1.x + (double)m1.y * v1.y + (double)m1.z * v1.z + (double)m1.w * v1.w;
  }
  for (int off = 32; off > 0; off >>= 1) q += __shfl_down(q, off);
  if (lane == 0) qv[r] += q;
}

// ------- centered Gram via bf16 MFMA: G[b] (+)= CHBc @ CHBc^T -------
template <bool ACC>
__global__ __launch_bounds__(256) void k_syrk_mma(const unsigned short* __restrict__ CHB,
                                                  float* __restrict__ ATT) {
  __shared__ __align__(16) char At[8192];
  __shared__ __align__(16) char Bt[8192];
  const int T = 8;
  int pr = blockIdx.x;
  int ti = 0, rem = pr;
  while (rem >= T - ti) { rem -= T - ti; ti++; }
  int tj = ti + rem;
  int b = blockIdx.y;
  const unsigned short* base = CHB + (size_t)b * N * KCH;
  const int tid = threadIdx.x;
  const int wave = tid >> 6, lane = tid & 63;
  f32x4 acc[2][8];
#pragma unroll
  for (int i = 0; i < 2; i++)
#pragma unroll
    for (int j = 0; j < 8; j++) acc[i][j] = (f32x4){0.f, 0.f, 0.f, 0.f};

  for (int k0 = 0; k0 < KCH; k0 += 32) {
    stage_tile(base, ti * 128, N, k0, KCH, At, tid);
    stage_tile(base, tj * 128, N, k0, KCH, Bt, tid);
    __syncthreads();
    bf16x8 af[2];
#pragma unroll
    for (int rf = 0; rf < 2; rf++)
      af[rf] = frag(At, wave * 32 + rf * 16 + (lane & 15), lane >> 4);
#pragma unroll
    for (int cf = 0; cf < 8; cf++) {
      bf16x8 bf_ = frag(Bt, cf * 16 + (lane & 15), lane >> 4);
#pragma unroll
      for (int rf = 0; rf < 2; rf++)
        acc[rf][cf] = __builtin_amdgcn_mfma_f32_16x16x32_bf16(af[rf], bf_, acc[rf][cf], 0, 0, 0);
    }
    __syncthreads();
  }
  float* att = ATT + (size_t)b * N * N;
#pragma unroll
  for (int rf = 0; rf < 2; rf++)
#pragma unroll
    for (int cf = 0; cf < 8; cf++)
#pragma unroll
      for (int r4 = 0; r4 < 4; r4++) {
        int row = ti * 128 + wave * 32 + rf * 16 + ((lane >> 4) << 2) + r4;
        int col = tj * 128 + cf * 16 + (lane & 15);
        if (row < N && col < N) {
          float v = acc[rf][cf][r4];
          if (ACC) {
            att[(size_t)row * N + col] += v;
            if (ti != tj) att[(size_t)col * N + row] += v;
          } else {
            att[(size_t)row * N + col] = v;
            if (ti != tj) att[(size_t)col * N + row] = v;
          }
        }
      }
}

// -------- top-50 on s = G + q_m - q_n, softmax(s/8), flagging --------
// Register bitonic on 32-bit keys: (~monotone(sv) & 0xFFFFFC00) | idx.
__global__ __launch_bounds__(256) void k_topk(float* __restrict__ ATT, const double* __restrict__ qv,
                                              const float* __restrict__ INITA,
                                              int* __restrict__ fcnt, int* __restrict__ frow,
                                              int* __restrict__ fcw, int* __restrict__ fidx,
                                              float* __restrict__ fv32) {
  int row = blockIdx.x;  // b*N + n
  int n = row % N;
  int b = row / N;
  float* arow = ATT + (size_t)row * N;
  __shared__ unsigned keys[1024];
  __shared__ float svs[1024];
  __shared__ float outr[N];
  __shared__ float sred;
  __shared__ int s_slot, s_cw;
  int tid = threadIdx.x;
  double qn = qv[row];
  unsigned kreg[4];
#pragma unroll
  for (int c = 0; c < 4; c++) {
    int i = tid + 256 * c;
    unsigned kk = 0xFFFFFFFFu;
    float sv = -1e30f;
    if (i < N) {
      sv = (float)((double)arow[i] + qv[(size_t)b * N + i] - qn);
      unsigned u = __float_as_uint(sv);
      u ^= (u >> 31) ? 0xFFFFFFFFu : 0x80000000u;
      kk = ((~u) & 0xFFFFFC00u) | (unsigned)i;
    }
    svs[i] = sv;
    kreg[c] = kk;
  }
  __syncthreads();
  for (int ksz = 2; ksz <= 1024; ksz <<= 1) {
    for (int j = ksz >> 1; j > 0; j >>= 1) {
      if (j <= 32) {
#pragma unroll
        for (int c = 0; c < 4; c++) {
          int e = tid + 256 * c;
          unsigned pk = __shfl_xor(kreg[c], j);
          bool takemin = (((e & j) == 0) == ((e & ksz) == 0));
          unsigned mn = kreg[c] < pk ? kreg[c] : pk;
          unsigned mx = kreg[c] < pk ? pk : kreg[c];
          kreg[c] = takemin ? mn : mx;
        }
      } else if (j >= 256) {
        int sw = j >> 8;
#pragma unroll
        for (int c = 0; c < 4; c++) {
          if ((c & sw) == 0) {
            int e = tid + 256 * c;
            bool up = (e & ksz) == 0;
            unsigned a = kreg[c], b2 = kreg[c | sw];
            if ((a > b2) == up) { kreg[c] = b2; kreg[c | sw] = a; }
          }
        }
      } else {
#pragma unroll
        for (int c = 0; c < 4; c++) keys[tid + 256 * c] = kreg[c];
        __syncthreads();
#pragma unroll
        for (int c = 0; c < 4; c++) {
          int e = tid + 256 * c;
          unsigned pk = keys[e ^ j];
          bool takemin = (((e & j) == 0) == ((e & ksz) == 0));
          unsigned mn = kreg[c] < pk ? kreg[c] : pk;
          unsigned mx = kreg[c] < pk ? pk : kreg[c];
          kreg[c] = takemin ? mn : mx;
        }
        __syncthreads();
      }
    }
  }
#pragma unroll
  for (int c = 0; c < 4; c++) keys[tid + 256 * c] = kreg[c];
  __syncthreads();

  float v49 = svs[keys[49] & 1023u];
  float v50v = svs[keys[50] & 1023u];
  float FLAGW = 8e-3f + 2e-5f * fabsf(v49);   // s-units
  bool flag = (v50v >= v49 - FLAGW);
  if (flag) {
    if (tid == 0) {
      int cin = 0;
      for (int r = 0; r < 50; r++)
        if (svs[keys[r] & 1023u] > v49 + FLAGW) cin++;
      int rhi = 50;
      while (rhi < 113) {
        float vv = svs[keys[rhi + 1] & 1023u];
        if (vv >= v49 - FLAGW) rhi++; else break;
      }
      int w = rhi - cin + 1;
      if (w > CANDMAX) w = CANDMAX;
      if (cin + w < 50) w = 50 - cin;
      int slot = atomicAdd(fcnt, 1);
      frow[slot] = row;
      fcw[slot] = cin | (w << 8);
      s_slot = slot;
      s_cw = cin | (w << 8);
    }
    __syncthreads();
    int slot = s_slot;
    int tot = (s_cw & 255) + (s_cw >> 8);
    for (int r = tid; r < tot; r += 256) {
      unsigned kk = keys[r];
      fidx[(size_t)slot * WST + r] = (int)(kk & 1023u);
      fv32[(size_t)slot * WST + r] = svs[kk & 1023u];
    }
    __syncthreads();
  }

  float vmax = svs[keys[0] & 1023u];
  float e = 0.f;
  int myidx = 0;
  if (tid < TOPKK) {
    unsigned kk = keys[tid];
    myidx = (int)(kk & 1023u);
    e = expf((svs[myidx] - vmax) * 0.125f);
  }
  float s = e;
  for (int off = 32; off > 0; off >>= 1) s += __shfl_down(s, off);
  if (tid == 0) sred = s;
  for (int m2 = tid; m2 < N; m2 += 256) outr[m2] = 0.2f * INITA[(size_t)n * N + m2];
  __syncthreads();
  if (tid < TOPKK) outr[myidx] = 0.2f * INITA[(size_t)n * N + myidx] + 0.8f * (e / sred);
  __syncthreads();
  for (int m2 = tid; m2 < N; m2 += 256) arow[m2] = outr[m2];
}

// -------- fixup: fv32 ranking + minimax mass-split at near-tied boundaries --------
__global__ __launch_bounds__(256) void k_fixup(float* __restrict__ ATT, const float* __restrict__ INITA,
                                               const int* __restrict__ fcnt, const int* __restrict__ frow,
                                               const int* __restrict__ fcw, const int* __restrict__ fidx,
                                               const float* __restrict__ fv32) {
  __shared__ double wts[56];
  __shared__ int mm[56];
  __shared__ int s_tot;
  int tid = threadIdx.x;
  int cnt = *fcnt;
  for (int slot = blockIdx.x; slot < cnt; slot += gridDim.x) {
    int row = frow[slot];
    int cw = fcw[slot];
    int cin = cw & 255, w = cw >> 8;
    int n = row % N;
    __syncthreads();
    if (tid == 0) {
      int need = 50 - cin;
      if (need > w) need = w;
      double cv[CANDMAX]; int cm[CANDMAX]; float cs[CANDMAX];
      for (int c = 0; c < w; c++) {
        float sv = fv32[(size_t)slot * WST + cin + c];
        cv[c] = (double)sv * 0.125;
        cm[c] = fidx[(size_t)slot * WST + cin + c];
        cs[c] = sv;
      }
      int ord[CANDMAX];
      for (int c = 0; c < w; c++) ord[c] = c;
      for (int a2 = 0; a2 < w; a2++) {
        int best = a2;
        for (int c2 = a2 + 1; c2 < w; c2++) {
          int i1 = ord[c2], i0 = ord[best];
          if (cv[i1] > cv[i0] || (cv[i1] == cv[i0] && cm[i1] < cm[i0])) best = c2;
        }
        int tswap = ord[a2]; ord[a2] = ord[best]; ord[best] = tswap;
      }
      double b_in = cv[ord[need - 1]];
      double b_out = (need < w) ? cv[ord[need]] : -1e300;
      const double DATT = 1e-3;
      double fac[56];
      int tot = 0;
      for (int r = 0; r < cin; r++) {
        wts[tot] = (double)fv32[(size_t)slot * WST + r];
        mm[tot] = fidx[(size_t)slot * WST + r];
        fac[tot++] = 1.0;
      }
      if (need == w || b_in - b_out > DATT) {
        for (int t3 = 0; t3 < need; t3++) {
          wts[tot] = (double)cs[ord[t3]];
          mm[tot] = cm[ord[t3]];
          fac[tot++] = 1.0;
        }
      } else {
        int gs = 0;
        while (gs < w && cv[ord[gs]] > b_in + DATT) gs++;
        int ge = w - 1;
        while (ge >= 0 && cv[ord[ge]] < b_out - DATT) ge--;
        double mid = 0.5 * (b_in + b_out);
        while (ge - gs + 1 > 3) {
          if (cv[ord[gs]] - mid >= mid - cv[ord[ge]]) gs++;
          else ge--;
        }
        int fullc = gs;
        int gcount = ge - gs + 1;
        int gneed = need - fullc;
        if (gneed < 0) gneed = 0;
        if (gneed > gcount) gneed = gcount;
        double frac = (gcount > 0) ? (double)gneed / (double)gcount : 0.0;
        for (int t3 = 0; t3 < fullc; t3++) {
          wts[tot] = (double)cs[ord[t3]];
          mm[tot] = cm[ord[t3]];
          fac[tot++] = 1.0;
        }
        for (int t3 = gs; t3 <= ge; t3++) {
          wts[tot] = (double)cs[ord[t3]];
          mm[tot] = cm[ord[t3]];
          fac[tot++] = frac;
        }
      }
      double vmax = -1e300;
      for (int r = 0; r < tot; r++)
        if (fac[r] > 0.0 && wts[r] > vmax) vmax = wts[r];
      double S = 0.0;
      for (int r = 0; r < tot; r++) {
        double e = fac[r] * exp((wts[r] - vmax) * 0.125);
        wts[r] = e;
        S += e;
      }
      double inv = 1.0 / S;
      for (int r = 0; r < tot; r++) wts[r] *= inv;
      s_tot = tot;
    }
    __syncthreads();
    int tot = s_tot;
    float* arow = ATT + (size_t)row * N;
    for (int m2 = tid; m2 < N; m2 += 256) arow[m2] = 0.2f * INITA[(size_t)n * N + m2];
    __syncthreads();
    if (tid < tot && wts[tid] > 0.0)
      arow[mm[tid]] = 0.2f * INITA[(size_t)n * N + mm[tid]] + 0.8f * (float)wts[tid];
    __syncthreads();
  }
}

// ---------------- GCN degree: two-stage coalesced ----------------
__global__ __launch_bounds__(256) void k_degp(const float* __restrict__ ADJ, float* __restrict__ DPART) {
  int ch = blockIdx.x, b = blockIdx.y;
  int tid = threadIdx.x;
  float reg[4] = {0.f, 0.f, 0.f, 0.f};
  int j0 = ch * 123, j1 = j0 + 123;
  if (j1 > N) j1 = N;
  const float* adj = ADJ + (size_t)b * N * N;
  for (int j = j0; j < j1; j++) {
    const float* rowp = adj + (size_t)j * N;
#pragma unroll
    for (int k = 0; k < 4; k++) {
      int i = tid + 256 * k;
      if (i < N) reg[k] += rowp[i];
    }
  }
  float* dp = DPART + ((size_t)b * 8 + ch) * N;
#pragma unroll
  for (int k = 0; k < 4; k++) {
    int i = tid + 256 * k;
    if (i < N) dp[i] = reg[k];
  }
}
__global__ void k_degf(const float* __restrict__ DPART, float* __restrict__ DINV) {
  int t = blockIdx.x * 256 + threadIdx.x;
  if (t >= M) return;
  int b = t / N, i = t - b * N;
  float s = 1.f;
#pragma unroll
  for (int c = 0; c < 8; c++) s += DPART[((size_t)b * 8 + c) * N + i];
  DINV[t] = rsqrtf(s);
}

// ---------------- spmm partial (F=128, 4-way j-split) ----------------
__global__ __launch_bounds__(256) void k_spmmp(const float* __restrict__ ADJ, const float* __restrict__ DINV,
                                               const float* __restrict__ X, float* __restrict__ PP) {
  __shared__ float As[16][132];
  __shared__ float Ws[16][132];
  const int tid = threadIdx.x;
  const int i0 = blockIdx.x * 128;
  const int b = blockIdx.z >> 2;
  const int q = blockIdx.z & 3;
  const int jstart = q * JQ;
  const int jend = (q == 3) ? N : (jstart + JQ);
  const float* adj = ADJ + (size_t)b * N * N;
  const float* dv = DINV + b * N;
  const float* xb = X + (size_t)b * N * 128;
  const int ty = tid >> 4, tx = tid & 15;
  float acc[8][8];
#pragma unroll
  for (int i = 0; i < 8; i++)
#pragma unroll
    for (int j = 0; j < 8; j++) acc[i][j] = 0.f;

  for (int j0 = jstart; j0 < jend; j0 += 16) {
#pragma unroll
    for (int l = 0; l < 8; l++) {
      int idx = tid + l * 256;
      int r = idx >> 7, c = idx & 127;
      int j = j0 + r, i = i0 + c;
      float v = 0.f;
      if (j < jend && i < N) {
        float dj = dv[j];
        v = adj[(size_t)j * N + i] * dj;
        if (i == j) v += dj;
      }
      As[r][c] = v;
      float w = 0.f;
      if (j < jend) w = xb[(size_t)j * 128 + c];
      Ws[r][c] = w;
    }
    __syncthreads();
#pragma unroll
    for (int k = 0; k < 16; k++) {
      float a[8], bb[8];
      *reinterpret_cast<float4*>(&a[0]) = *reinterpret_cast<const float4*>(&As[k][ty * 8]);
      *reinterpret_cast<float4*>(&a[4]) = *reinterpret_cast<const float4*>(&As[k][ty * 8 + 4]);
      *reinterpret_cast<float4*>(&bb[0]) = *reinterpret_cast<const float4*>(&Ws[k][tx * 8]);
      *reinterpret_cast<float4*>(&bb[4]) = *reinterpret_cast<const float4*>(&Ws[k][tx * 8 + 4]);
#pragma unroll
      for (int i = 0; i < 8; i++)
#pragma unroll
        for (int j = 0; j < 8; j++) acc[i][j] = fmaf(a[i], bb[j], acc[i][j]);
    }
    __syncthreads();
  }
#pragma unroll
  for (int i = 0; i < 8; i++) {
    int row = i0 + ty * 8 + i;
    if (row >= N) continue;
#pragma unroll
    for (int j4 = 0; j4 < 2; j4++) {
      float4 v;
      float* vv = reinterpret_cast<float*>(&v);
#pragma unroll
      for (int j = 0; j < 4; j++) vv[j] = acc[i][j4 * 4 + j];
      *reinterpret_cast<float4*>(&PP[(((size_t)q * M) + (size_t)b * N + row) * 128 +
                                     tx * 8 + j4 * 4]) = v;
    }
  }
}

// combine: v = (PP0+PP1+PP2+PP3)*di (+bias); OUTBF -> bf16 hi/lo, else fp32
template <bool HASBIAS, bool OUTBF>
__global__ void k_spmmc(const float* __restrict__ PP, const float* __restrict__ DINV,
                        const float* __restrict__ bias, float* __restrict__ OUT,
                        unsigned short* __restrict__ OH, unsigned short* __restrict__ OL) {
  int t = blockIdx.x * 256 + threadIdx.x;   // < M*128 exact
  int row = t >> 7, f = t & 127;
  float v = ((PP[t] + PP[(size_t)M * 128 + t]) +
             (PP[(size_t)2 * M * 128 + t] + PP[(size_t)3 * M * 128 + t])) * DINV[row];
  if (HASBIAS) v += bias[f];
  if (OUTBF) {
    unsigned short hi = f2bf(v);
    OH[t] = hi;
    OL[t] = f2bf(v - bf2f(hi));
  } else {
    OUT[t] = v;
  }
}

// ---------------- drug embed (fp32) ----------------
__global__ __launch_bounds__(256) void k_drug_l1(const float* __restrict__ d1, const float* __restrict__ d2,
                                                 const float* __restrict__ W, const float* __restrict__ bias,
                                                 float* __restrict__ T1) {
  __shared__ float row[DF];
  int blk = blockIdx.x;
  const float* dr = ((blk & 16) ? d2 : d1) + (size_t)(blk & 15) * DF;
  for (int i = threadIdx.x; i < DF; i += 256) row[i] = dr[i];
  __syncthreads();
  for (int e = threadIdx.x; e < 512; e += 256) {
    float s = bias[e];
    for (int k = 0; k < DF; k++) s = fmaf(row[k], W[(size_t)k * 512 + e], s);
    T1[(size_t)blk * 512 + e] = fmaxf(s, 0.f);
  }
}

__global__ __launch_bounds__(128) void k_drug_l2(const float* __restrict__ T1, const float* __restrict__ W,
                                                 const float* __restrict__ bias, const float* __restrict__ lg,
                                                 const float* __restrict__ lb, float* __restrict__ D) {
  __shared__ float row[512];
  __shared__ float red[4];
  int blk = blockIdx.x;
  int e = threadIdx.x;
  for (int i = e; i < 512; i += 128) row[i] = T1[(size_t)blk * 512 + i];
  __syncthreads();
  float s = bias[e];
  for (int k = 0; k < 512; k++) s = fmaf(row[k], W[k * 128 + e], s);
  float t = s;
  for (int off = 32; off > 0; off >>= 1) t += __shfl_down(t, off);
  if ((e & 63) == 0) red[e >> 6] = t;
  __syncthreads();
  float mean = (red[0] + red[1]) * (1.f / 128.f);
  float dd = s - mean;
  float wv = dd * dd;
  for (int off = 32; off > 0; off >>= 1) wv += __shfl_down(wv, off);
  if ((e & 63) == 0) red[2 + (e >> 6)] = wv;
  __syncthreads();
  float var = (red[2] + red[3]) * (1.f / 128.f);
  D[(size_t)blk * 128 + e] = dd * rsqrtf(var + 1e-5f) * lg[e] + lb[e];
}

// ---------------- head + decoder ----------------
__global__ void k_gemb(const float* __restrict__ NODE, float* __restrict__ GEMB) {
  int t = blockIdx.x * 256 + threadIdx.x;
  int b = t >> 7, f = t & 127;
  const float* p = NODE + (size_t)b * N * IB2 + f;
  float s = 0.f;
  for (int n2 = 0; n2 < N; n2++) s += p[(size_t)n2 * IB2];
  GEMB[t] = s * (1.f / (float)N);
}

__global__ void k_heads(const float* __restrict__ GEMB, const float* __restrict__ EPS,
                        float* __restrict__ out_mu, float* __restrict__ out_std, float* __restrict__ Z) {
  int t = blockIdx.x * 256 + threadIdx.x;
  int b = t >> 6, q = t & 63;
  float mu = GEMB[b * 128 + q];
  float xs = GEMB[b * 128 + 64 + q] - 64.f;
  float sp = (xs > 20.f) ? xs : log1pf(expf(xs));
  out_mu[t] = mu;
  out_std[t] = sp;
  Z[t] = mu + EPS[t] * sp;
}

__global__ __launch_bounds__(512) void k_dec1(const float* __restrict__ Z, const float* __restrict__ W1,
                                              const float* __restrict__ b1, const float* __restrict__ bg,
                                              const float* __restrict__ bb, float* __restrict__ DEC) {
  int f = threadIdx.x;
  float d[16];
  for (int b = 0; b < 16; b++) {
    float s = b1[f];
    for (int k = 0; k < 64; k++) s = fmaf(Z[b * 64 + k], W1[k * 512 + f], s);
    d[b] = s;
  }
  float m = 0.f;
  for (int b = 0; b < 16; b++) m += d[b];
  m *= (1.f / 16.f);
  float v = 0.f;
  for (int b = 0; b < 16; b++) { float t = d[b] - m; v += t * t; }
  v *= (1.f / 16.f);
  float sc = rsqrtf(v + 1e-5f) * bg[f];
  float sh = bb[f];
  for (int b = 0; b < 16; b++) {
    float x = (d[b] - m) * sc + sh;
    DEC[b * 512 + f] = fmaxf(x, 0.f);
  }
}

__global__ void k_dec2(const float* __restrict__ DEC, const float* __restrict__ W2,
                       const float* __restrict__ b2, float* __restrict__ X2) {
  int t = blockIdx.x * 256 + threadIdx.x;
  if (t >= M) return;
  int b = t / N, n2 = t - b * N;
  float s = b2[n2];
  const float* db = DEC + b * 512;
  for (int f = 0; f < 512; f++) s = fmaf(db[f], W2[(size_t)f * N + n2], s);
  X2[t] = fmaxf(s, 0.f);
}

}  // namespace

extern "C" void kernel_launch(void* const* d_in, const int* in_sizes, int n_in,
                              void* d_out, int out_size, void* d_ws, size_t ws_size,
                              hipStream_t stream) {
  const float* x1 = (const float*)d_in[0];
  const float* drug1 = (const float*)d_in[1];
  const float* drug2 = (const float*)d_in[2];
  const float* eps = (const float*)d_in[3];
  const int* ei = (const int*)d_in[4];
  const float* gate_W = (const float*)d_in[5];
  const float* gate_b = (const float*)d_in[6];
  const float* emb = (const float*)d_in[7];
  const float* encW1 = (const float*)d_in[8];
  const float* encb1 = (const float*)d_in[9];
  const float* encW2 = (const float*)d_in[10];
  const float* encb2 = (const float*)d_in[11];
  const float* netW1 = (const float*)d_in[12];
  const float* netb1 = (const float*)d_in[13];
  const float* netW2 = (const float*)d_in[14];
  const float* netb2 = (const float*)d_in[15];
  const float* ln_g = (const float*)d_in[16];
  const float* ln_b = (const float*)d_in[17];
  const float* feat_mask = (const float*)d_in[18];
  const float* W_sims = (const float*)d_in[19];
  const float* gcnW1 = (const float*)d_in[20];
  const float* gcnb1 = (const float*)d_in[21];
  const float* gcnW2 = (const float*)d_in[22];
  const float* gcnb2 = (const float*)d_in[23];
  const float* decW1 = (const float*)d_in[24];
  const float* decb1 = (const float*)d_in[25];
  const float* bn_g = (const float*)d_in[26];
  const float* bn_b = (const float*)d_in[27];
  const float* decW2 = (const float*)d_in[28];
  const float* decb2 = (const float*)d_in[29];
  (void)in_sizes; (void)n_in; (void)out_size; (void)ws_size;

  // Workspace layout (~190 MB; known-good <=192 MB)
  size_t o = 0;
  auto A = [&](size_t bytes) { char* p = (char*)d_ws + o; o += (bytes + 255) & ~(size_t)255; return p; };
  unsigned short* WTH = (unsigned short*)A((size_t)KATT * 256 * 2);  // 2 MB
  unsigned short* WTL = (unsigned short*)A((size_t)KATT * 256 * 2);  // 2 MB
  char* RBIG = A((size_t)64 * 1024 * 1024);                          // 64 MB
  float* Hb = (float*)A((size_t)M * 128 * 4);                        // 8 MB
  float* ADJ1 = (float*)A((size_t)B * N * N * 4);                    // 61 MB
  float* INITA = (float*)A((size_t)N * N * 4);                       // 3.8 MB
  float* T1 = (float*)A(32 * 512 * 4);
  float* Dd32 = (float*)A(32 * 128 * 4);
  float* DINV = (float*)A(M * 4);
  float* DPART = (float*)A((size_t)16 * 8 * N * 4);                  // 0.5 MB
  float* GEMB = (float*)A(B * 128 * 4);
  float* Zb = (float*)A(B * 64 * 4);
  float* DEC = (float*)A(B * 512 * 4);
  int* fcnt = (int*)A(256);
  float* MU = (float*)A((size_t)B * KCH * 4);                        // 64 KB
  double* qv = (double*)A((size_t)M * 8);
  unsigned short* FUSH = (unsigned short*)A((size_t)M * 256 * 2);    // 8 MB
  unsigned short* FUSL = (unsigned short*)A((size_t)M * 256 * 2);    // 8 MB
  unsigned short* CHB = (unsigned short*)A((size_t)M * KCH * 2);     // 30.6 MB
  unsigned short* WE1H = (unsigned short*)A(512 * 512 * 2);
  unsigned short* WE1L = (unsigned short*)A(512 * 512 * 2);
  unsigned short* WE2H = (unsigned short*)A(128 * 512 * 2);
  unsigned short* WE2L = (unsigned short*)A(128 * 512 * 2);
  unsigned short* WG1H = (unsigned short*)A(512 * 128 * 2);
  unsigned short* WG1L = (unsigned short*)A(512 * 128 * 2);
  unsigned short* WG2H = (unsigned short*)A(128 * 512 * 2);
  unsigned short* WG2L = (unsigned short*)A(128 * 512 * 2);

  // RBIG unions (phases don't overlap)
  //  encoder: GEH@0 GEL@16M H1H@32M H1L@48M
  //  g-loop chunks: CH (61.1 MB); after chunks (CH dead): FLAGS
  //  GCN: AGGH@0 AGGL@4M PP@8M..40M (4 partials); TTH/TTL live in dead CHB
  unsigned short* GEH = (unsigned short*)RBIG;
  unsigned short* GEL = (unsigned short*)(RBIG + (size_t)16 * 1024 * 1024);
  unsigned short* H1H = (unsigned short*)(RBIG + (size_t)32 * 1024 * 1024);
  unsigned short* H1L = (unsigned short*)(RBIG + (size_t)48 * 1024 * 1024);
  float* CH = (float*)RBIG;
  char* FLAGS = RBIG;                          // alias CH: live only after chunk loop
  int* frow = (int*)FLAGS;
  int* fcw = (int*)(FLAGS + (size_t)M * 4);
  int* fidx = (int*)(FLAGS + (size_t)2 * M * 4);
  float* fv32 = (float*)(FLAGS + (size_t)2 * M * 4 + (size_t)M * WST * 4);
  unsigned short* AGGH = (unsigned short*)RBIG;
  unsigned short* AGGL = (unsigned short*)(RBIG + (size_t)4 * 1024 * 1024);
  float* PP = (float*)(RBIG + (size_t)8 * 1024 * 1024);              // 4*M*128*4 = 32 MB
  unsigned short* TTH = CHB;                                         // M*512*2 = 15.3 MB
  unsigned short* TTL = CHB + (size_t)M * 512;                       // 15.3 MB (fits CHB 30.6)
  float* TW2 = (float*)FUSH;                   // GCN phase: FUS dead
  float* NODE = (float*)FUSL;

  float* out = (float*)d_out;
  float* out_x2 = out;
  float* out_adj2 = out + M;
  float* out_mu = out + M + (size_t)B * N * N;
  float* out_std = out_mu + B * 64;

  k_wt<<<4096, 256, 0, stream>>>(W_sims, feat_mask, WTH, WTL);
  k_wtrans<<<1024, 256, 0, stream>>>(encW1, WE1H, WE1L, 512, 512);
  k_wtrans<<<256, 256, 0, stream>>>(encW2, WE2H, WE2L, 512, 128);
  k_wtrans<<<256, 256, 0, stream>>>(gcnW1, WG1H, WG1L, 128, 512);
  k_wtrans<<<256, 256, 0, stream>>>(gcnW2, WG2H, WG2L, 512, 128);
  // encoder in split-bf16 MFMA
  k_gate_emb_bf<<<31296, 256, 0, stream>>>(x1, gate_W, gate_b, emb, GEH, GEL);
  k_mgemm<1, true, false, true><<<dim3(123, 4), 256, 0, stream>>>(
      GEH, GEL, WE1H, WE1L, encb1, nullptr, H1H, H1L, M, 512, 512);
  k_mgemm<0, true, true, false><<<dim3(123, 1), 256, 0, stream>>>(
      H1H, H1L, WE2H, WE2L, encb2, Hb, nullptr, nullptr, M, 512, 128);
  k_drug_l1<<<32, 256, 0, stream>>>(drug1, drug2, netW1, netb1, T1);
  k_drug_l2<<<32, 128, 0, stream>>>(T1, netW2, netb2, ln_g, ln_b, Dd32);
  k_zero<<<(N * N + 255) / 256, 256, 0, stream>>>(INITA, N * N);
  k_scatter<<<(NEDGE + 255) / 256, 256, 0, stream>>>(ei, INITA);

  for (int g = 0; g < 2; g++) {
    float* att = (g == 0) ? ADJ1 : out_adj2;
    const float* DDg = Dd32 + (size_t)g * 16 * 128;
    hipMemsetAsync(fcnt, 0, 4, stream);
    hipMemsetAsync(qv, 0, (size_t)M * 8, stream);
    k_fus<<<15648, 256, 0, stream>>>(Hb, DDg, FUSH, FUSL);
    for (int c = 0; c < NCH; c++) {
      k_hp_mma<<<dim3(123, KCH / 128), 256, 0, stream>>>(FUSH, FUSL, WTH + (size_t)c * KCH * 256,
                                                         WTL + (size_t)c * KCH * 256, CH);
      k_mu<<<dim3(KCH / 32, 16), 256, 0, stream>>>(CH, MU);
      k_centerq<<<M / 4, 256, 0, stream>>>(CH, MU, CHB, qv);
      if (c == 0)
        k_syrk_mma<false><<<dim3(36, 16), 256, 0, stream>>>(CHB, att);
      else
        k_syrk_mma<true><<<dim3(36, 16), 256, 0, stream>>>(CHB, att);
    }
    k_topk<<<M, 256, 0, stream>>>(att, qv, INITA, fcnt, frow, fcw, fidx, fv32);
    k_fixup<<<1024, 256, 0, stream>>>(att, INITA, fcnt, frow, fcw, fidx, fv32);
  }

  k_degp<<<dim3(8, 16), 256, 0, stream>>>(ADJ1, DPART);
  k_degf<<<(M + 255) / 256, 256, 0, stream>>>(DPART, DINV);
  // GCN layer 1: aggregate Hb first (associativity), then @W1 via MFMA
  k_spmmp<<<dim3(8, 1, 64), 256, 0, stream>>>(ADJ1, DINV, Hb, PP);
  k_spmmc<false, true><<<(M * 128) / 256, 256, 0, stream>>>(PP, DINV, nullptr, nullptr, AGGH, AGGL);
  k_mgemm<2, true, false, true><<<dim3(123, 4), 256, 0, stream>>>(
      AGGH, AGGL, WG1H, WG1L, gcnb1, nullptr, TTH, TTL, M, 128, 512);
  // GCN layer 2
  k_mgemm<0, false, true, false><<<dim3(123, 1), 256, 0, stream>>>(
      TTH, TTL, WG2H, WG2L, nullptr, TW2, nullptr, nullptr, M, 512, 128);
  k_spmmp<<<dim3(8, 1, 64), 256, 0, stream>>>(ADJ1, DINV, TW2, PP);
  k_spmmc<true, false><<<(M * 128) / 256, 256, 0, stream>>>(PP, DINV, gcnb2, NODE, nullptr, nullptr);
  k_gemb<<<8, 256, 0, stream>>>(NODE, GEMB);
  k_heads<<<4, 256, 0, stream>>>(GEMB, eps, out_mu, out_std, Zb);
  k_dec1<<<1, 512, 0, stream>>>(Zb, decW1, decb1, bn_g, bn_b, DEC);
  k_dec2<<<(M + 255) / 256, 256, 0, stream>>>(DEC, decW2, decb2, out_x2);
}